// Round 6
// baseline (87.548 us; speedup 1.0000x reference)
//
#include <hip/hip_runtime.h>
#include <hip/hip_bf16.h>
#include <math.h>

#define TOKS 16384
#define CDIM 1024
#define NEXP 8
#define RDIM 64
#define CAP  TOKS
#define NBLK_R 1024   // router blocks (16 tokens each)
#define FT_MAX 576    // max fused tiles: 16384/32 + 64 partials
#define NSPLIT 2      // output-slice split (blockIdx.y)

using f32x4   = __attribute__((ext_vector_type(4))) float;
using bf16x8  = __attribute__((ext_vector_type(8))) short;
using ushort8 = __attribute__((ext_vector_type(8))) unsigned short;

__device__ __forceinline__ ushort f2bf(float f) {
  unsigned u = __builtin_bit_cast(unsigned, f);
  u += 0x7fffu + ((u >> 16) & 1u);   // round-to-nearest-even
  return (ushort)(u >> 16);
}

// ---- pre-pass: rw permute; Wd -> wdt[e][s][r][kk] (8KB tiles, s=k/64);
//      Wu -> wut[e][n0][cc][r] (16KB tiles, n0=c/128). Tile-contiguous so
//      expert_kernel staging is fully coalesced.
__global__ __launch_bounds__(256) void convert_kernel(
    const float* __restrict__ Wd, const float* __restrict__ Wu,
    const float* __restrict__ rw_all, const int* __restrict__ key_id,
    ushort* __restrict__ wdt, ushort* __restrict__ wut,
    float* __restrict__ rw_p) {
  const int t = blockIdx.x * 256 + threadIdx.x;
  if (t < 2048) {              // rw_p: one float4 per thread
    const int st = t >> 7, rem = t & 127;
    const int h = rem >> 6, l = rem & 63;
    const int C = (st >> 2) * 256 + l * 4 + (st & 3);
    const float4 v = *(const float4*)(rw_all + (size_t)key_id[0] * CDIM * NEXP
                                      + C * 8 + h * 4);
    ((float4*)rw_p)[t] = v;
  } else if (t < 133120) {     // Wd: (e, r, k4) -> wdt[((e*16+s)*64+r)*16 + kq4]
    const int u = t - 2048;
    const int k4 = u & 255, r = (u >> 8) & 63, e = u >> 14;
    ushort4 h;
    h.x = f2bf(Wd[(size_t)(e * 1024 + k4 * 4 + 0) * 64 + r]);
    h.y = f2bf(Wd[(size_t)(e * 1024 + k4 * 4 + 1) * 64 + r]);
    h.z = f2bf(Wd[(size_t)(e * 1024 + k4 * 4 + 2) * 64 + r]);
    h.w = f2bf(Wd[(size_t)(e * 1024 + k4 * 4 + 3) * 64 + r]);
    const int s = k4 >> 4;          // k-block
    const int kq4 = k4 & 15;        // ushort4 index within row
    ((ushort4*)wdt)[((e * 16 + s) * 64 + r) * 16 + kq4] = h;
  } else {                     // Wu: (e, c, r4) -> wut[((e*8+n0)*128+cc)*16 + r4]
    const int u = t - 133120;
    const int r4 = u & 15, c = (u >> 4) & 1023, e = u >> 14;
    ushort4 h;
    h.x = f2bf(Wu[(size_t)(e * 64 + r4 * 4 + 0) * 1024 + c]);
    h.y = f2bf(Wu[(size_t)(e * 64 + r4 * 4 + 1) * 1024 + c]);
    h.z = f2bf(Wu[(size_t)(e * 64 + r4 * 4 + 2) * 1024 + c]);
    h.w = f2bf(Wu[(size_t)(e * 64 + r4 * 4 + 3) * 1024 + c]);
    const int n0 = c >> 7, cc = c & 127;
    ((ushort4*)wut)[((e * 8 + n0) * 128 + cc) * 16 + r4] = h;
  }
}

// ---------------- router: wave = token; NO global atomics ------------------
__global__ __launch_bounds__(256) void router_kernel(
    const float* __restrict__ x, const float* __restrict__ rw_p,
    const float* __restrict__ rb_all, const int* __restrict__ key_id,
    float* __restrict__ imp_part,
    int* __restrict__ pbuf, float2* __restrict__ ggbuf,
    int* __restrict__ histT, ushort* __restrict__ xb) {
  __shared__ float s_imp[4][NEXP];
  __shared__ int   s_pb[16];
  __shared__ float s_g1[16], s_g2[16];
  const int tid = threadIdx.x;
  const int lane = tid & 63;
  const int wave = tid >> 6;
  const int kid = key_id[0];
  const float4* rwp4 = (const float4*)rw_p;
  const float* rb = rb_all + (size_t)kid * NEXP;
  const int eln = ((lane & 1) << 2) | (lane & 2) | ((lane >> 2) & 1);
  const float rbe = rb[eln];
  float impacc = 0.f;

  const int wg = blockIdx.x * 4 + wave;
#pragma unroll 1
  for (int tt = 0; tt < 4; ++tt) {
    const int token = wg * 4 + tt;
    const float* xr = x + (size_t)token * CDIM + lane * 4;
    float4 xv[4];
#pragma unroll
    for (int j = 0; j < 4; ++j) xv[j] = *(const float4*)(xr + j * 256);
    ushort* xo = xb + (size_t)token * CDIM + lane * 4;
#pragma unroll
    for (int j = 0; j < 4; ++j) {
      ushort4 h;
      h.x = f2bf(xv[j].x); h.y = f2bf(xv[j].y);
      h.z = f2bf(xv[j].z); h.w = f2bf(xv[j].w);
      *(ushort4*)(xo + j * 256) = h;
    }
    float acc[8];
#pragma unroll
    for (int e = 0; e < 8; ++e) acc[e] = 0.f;
#pragma unroll
    for (int j = 0; j < 4; ++j) {
#pragma unroll
      for (int i = 0; i < 4; ++i) {
        const int st = j * 4 + i;
        const float4 wA = rwp4[st * 128 + lane];
        const float4 wB = rwp4[st * 128 + 64 + lane];
        const float xi = (&xv[j].x)[i];
        acc[0] = fmaf(xi, wA.x, acc[0]);
        acc[1] = fmaf(xi, wA.y, acc[1]);
        acc[2] = fmaf(xi, wA.z, acc[2]);
        acc[3] = fmaf(xi, wA.w, acc[3]);
        acc[4] = fmaf(xi, wB.x, acc[4]);
        acc[5] = fmaf(xi, wB.y, acc[5]);
        acc[6] = fmaf(xi, wB.z, acc[6]);
        acc[7] = fmaf(xi, wB.w, acc[7]);
      }
    }
    // butterfly 8 accs -> 1 (expert = bitrev3(lane&7)), then 64-lane sum
#pragma unroll
    for (int i = 0; i < 4; ++i) {
      const float send = (lane & 1) ? acc[i] : acc[i + 4];
      const float recv = __shfl_xor(send, 1);
      acc[i] = ((lane & 1) ? acc[i + 4] : acc[i]) + recv;
    }
#pragma unroll
    for (int i = 0; i < 2; ++i) {
      const float send = (lane & 2) ? acc[i] : acc[i + 2];
      const float recv = __shfl_xor(send, 2);
      acc[i] = ((lane & 2) ? acc[i + 2] : acc[i]) + recv;
    }
    {
      const float send = (lane & 4) ? acc[0] : acc[1];
      const float recv = __shfl_xor(send, 4);
      acc[0] = ((lane & 4) ? acc[1] : acc[0]) + recv;
    }
    float v = acc[0];
    v += __shfl_xor(v, 8); v += __shfl_xor(v, 16); v += __shfl_xor(v, 32);

    const float logit = v + rbe;
    float mx = logit;
    mx = fmaxf(mx, __shfl_xor(mx, 1));
    mx = fmaxf(mx, __shfl_xor(mx, 2));
    mx = fmaxf(mx, __shfl_xor(mx, 4));
    const float ex = expf(logit - mx);
    float sm = ex;
    sm += __shfl_xor(sm, 1); sm += __shfl_xor(sm, 2); sm += __shfl_xor(sm, 4);
    const float p = ex / sm;
    float bv = p; int bi = eln;
#pragma unroll
    for (int mk = 1; mk <= 4; mk <<= 1) {
      const float ov = __shfl_xor(bv, mk);
      const int oi = __shfl_xor(bi, mk);
      if (ov > bv || (ov == bv && oi < bi)) { bv = ov; bi = oi; }
    }
    const int e1 = bi; const float v1 = bv;
    float cv = (eln == e1) ? -1.f : p; int ci = eln;
#pragma unroll
    for (int mk = 1; mk <= 4; mk <<= 1) {
      const float ov = __shfl_xor(cv, mk);
      const int oi = __shfl_xor(ci, mk);
      if (ov > cv || (ov == cv && oi < ci)) { cv = ov; ci = oi; }
    }
    const int e2 = ci; const float v2 = cv;

    if (lane == 0) {
      const float gs = 1.f / (v1 + v2);
      const int li = wave * 4 + tt;
      s_g1[li] = v1 * gs;
      s_g2[li] = v2 * gs;
      s_pb[li] = e1 * 8 + e2;
    }
    impacc += p;
  }
  if (lane < 8) s_imp[wave][eln] = impacc;
  __syncthreads();
  if (tid < 8)
    imp_part[blockIdx.x * 8 + tid] =
        s_imp[0][tid] + s_imp[1][tid] + s_imp[2][tid] + s_imp[3][tid];

  // per-token records (coalesced, block-contiguous)
  if (tid < 16) {
    pbuf[blockIdx.x * 16 + tid] = s_pb[tid];
    ggbuf[blockIdx.x * 16 + tid] = make_float2(s_g1[tid], s_g2[tid]);
  }
  // transposed histograms: histT[c*1024 + blk], c in [0,80)
  if (tid < 80) {
    int c = 0;
    if (tid < 16) {
      const int k = tid >> 3, e = tid & 7;
#pragma unroll
      for (int j = 0; j < 16; ++j)
        c += ((k ? (s_pb[j] & 7) : (s_pb[j] >> 3)) == e) ? 1 : 0;
    } else {
      const int b = tid - 16;
#pragma unroll
      for (int j = 0; j < 16; ++j) c += (s_pb[j] == b) ? 1 : 0;
    }
    histT[tid * 1024 + blockIdx.x] = c;
  }
}

// -------- scan: one block per counter, parallel prefix over 1024 blocks ----
__global__ __launch_bounds__(256) void scan_kernel(
    const int* __restrict__ histT, int* __restrict__ baseT,
    int* __restrict__ cnt, int* __restrict__ cnt_pair) {
  __shared__ int ls[256];
  const int c = blockIdx.x;
  const int t = threadIdx.x;
  const int4 v = ((const int4*)(histT + (c << 10)))[t];
  const int s = v.x + v.y + v.z + v.w;
  ls[t] = s;
  __syncthreads();
#pragma unroll
  for (int off = 1; off < 256; off <<= 1) {
    const int add = (t >= off) ? ls[t - off] : 0;
    __syncthreads();
    ls[t] += add;
    __syncthreads();
  }
  const int incl = ls[t];
  const int excl = incl - s;
  int4 b;
  b.x = excl;
  b.y = excl + v.x;
  b.z = excl + v.x + v.y;
  b.w = excl + v.x + v.y + v.z;
  ((int4*)(baseT + (c << 10)))[t] = b;
  if (t == 255) {
    if (c < 16) cnt[c * 32] = incl;
    else        cnt_pair[(c - 16) * 32] = incl;
  }
}

// -------- scatter (blocks 0..255) + plan (block 256) -----------------------
__global__ __launch_bounds__(256) void scatter_kernel(
    const int* __restrict__ baseT, const int* __restrict__ pbuf,
    const int* __restrict__ cnt_pair,
    int* __restrict__ pairlist, int* __restrict__ fplan,
    int* __restrict__ totals) {
  if (blockIdx.x == 256) {   // plan: 32-token tiles per pair bucket
    __shared__ int uoff[64];
    const int t = threadIdx.x;
    if (t == 0) {
      int a = 0;
      for (int b = 0; b < 64; ++b) { uoff[b] = a; a += (cnt_pair[b * 32] + 31) >> 5; }
      totals[1] = a;
    }
    __syncthreads();
    if (t < 64) {
      const int nb = (cnt_pair[t * 32] + 31) >> 5;
      for (int i = 0; i < nb; ++i) fplan[uoff[t] + i] = (t << 16) | i;
    }
    return;
  }
  const int tid = threadIdx.x;
  const int lane = tid & 63;
  const int wave = tid >> 6;
  const int rb = blockIdx.x * 4 + wave;   // router block, 0..1023
  const int i = lane;
  int pb = 0;
  if (lane < 16) pb = pbuf[rb * 16 + lane];
  int rp = 0;
#pragma unroll
  for (int j = 0; j < 15; ++j) {
    const int q = __shfl(pb, j);
    if (j < i) rp += (q == pb) ? 1 : 0;
  }
  if (lane < 16) {
    const int token = rb * 16 + i;
    const int sp = baseT[((16 + pb) << 10) + rb] + rp;
    pairlist[pb * CAP + sp] = token;
  }
}

// ---- fused expert: 32-token pair tile, y-split output slices --------------
// Phase 1 (redundant per y): H0|H1 = GELU(x@Wd_e1)*g1 | GELU(x@Wd_e2)*g2
//   (M=32, N=128, K=1024), register-prefetch staging, 41KB LDS -> 3 blocks/CU.
// Phase 2: 4 of 8 col slices: out = H0@WuA + H1@WuB  (M=32, N=128, K=64+64)
__global__ __launch_bounds__(256) void expert_kernel(
    const ushort* __restrict__ xb, const ushort* __restrict__ wdt,
    const ushort* __restrict__ wut,
    const int* __restrict__ cnt_pair, const int* __restrict__ pairlist,
    const float2* __restrict__ ggbuf,
    const int* __restrict__ fplan, const int* __restrict__ totals,
    float* __restrict__ out) {
  if (blockIdx.x >= totals[1]) return;
  const int ent = fplan[blockIdx.x];
  const int b = ent >> 16, tile = ent & 0xffff;
  const int ea = b >> 3, eb = b & 7;
  const int n = cnt_pair[b * 32];
  const int start = tile * 32;
  const int ybase = blockIdx.y * 4;

  __shared__ __align__(16) char smem[41472];
  ushort* As  = (ushort*)(smem);            // 4 KB  phase1 (32x64)
  ushort* BsA = (ushort*)(smem + 4096);     // 8 KB  phase1 (64x64)
  ushort* BsB = (ushort*)(smem + 12288);    // 8 KB  phase1
  ushort* BuA = (ushort*)(smem);            // 16 KB phase2 (128x64, aliases)
  ushort* BuB = (ushort*)(smem + 16384);    // 16 KB phase2
  ushort* Hs0 = (ushort*)(smem + 32768);    // 4 KB  (32x64)
  ushort* Hs1 = (ushort*)(smem + 36864);    // 4 KB
  int*   toks = (int*)(smem + 40960);       // 128 B
  float* g1s  = (float*)(smem + 41088);     // 128 B
  float* g2s  = (float*)(smem + 41216);     // 128 B

  const int tid = threadIdx.x;
  const int lane = tid & 63;
  const int w = tid >> 6;
  const int wr = w >> 1, wc = w & 1;

  if (tid < 32) {
    int tk = -1; float2 gg = make_float2(0.f, 0.f);
    if (start + tid < n) {
      tk = pairlist[b * CAP + start + tid];
      gg = ggbuf[tk];
    }
    toks[tid] = tk; g1s[tid] = gg.x; g2s[tid] = gg.y;
  }
  __syncthreads();

  // staging geometry: row = tid>>3 (0..31), 8 ushorts at (tid&7)*8; B rows
  // 0..31 via lof0 and 32..63 via lof0+2048.
  const int rowS = tid >> 3;
  const int c8s = (tid & 7) * 8;
  const int lof0 = rowS * 64 + (c8s ^ ((rowS & 7) << 3));

  const int tkS = toks[rowS];
  const ushort* xrow = xb + (size_t)(tkS < 0 ? 0 : tkS) * CDIM + c8s;
  const ushort* wdA = wdt + ((size_t)ea << 16);   // 16 tiles x 4096
  const ushort* wdB = wdt + ((size_t)eb << 16);

  f32x4 acc[4];
#pragma unroll
  for (int nn = 0; nn < 4; ++nn) acc[nn] = (f32x4){0.f, 0.f, 0.f, 0.f};

  ushort8 rA, rBA0, rBA1, rBB0, rBB1;
  // prologue: load step 0
  rA   = *(const ushort8*)(xrow);
  rBA0 = *(const ushort8*)(wdA + tid * 8);
  rBA1 = *(const ushort8*)(wdA + (tid + 256) * 8);
  rBB0 = *(const ushort8*)(wdB + tid * 8);
  rBB1 = *(const ushort8*)(wdB + (tid + 256) * 8);

#pragma unroll 1
  for (int s = 0; s < 16; ++s) {
    __syncthreads();                       // prev step's LDS reads done
    *(ushort8*)&As [lof0]        = rA;
    *(ushort8*)&BsA[lof0]        = rBA0;
    *(ushort8*)&BsA[lof0 + 2048] = rBA1;
    *(ushort8*)&BsB[lof0]        = rBB0;
    *(ushort8*)&BsB[lof0 + 2048] = rBB1;
    if (s < 15) {                          // prefetch step s+1 (overlaps MFMA)
      rA   = *(const ushort8*)(xrow + (s + 1) * 64);
      rBA0 = *(const ushort8*)(wdA + ((s + 1) << 12) + tid * 8);
      rBA1 = *(const ushort8*)(wdA + ((s + 1) << 12) + (tid + 256) * 8);
      rBB0 = *(const ushort8*)(wdB + ((s + 1) << 12) + tid * 8);
      rBB1 = *(const ushort8*)(wdB + ((s + 1) << 12) + (tid + 256) * 8);
    }
    __syncthreads();
    const ushort* Bsx = wc ? BsB : BsA;
#pragma unroll
    for (int kk = 0; kk < 64; kk += 32) {
      const int kb = kk + (lane >> 4) * 8;
      bf16x8 a, bb[4];
      {
        const int row = wr * 16 + (lane & 15);
        a = *(const bf16x8*)&As[row * 64 + (kb ^ ((row & 7) << 3))];
      }
#pragma unroll
      for (int nn = 0; nn < 4; ++nn) {
        const int r = nn * 16 + (lane & 15);
        bb[nn] = *(const bf16x8*)&Bsx[r * 64 + (kb ^ ((r & 7) << 3))];
      }
#pragma unroll
      for (int nn = 0; nn < 4; ++nn)
        acc[nn] = __builtin_amdgcn_mfma_f32_16x16x32_bf16(a, bb[nn], acc[nn], 0, 0, 0);
    }
  }

  // issue phase-2 slice-0 weight loads early (hide under GELU epilogue)
  const ushort* wuA = wut + ((size_t)ea << 16);   // 8 tiles x 8192
  const ushort* wuB = wut + ((size_t)eb << 16);
  ushort8 rUA[4], rUB[4];
#pragma unroll
  for (int j = 0; j < 4; ++j) {
    rUA[j] = *(const ushort8*)(wuA + ((size_t)ybase << 13) + (tid + j * 256) * 8);
    rUB[j] = *(const ushort8*)(wuB + ((size_t)ybase << 13) + (tid + j * 256) * 8);
  }

  // phase-1 epilogue: GELU * gate -> Hs{wc} (swizzled; own rows, no race)
  {
    ushort* Hsx = wc ? Hs1 : Hs0;
    const float* gsx = wc ? g2s : g1s;
#pragma unroll
    for (int nn = 0; nn < 4; ++nn)
#pragma unroll
      for (int q = 0; q < 4; ++q) {
        const int slot = wr * 16 + (lane >> 4) * 4 + q;
        const int r = nn * 16 + (lane & 15);
        const float v = acc[nn][q];
        const float ge = 0.5f * v * (1.f + erff(v * 0.70710678118654752f));
        Hsx[slot * 64 + (r ^ ((slot & 7) << 3))] = f2bf(ge * gsx[slot]);
      }
  }

  // phase-2 staging geometry (128x64 tiles): rows ccS0 + j*32
  const int ccS0 = tid >> 3;
  const int rq8 = (tid & 7) * 8;
  const int swzU = (ccS0 & 7) << 3;

#pragma unroll 1
  for (int j = 0; j < 4; ++j) {
    const int n0 = ybase + j;
    __syncthreads();                     // Hs visible / prev Bu reads done
#pragma unroll
    for (int jj = 0; jj < 4; ++jj) {
      const int cc = ccS0 + jj * 32;
      *(ushort8*)&BuA[cc * 64 + (rq8 ^ swzU)] = rUA[jj];
      *(ushort8*)&BuB[cc * 64 + (rq8 ^ swzU)] = rUB[jj];
    }
    if (j < 3) {                         // prefetch next slice
#pragma unroll
      for (int jj = 0; jj < 4; ++jj) {
        rUA[jj] = *(const ushort8*)(wuA + ((size_t)(n0 + 1) << 13) + (tid + jj * 256) * 8);
        rUB[jj] = *(const ushort8*)(wuB + ((size_t)(n0 + 1) << 13) + (tid + jj * 256) * 8);
      }
    }
    __syncthreads();
    f32x4 uac[4];
#pragma unroll
    for (int nn = 0; nn < 4; ++nn) uac[nn] = (f32x4){0.f, 0.f, 0.f, 0.f};
    // pass A: H0 @ WuA
#pragma unroll
    for (int kk = 0; kk < 64; kk += 32) {
      const int kb = kk + (lane >> 4) * 8;
      bf16x8 a, bb[4];
      {
        const int row = wr * 16 + (lane & 15);
        a = *(const bf16x8*)&Hs0[row * 64 + (kb ^ ((row & 7) << 3))];
      }
#pragma unroll
      for (int nn = 0; nn < 4; ++nn) {
        const int c = wc * 64 + nn * 16 + (lane & 15);
        bb[nn] = *(const bf16x8*)&BuA[c * 64 + (kb ^ ((c & 7) << 3))];
      }
#pragma unroll
      for (int nn = 0; nn < 4; ++nn)
        uac[nn] = __builtin_amdgcn_mfma_f32_16x16x32_bf16(a, bb[nn], uac[nn], 0, 0, 0);
    }
    // pass B: H1 @ WuB (accumulate)
#pragma unroll
    for (int kk = 0; kk < 64; kk += 32) {
      const int kb = kk + (lane >> 4) * 8;
      bf16x8 a, bb[4];
      {
        const int row = wr * 16 + (lane & 15);
        a = *(const bf16x8*)&Hs1[row * 64 + (kb ^ ((row & 7) << 3))];
      }
#pragma unroll
      for (int nn = 0; nn < 4; ++nn) {
        const int c = wc * 64 + nn * 16 + (lane & 15);
        bb[nn] = *(const bf16x8*)&BuB[c * 64 + (kb ^ ((c & 7) << 3))];
      }
#pragma unroll
      for (int nn = 0; nn < 4; ++nn)
        uac[nn] = __builtin_amdgcn_mfma_f32_16x16x32_bf16(a, bb[nn], uac[nn], 0, 0, 0);
    }
    // store this 128-col slice
#pragma unroll
    for (int q = 0; q < 4; ++q) {
      const int slot = wr * 16 + (lane >> 4) * 4 + q;
      const int tk = toks[slot];
      if (tk >= 0) {
        float* orow = out + (size_t)tk * CDIM + n0 * 128 + wc * 64 + (lane & 15);
#pragma unroll
        for (int nn = 0; nn < 4; ++nn) orow[nn * 16] = uac[nn][q];
      }
    }
  }
}

// ---------------- aux: deterministic reduce of per-block importance --------
__global__ __launch_bounds__(256) void aux_kernel(
    const int* __restrict__ cnt, const float* __restrict__ imp_part,
    float* __restrict__ out_aux) {
  __shared__ float red[256];
  __shared__ float tot[NEXP];
  const int t = threadIdx.x;
  const int e = t & 7, b0 = t >> 3;
  float s = 0.f;
  for (int j = 0; j < NBLK_R / 32; ++j)
    s += imp_part[(b0 + 32 * j) * 8 + e];
  red[t] = s;
  __syncthreads();
  if (t < 8) {
    float tt = 0.f;
    for (int w = 0; w < 32; ++w) tt += red[w * 8 + t];
    tot[t] = tt;
  }
  __syncthreads();
  if (t == 0) {
    float a = 0.f;
#pragma unroll
    for (int ee = 0; ee < NEXP; ++ee)
      a += (tot[ee] / (float)TOKS) *
           ((float)(cnt[ee * 32] + cnt[(NEXP + ee) * 32]) / (float)(2 * TOKS));
    out_aux[0] = 0.001f * 8.f * a;
  }
}

extern "C" void kernel_launch(void* const* d_in, const int* in_sizes, int n_in,
                              void* d_out, int out_size, void* d_ws, size_t ws_size,
                              hipStream_t stream) {
  const float* x   = (const float*)d_in[0];
  const float* rw  = (const float*)d_in[1];
  const float* rb  = (const float*)d_in[2];
  const float* Wd  = (const float*)d_in[3];
  const float* Wu  = (const float*)d_in[4];
  const int* key_id = (const int*)d_in[5];
  float* out = (float*)d_out;

  char* ws = (char*)d_ws;
  int*    cnt      = (int*)ws;                    // 2 KB  (16 x 128B)
  int*    cnt_pair = (int*)(ws + 2048);           // 8 KB  (64 x 128B)
  int*    totals   = (int*)(ws + 10240);          // 8 B
  float*  imp_part = (float*)(ws + 16384);        // 32 KB
  int*    fplan    = (int*)(ws + 49152);          // ~2.3 KB
  ushort* wdt      = (ushort*)(ws + 2162688);     // 1 MB
  ushort* wut      = (ushort*)(ws + 3211264);     // 1 MB
  ushort* xb       = (ushort*)(ws + 4259840);     // 32 MB -> 37814272
  float*  rw_p     = (float*)(ws + 37814272);     // 32 KB -> 37847040
  int*    pairlist = (int*)(ws + 37847040);       // 4 MB  -> 42041344
  // router scratch (consumed by scan/scatter before expert_kernel runs)
  int*    histT = (int*)(ws + 42041344);                // 320 KB
  int*    baseT = (int*)(ws + 42041344 + 327680);       // 320 KB
  int*    pbuf  = (int*)(ws + 42041344 + 655360);       // 64 KB
  float2* ggbuf = (float2*)(ws + 42041344 + 720896);    // 128 KB (live into expert)

  convert_kernel<<<1032, 256, 0, stream>>>(Wd, Wu, rw, key_id, wdt, wut, rw_p);
  router_kernel<<<NBLK_R, 256, 0, stream>>>(x, rw_p, rb, key_id, imp_part,
                                            pbuf, ggbuf, histT, xb);
  scan_kernel<<<80, 256, 0, stream>>>(histT, baseT, cnt, cnt_pair);
  scatter_kernel<<<257, 256, 0, stream>>>(baseT, pbuf, cnt_pair,
                                          pairlist, fplan, totals);
  expert_kernel<<<dim3(FT_MAX, NSPLIT), 256, 0, stream>>>(
      xb, wdt, wut, cnt_pair, pairlist, ggbuf, fplan, totals, out);
  aux_kernel<<<1, 256, 0, stream>>>(cnt, imp_part, out + (size_t)TOKS * CDIM);
}

// Round 7
// 82.366 us; speedup vs baseline: 1.0629x; 1.0629x over previous
//
#include <hip/hip_runtime.h>
#include <hip/hip_bf16.h>
#include <math.h>

#define TOKS 16384
#define CDIM 1024
#define NEXP 8
#define RDIM 64
#define CAP  TOKS
#define NBLK_R 1024   // router blocks (16 tokens each)
#define DT_MAX 1056   // max down tiles: 32768/32 + 16
#define UT_MAX 320    // max up tiles: 16384/64 + 64

using f32x4   = __attribute__((ext_vector_type(4))) float;
using bf16x8  = __attribute__((ext_vector_type(8))) short;
using ushort8 = __attribute__((ext_vector_type(8))) unsigned short;

__device__ __forceinline__ ushort f2bf(float f) {
  unsigned u = __builtin_bit_cast(unsigned, f);
  u += 0x7fffu + ((u >> 16) & 1u);   // round-to-nearest-even
  return (ushort)(u >> 16);
}

// ---- pre-pass: rw permute; Wd -> wdt[e][s][r][kk] (8KB tiles, s=k/64);
//      Wu -> wut[e][n0][cc][r] (16KB tiles, n0=c/128). Tile-contiguous so
//      down/up staging is fully coalesced.
__global__ __launch_bounds__(256) void convert_kernel(
    const float* __restrict__ Wd, const float* __restrict__ Wu,
    const float* __restrict__ rw_all, const int* __restrict__ key_id,
    ushort* __restrict__ wdt, ushort* __restrict__ wut,
    float* __restrict__ rw_p) {
  const int t = blockIdx.x * 256 + threadIdx.x;
  if (t < 2048) {              // rw_p: one float4 per thread
    const int st = t >> 7, rem = t & 127;
    const int h = rem >> 6, l = rem & 63;
    const int C = (st >> 2) * 256 + l * 4 + (st & 3);
    const float4 v = *(const float4*)(rw_all + (size_t)key_id[0] * CDIM * NEXP
                                      + C * 8 + h * 4);
    ((float4*)rw_p)[t] = v;
  } else if (t < 133120) {     // Wd: (e, r, k4) -> wdt[((e*16+s)*64+r)*16 + kq4]
    const int u = t - 2048;
    const int k4 = u & 255, r = (u >> 8) & 63, e = u >> 14;
    ushort4 h;
    h.x = f2bf(Wd[(size_t)(e * 1024 + k4 * 4 + 0) * 64 + r]);
    h.y = f2bf(Wd[(size_t)(e * 1024 + k4 * 4 + 1) * 64 + r]);
    h.z = f2bf(Wd[(size_t)(e * 1024 + k4 * 4 + 2) * 64 + r]);
    h.w = f2bf(Wd[(size_t)(e * 1024 + k4 * 4 + 3) * 64 + r]);
    const int s = k4 >> 4;          // k-block
    const int kq4 = k4 & 15;        // ushort4 index within row
    ((ushort4*)wdt)[((e * 16 + s) * 64 + r) * 16 + kq4] = h;
  } else {                     // Wu: (e, c, r4) -> wut[((e*8+n0)*128+cc)*16 + r4]
    const int u = t - 133120;
    const int r4 = u & 15, c = (u >> 4) & 1023, e = u >> 14;
    ushort4 h;
    h.x = f2bf(Wu[(size_t)(e * 64 + r4 * 4 + 0) * 1024 + c]);
    h.y = f2bf(Wu[(size_t)(e * 64 + r4 * 4 + 1) * 1024 + c]);
    h.z = f2bf(Wu[(size_t)(e * 64 + r4 * 4 + 2) * 1024 + c]);
    h.w = f2bf(Wu[(size_t)(e * 64 + r4 * 4 + 3) * 1024 + c]);
    const int n0 = c >> 7, cc = c & 127;
    ((ushort4*)wut)[((e * 8 + n0) * 128 + cc) * 16 + r4] = h;
  }
}

// ---------------- router: wave = token; NO global atomics ------------------
__global__ __launch_bounds__(256) void router_kernel(
    const float* __restrict__ x, const float* __restrict__ rw_p,
    const float* __restrict__ rb_all, const int* __restrict__ key_id,
    float* __restrict__ imp_part,
    int* __restrict__ pbuf, float2* __restrict__ ggbuf,
    int* __restrict__ histT, ushort* __restrict__ xb) {
  __shared__ float s_imp[4][NEXP];
  __shared__ int   s_pb[16];
  __shared__ float s_g1[16], s_g2[16];
  const int tid = threadIdx.x;
  const int lane = tid & 63;
  const int wave = tid >> 6;
  const int kid = key_id[0];
  const float4* rwp4 = (const float4*)rw_p;
  const float* rb = rb_all + (size_t)kid * NEXP;
  const int eln = ((lane & 1) << 2) | (lane & 2) | ((lane >> 2) & 1);
  const float rbe = rb[eln];
  float impacc = 0.f;

  const int wg = blockIdx.x * 4 + wave;
#pragma unroll 1
  for (int tt = 0; tt < 4; ++tt) {
    const int token = wg * 4 + tt;
    const float* xr = x + (size_t)token * CDIM + lane * 4;
    float4 xv[4];
#pragma unroll
    for (int j = 0; j < 4; ++j) xv[j] = *(const float4*)(xr + j * 256);
    ushort* xo = xb + (size_t)token * CDIM + lane * 4;
#pragma unroll
    for (int j = 0; j < 4; ++j) {
      ushort4 h;
      h.x = f2bf(xv[j].x); h.y = f2bf(xv[j].y);
      h.z = f2bf(xv[j].z); h.w = f2bf(xv[j].w);
      *(ushort4*)(xo + j * 256) = h;
    }
    float acc[8];
#pragma unroll
    for (int e = 0; e < 8; ++e) acc[e] = 0.f;
#pragma unroll
    for (int j = 0; j < 4; ++j) {
#pragma unroll
      for (int i = 0; i < 4; ++i) {
        const int st = j * 4 + i;
        const float4 wA = rwp4[st * 128 + lane];
        const float4 wB = rwp4[st * 128 + 64 + lane];
        const float xi = (&xv[j].x)[i];
        acc[0] = fmaf(xi, wA.x, acc[0]);
        acc[1] = fmaf(xi, wA.y, acc[1]);
        acc[2] = fmaf(xi, wA.z, acc[2]);
        acc[3] = fmaf(xi, wA.w, acc[3]);
        acc[4] = fmaf(xi, wB.x, acc[4]);
        acc[5] = fmaf(xi, wB.y, acc[5]);
        acc[6] = fmaf(xi, wB.z, acc[6]);
        acc[7] = fmaf(xi, wB.w, acc[7]);
      }
    }
    // butterfly 8 accs -> 1 (expert = bitrev3(lane&7)), then 64-lane sum
#pragma unroll
    for (int i = 0; i < 4; ++i) {
      const float send = (lane & 1) ? acc[i] : acc[i + 4];
      const float recv = __shfl_xor(send, 1);
      acc[i] = ((lane & 1) ? acc[i + 4] : acc[i]) + recv;
    }
#pragma unroll
    for (int i = 0; i < 2; ++i) {
      const float send = (lane & 2) ? acc[i] : acc[i + 2];
      const float recv = __shfl_xor(send, 2);
      acc[i] = ((lane & 2) ? acc[i + 2] : acc[i]) + recv;
    }
    {
      const float send = (lane & 4) ? acc[0] : acc[1];
      const float recv = __shfl_xor(send, 4);
      acc[0] = ((lane & 4) ? acc[1] : acc[0]) + recv;
    }
    float v = acc[0];
    v += __shfl_xor(v, 8); v += __shfl_xor(v, 16); v += __shfl_xor(v, 32);

    const float logit = v + rbe;
    float mx = logit;
    mx = fmaxf(mx, __shfl_xor(mx, 1));
    mx = fmaxf(mx, __shfl_xor(mx, 2));
    mx = fmaxf(mx, __shfl_xor(mx, 4));
    const float ex = expf(logit - mx);
    float sm = ex;
    sm += __shfl_xor(sm, 1); sm += __shfl_xor(sm, 2); sm += __shfl_xor(sm, 4);
    const float p = ex / sm;
    float bv = p; int bi = eln;
#pragma unroll
    for (int mk = 1; mk <= 4; mk <<= 1) {
      const float ov = __shfl_xor(bv, mk);
      const int oi = __shfl_xor(bi, mk);
      if (ov > bv || (ov == bv && oi < bi)) { bv = ov; bi = oi; }
    }
    const int e1 = bi; const float v1 = bv;
    float cv = (eln == e1) ? -1.f : p; int ci = eln;
#pragma unroll
    for (int mk = 1; mk <= 4; mk <<= 1) {
      const float ov = __shfl_xor(cv, mk);
      const int oi = __shfl_xor(ci, mk);
      if (ov > cv || (ov == cv && oi < ci)) { cv = ov; ci = oi; }
    }
    const int e2 = ci; const float v2 = cv;

    if (lane == 0) {
      const float gs = 1.f / (v1 + v2);
      const int li = wave * 4 + tt;
      s_g1[li] = v1 * gs;
      s_g2[li] = v2 * gs;
      s_pb[li] = e1 * 8 + e2;
    }
    impacc += p;
  }
  if (lane < 8) s_imp[wave][eln] = impacc;
  __syncthreads();
  if (tid < 8)
    imp_part[blockIdx.x * 8 + tid] =
        s_imp[0][tid] + s_imp[1][tid] + s_imp[2][tid] + s_imp[3][tid];

  // per-token records (coalesced, block-contiguous)
  if (tid < 16) {
    pbuf[blockIdx.x * 16 + tid] = s_pb[tid];
    ggbuf[blockIdx.x * 16 + tid] = make_float2(s_g1[tid], s_g2[tid]);
  }
  // transposed histograms: histT[c*1024 + blk], c in [0,80)
  if (tid < 80) {
    int c = 0;
    if (tid < 16) {
      const int k = tid >> 3, e = tid & 7;
#pragma unroll
      for (int j = 0; j < 16; ++j)
        c += ((k ? (s_pb[j] & 7) : (s_pb[j] >> 3)) == e) ? 1 : 0;
    } else {
      const int b = tid - 16;
#pragma unroll
      for (int j = 0; j < 16; ++j) c += (s_pb[j] == b) ? 1 : 0;
    }
    histT[tid * 1024 + blockIdx.x] = c;
  }
}

// -------- scan: one block per counter, parallel prefix over 1024 blocks ----
__global__ __launch_bounds__(256) void scan_kernel(
    const int* __restrict__ histT, int* __restrict__ baseT,
    int* __restrict__ cnt, int* __restrict__ cnt_pair) {
  __shared__ int ls[256];
  const int c = blockIdx.x;
  const int t = threadIdx.x;
  const int4 v = ((const int4*)(histT + (c << 10)))[t];
  const int s = v.x + v.y + v.z + v.w;
  ls[t] = s;
  __syncthreads();
#pragma unroll
  for (int off = 1; off < 256; off <<= 1) {
    const int add = (t >= off) ? ls[t - off] : 0;
    __syncthreads();
    ls[t] += add;
    __syncthreads();
  }
  const int incl = ls[t];
  const int excl = incl - s;
  int4 b;
  b.x = excl;
  b.y = excl + v.x;
  b.z = excl + v.x + v.y;
  b.w = excl + v.x + v.y + v.z;
  ((int4*)(baseT + (c << 10)))[t] = b;
  if (t == 255) {
    if (c < 16) cnt[c * 32] = incl;
    else        cnt_pair[(c - 16) * 32] = incl;
  }
}

// -------- scatter (blocks 0..255: lists+pairs) + plan (block 256) ----------
__global__ __launch_bounds__(256) void scatter_kernel(
    const int* __restrict__ baseT, const int* __restrict__ pbuf,
    const float2* __restrict__ ggbuf,
    const int* __restrict__ cnt, const int* __restrict__ cnt_pair,
    int* __restrict__ list0, float* __restrict__ gate0,
    int* __restrict__ list1, float* __restrict__ gate1,
    int* __restrict__ pairlist,
    int* __restrict__ dplan, int* __restrict__ uplan,
    int* __restrict__ totals) {
  if (blockIdx.x == 256) {   // plan: 32-tok down tiles, 64-tok up tiles
    __shared__ int doff[16], uoff[64];
    const int t = threadIdx.x;
    if (t == 0) {
      int a = 0;
      for (int y = 0; y < 16; ++y) { doff[y] = a; a += (cnt[y * 32] + 31) >> 5; }
      totals[0] = a;
      a = 0;
      for (int b2 = 0; b2 < 64; ++b2) { uoff[b2] = a; a += (cnt_pair[b2 * 32] + 63) >> 6; }
      totals[1] = a;
    }
    __syncthreads();
    if (t < 16) {
      const int nd = (cnt[t * 32] + 31) >> 5;
      for (int i = 0; i < nd; ++i) dplan[doff[t] + i] = (t << 16) | i;
    }
    if (t < 64) {
      const int nu = (cnt_pair[t * 32] + 63) >> 6;
      for (int i = 0; i < nu; ++i) uplan[uoff[t] + i] = (t << 16) | i;
    }
    return;
  }
  const int tid = threadIdx.x;
  const int lane = tid & 63;
  const int wave = tid >> 6;
  const int rb = blockIdx.x * 4 + wave;   // router block, 0..1023
  const int i = lane;
  int pb = 0; float2 gg = make_float2(0.f, 0.f);
  if (lane < 16) { pb = pbuf[rb * 16 + lane]; gg = ggbuf[rb * 16 + lane]; }
  const int e1 = pb >> 3, e2 = pb & 7;
  int r0 = 0, r1 = 0, rp = 0;
#pragma unroll
  for (int j = 0; j < 15; ++j) {
    const int q = __shfl(pb, j);
    if (j < i) {
      r0 += ((q >> 3) == e1) ? 1 : 0;
      r1 += ((q & 7) == e2) ? 1 : 0;
      rp += (q == pb) ? 1 : 0;
    }
  }
  if (lane < 16) {
    const int token = rb * 16 + i;
    const int s0 = baseT[(e1 << 10) + rb] + r0;
    list0[e1 * CAP + s0] = token;
    gate0[e1 * CAP + s0] = gg.x;
    const int s1 = baseT[((8 + e2) << 10) + rb] + r1;
    list1[e2 * CAP + s1] = token;
    gate1[e2 * CAP + s1] = gg.y;
    const int sp = baseT[((16 + pb) << 10) + rb] + rp;
    pairlist[pb * CAP + sp] = token;
  }
}

// ---- down: H[k][tok] = GELU(x@Wd_e)*gate, 32-token x 64-r tiles -----------
// LDS 16.6KB -> 8 blocks/CU (wave cap) = full occupancy; grid ~1040.
__global__ __launch_bounds__(256) void down_kernel(
    const ushort* __restrict__ xb, const ushort* __restrict__ wdt,
    const int* __restrict__ cnt,
    const int* __restrict__ list0, const float* __restrict__ gate0,
    const int* __restrict__ list1, const float* __restrict__ gate1,
    const int* __restrict__ dplan, const int* __restrict__ totals,
    ushort* __restrict__ Hbuf) {
  if (blockIdx.x >= totals[0]) return;
  const int ent = dplan[blockIdx.x];
  const int y = ent >> 16, tile = ent & 0xffff;
  const int k = y >> 3, e = y & 7;
  const int n = cnt[y * 32];
  const int start = tile * 32;
  const int* list = k ? list1 : list0;
  const float* gate = k ? gate1 : gate0;

  __shared__ __align__(16) char smem[16640];
  ushort* As = (ushort*)(smem);            // 4 KB (32x64)
  ushort* Bs = (ushort*)(smem + 4096);     // 8 KB (64x64)
  ushort* Hs = (ushort*)(smem + 12288);    // 4 KB (32x64)
  int*  toks = (int*)(smem + 16384);       // 128 B
  float*  gs = (float*)(smem + 16512);     // 128 B

  const int tid = threadIdx.x;
  const int lane = tid & 63;
  const int w = tid >> 6;

  if (tid < 32) {
    int tk = -1; float g = 0.f;
    if (start + tid < n) {
      tk = list[e * CAP + start + tid];
      g = gate[e * CAP + start + tid];
    }
    toks[tid] = tk; gs[tid] = g;
  }
  __syncthreads();

  const int rowS = tid >> 3;               // 0..31
  const int c8s = (tid & 7) * 8;
  const int lofA = rowS * 64 + (c8s ^ ((rowS & 7) << 3));
  const int tkS = toks[rowS];
  const ushort* xrow = xb + (size_t)(tkS < 0 ? 0 : tkS) * CDIM + c8s;
  const ushort* wde = wdt + ((size_t)e << 16);   // 16 tiles x 4096 ushorts

  f32x4 acc[2];
  acc[0] = (f32x4){0.f, 0.f, 0.f, 0.f};
  acc[1] = (f32x4){0.f, 0.f, 0.f, 0.f};

  ushort8 rA, rB0, rB1;
  rA  = *(const ushort8*)(xrow);
  rB0 = *(const ushort8*)(wde + tid * 8);
  rB1 = *(const ushort8*)(wde + tid * 8 + 2048);

#pragma unroll 1
  for (int s = 0; s < 16; ++s) {
    __syncthreads();                       // prev step's LDS reads done
    *(ushort8*)&As[lofA]        = rA;
    *(ushort8*)&Bs[lofA]        = rB0;     // rows 0..31
    *(ushort8*)&Bs[lofA + 2048] = rB1;     // rows 32..63 (same swizzle: (r+32)&7==r&7)
    if (s < 15) {                          // prefetch step s+1 under MFMA
      rA  = *(const ushort8*)(xrow + (s + 1) * 64);
      rB0 = *(const ushort8*)(wde + ((s + 1) << 12) + tid * 8);
      rB1 = *(const ushort8*)(wde + ((s + 1) << 12) + tid * 8 + 2048);
    }
    __syncthreads();
#pragma unroll
    for (int kk = 0; kk < 64; kk += 32) {
      const int kb = kk + (lane >> 4) * 8;
      bf16x8 a[2], bb;
#pragma unroll
      for (int m = 0; m < 2; ++m) {
        const int row = m * 16 + (lane & 15);
        a[m] = *(const bf16x8*)&As[row * 64 + (kb ^ ((row & 7) << 3))];
      }
      {
        const int r = w * 16 + (lane & 15);
        bb = *(const bf16x8*)&Bs[r * 64 + (kb ^ ((r & 7) << 3))];
      }
#pragma unroll
      for (int m = 0; m < 2; ++m)
        acc[m] = __builtin_amdgcn_mfma_f32_16x16x32_bf16(a[m], bb, acc[m], 0, 0, 0);
    }
  }
  // epilogue: GELU*gate -> Hs (each wave owns its 16-col slice)
#pragma unroll
  for (int m = 0; m < 2; ++m)
#pragma unroll
    for (int q = 0; q < 4; ++q) {
      const int slot = m * 16 + (lane >> 4) * 4 + q;
      const int r = w * 16 + (lane & 15);
      const float v = acc[m][q];
      const float ge = 0.5f * v * (1.f + erff(v * 0.70710678118654752f));
      Hs[slot * 64 + (r ^ ((slot & 7) << 3))] = f2bf(ge * gs[slot]);
    }
  __syncthreads();
  // Hs -> Hbuf[(k<<14)+tok][64] (linear rows)
  {
    const int row = tid >> 3, c8 = (tid & 7) * 8;
    const int tk = toks[row];
    if (tk >= 0) {
      *(ushort8*)(Hbuf + ((size_t)((k << 14) + tk)) * 64 + c8) =
          *(const ushort8*)&Hs[row * 64 + (c8 ^ ((row & 7) << 3))];
    }
  }
}

// ---- up: out[t] = H0[t]@Wu_ea + H1[t]@Wu_eb, 64-tok x 128-col slices ------
// blockIdx.y = col slice (8); LDS 33KB -> 4 blocks/CU; grid ~2560.
__global__ __launch_bounds__(256) void up_kernel(
    const ushort* __restrict__ Hbuf, const ushort* __restrict__ wut,
    const int* __restrict__ cnt_pair, const int* __restrict__ pairlist,
    const int* __restrict__ uplan, const int* __restrict__ totals,
    float* __restrict__ out) {
  if (blockIdx.x >= totals[1]) return;
  const int ent = uplan[blockIdx.x];
  const int b = ent >> 16, tile = ent & 0xffff;
  const int ea = b >> 3, eb = b & 7;
  const int n = cnt_pair[b * 32];
  const int start = tile * 64;
  const int n0 = blockIdx.y;   // 0..7

  __shared__ __align__(16) char smem[33024];
  ushort* A0 = (ushort*)(smem);            // 8 KB (64x64)
  ushort* A1 = (ushort*)(smem + 8192);     // 8 KB
  ushort* Bu = (ushort*)(smem + 16384);    // 16 KB (128x64)
  int*  toks = (int*)(smem + 32768);       // 256 B

  const int tid = threadIdx.x;
  const int lane = tid & 63;
  const int w = tid >> 6;
  const int wr = w >> 1, wc = w & 1;

  if (tid < 64) {
    int tk = -1;
    if (start + tid < n) tk = pairlist[b * CAP + start + tid];
    toks[tid] = tk;
  }
  __syncthreads();
  // gather H0/H1 rows (swizzled)
#pragma unroll
  for (int i = 0; i < 2; ++i) {
    const int sc = tid + i * 256;
    const int row = sc >> 3, c8 = (sc & 7) * 8;
    const int tk = toks[row];
    const int tkc = tk < 0 ? 0 : tk;
    const ushort8 v0 = *(const ushort8*)(Hbuf + (size_t)tkc * 64 + c8);
    const ushort8 v1 = *(const ushort8*)(Hbuf + ((size_t)TOKS + tkc) * 64 + c8);
    *(ushort8*)&A0[row * 64 + (c8 ^ ((row & 7) << 3))] = v0;
    *(ushort8*)&A1[row * 64 + (c8 ^ ((row & 7) << 3))] = v1;
  }
  // stage Bu with expert-A tile; prefetch expert-B tile to regs
  const ushort* tA = wut + ((size_t)(ea * 8 + n0)) * 8192;
  const ushort* tB = wut + ((size_t)(eb * 8 + n0)) * 8192;
  const int ccS = tid >> 3, r8 = (tid & 7) * 8;
  ushort8 rB[4];
#pragma unroll
  for (int j = 0; j < 4; ++j) {
    const int cc = ccS + j * 32;
    *(ushort8*)&Bu[cc * 64 + (r8 ^ ((cc & 7) << 3))] =
        *(const ushort8*)(tA + (size_t)(tid + j * 256) * 8);
    rB[j] = *(const ushort8*)(tB + (size_t)(tid + j * 256) * 8);
  }
  __syncthreads();

  f32x4 uac[2][4];
#pragma unroll
  for (int m = 0; m < 2; ++m)
#pragma unroll
    for (int nn = 0; nn < 4; ++nn) uac[m][nn] = (f32x4){0.f, 0.f, 0.f, 0.f};

  // pass A: H0 @ Wu_ea
#pragma unroll
  for (int kk = 0; kk < 64; kk += 32) {
    const int kb = kk + (lane >> 4) * 8;
    bf16x8 a[2], bbv[4];
#pragma unroll
    for (int m = 0; m < 2; ++m) {
      const int row = wr * 32 + m * 16 + (lane & 15);
      a[m] = *(const bf16x8*)&A0[row * 64 + (kb ^ ((row & 7) << 3))];
    }
#pragma unroll
    for (int nn = 0; nn < 4; ++nn) {
      const int c = wc * 64 + nn * 16 + (lane & 15);
      bbv[nn] = *(const bf16x8*)&Bu[c * 64 + (kb ^ ((c & 7) << 3))];
    }
#pragma unroll
    for (int m = 0; m < 2; ++m)
#pragma unroll
      for (int nn = 0; nn < 4; ++nn)
        uac[m][nn] = __builtin_amdgcn_mfma_f32_16x16x32_bf16(a[m], bbv[nn], uac[m][nn], 0, 0, 0);
  }
  __syncthreads();
  // restage Bu with expert-B tile from regs
#pragma unroll
  for (int j = 0; j < 4; ++j) {
    const int cc = ccS + j * 32;
    *(ushort8*)&Bu[cc * 64 + (r8 ^ ((cc & 7) << 3))] = rB[j];
  }
  __syncthreads();
  // pass B: H1 @ Wu_eb (accumulate)
#pragma unroll
  for (int kk = 0; kk < 64; kk += 32) {
    const int kb = kk + (lane >> 4) * 8;
    bf16x8 a[2], bbv[4];
#pragma unroll
    for (int m = 0; m < 2; ++m) {
      const int row = wr * 32 + m * 16 + (lane & 15);
      a[m] = *(const bf16x8*)&A1[row * 64 + (kb ^ ((row & 7) << 3))];
    }
#pragma unroll
    for (int nn = 0; nn < 4; ++nn) {
      const int c = wc * 64 + nn * 16 + (lane & 15);
      bbv[nn] = *(const bf16x8*)&Bu[c * 64 + (kb ^ ((c & 7) << 3))];
    }
#pragma unroll
    for (int m = 0; m < 2; ++m)
#pragma unroll
      for (int nn = 0; nn < 4; ++nn)
        uac[m][nn] = __builtin_amdgcn_mfma_f32_16x16x32_bf16(a[m], bbv[nn], uac[m][nn], 0, 0, 0);
  }
  // store this 128-col slice (each token row owned by exactly one bucket)
#pragma unroll
  for (int m = 0; m < 2; ++m)
#pragma unroll
    for (int q = 0; q < 4; ++q) {
      const int slot = wr * 32 + m * 16 + (lane >> 4) * 4 + q;
      const int tk = toks[slot];
      if (tk >= 0) {
        float* orow = out + (size_t)tk * CDIM + n0 * 128 + wc * 64 + (lane & 15);
#pragma unroll
        for (int nn = 0; nn < 4; ++nn) orow[nn * 16] = uac[m][nn][q];
      }
    }
}

// ---------------- aux: deterministic reduce of per-block importance --------
__global__ __launch_bounds__(256) void aux_kernel(
    const int* __restrict__ cnt, const float* __restrict__ imp_part,
    float* __restrict__ out_aux) {
  __shared__ float red[256];
  __shared__ float tot[NEXP];
  const int t = threadIdx.x;
  const int e = t & 7, b0 = t >> 3;
  float s = 0.f;
  for (int j = 0; j < NBLK_R / 32; ++j)
    s += imp_part[(b0 + 32 * j) * 8 + e];
  red[t] = s;
  __syncthreads();
  if (t < 8) {
    float tt = 0.f;
    for (int w = 0; w < 32; ++w) tt += red[w * 8 + t];
    tot[t] = tt;
  }
  __syncthreads();
  if (t == 0) {
    float a = 0.f;
#pragma unroll
    for (int ee = 0; ee < NEXP; ++ee)
      a += (tot[ee] / (float)TOKS) *
           ((float)(cnt[ee * 32] + cnt[(NEXP + ee) * 32]) / (float)(2 * TOKS));
    out_aux[0] = 0.001f * 8.f * a;
  }
}

extern "C" void kernel_launch(void* const* d_in, const int* in_sizes, int n_in,
                              void* d_out, int out_size, void* d_ws, size_t ws_size,
                              hipStream_t stream) {
  const float* x   = (const float*)d_in[0];
  const float* rw  = (const float*)d_in[1];
  const float* rb  = (const float*)d_in[2];
  const float* Wd  = (const float*)d_in[3];
  const float* Wu  = (const float*)d_in[4];
  const int* key_id = (const int*)d_in[5];
  float* out = (float*)d_out;

  char* ws = (char*)d_ws;
  int*    cnt      = (int*)ws;                    // 2 KB  (16 x 128B)
  int*    cnt_pair = (int*)(ws + 2048);           // 8 KB  (64 x 128B)
  int*    totals   = (int*)(ws + 10240);          // 8 B
  float*  imp_part = (float*)(ws + 16384);        // 32 KB
  int*    dplan    = (int*)(ws + 49152);          // ~4.2 KB
  int*    uplan    = (int*)(ws + 57344);          // ~1.3 KB
  int*    list0    = (int*)(ws + 65536);          // 512 KB
  float*  gate0    = (float*)(ws + 65536 + 524288);
  int*    list1    = (int*)(ws + 65536 + 1048576);
  float*  gate1    = (float*)(ws + 65536 + 1572864);
  ushort* wdt      = (ushort*)(ws + 2162688);     // 1 MB
  ushort* wut      = (ushort*)(ws + 3211264);     // 1 MB
  ushort* xb       = (ushort*)(ws + 4259840);     // 32 MB -> 37814272
  float*  rw_p     = (float*)(ws + 37814272);     // 32 KB -> 37847040
  int*    pairlist = (int*)(ws + 37847040);       // 4 MB  -> 42041344
  ushort* Hbuf     = (ushort*)(ws + 42041344);    // 4 MB  -> 46235648

  // Router scratch ALIASES the Hbuf region: fully consumed by scan/scatter
  // before down_kernel writes Hbuf. ~0.85 MB.
  int*    histT = (int*)(ws + 42041344);                // 320 KB
  int*    baseT = (int*)(ws + 42041344 + 327680);       // 320 KB
  int*    pbuf  = (int*)(ws + 42041344 + 655360);       // 64 KB
  float2* ggbuf = (float2*)(ws + 42041344 + 720896);    // 128 KB

  convert_kernel<<<1032, 256, 0, stream>>>(Wd, Wu, rw, key_id, wdt, wut, rw_p);
  router_kernel<<<NBLK_R, 256, 0, stream>>>(x, rw_p, rb, key_id, imp_part,
                                            pbuf, ggbuf, histT, xb);
  scan_kernel<<<80, 256, 0, stream>>>(histT, baseT, cnt, cnt_pair);
  scatter_kernel<<<257, 256, 0, stream>>>(baseT, pbuf, ggbuf, cnt, cnt_pair,
                                          list0, gate0, list1, gate1,
                                          pairlist, dplan, uplan, totals);
  down_kernel<<<DT_MAX, 256, 0, stream>>>(xb, wdt, cnt, list0, gate0,
                                          list1, gate1, dplan, totals, Hbuf);
  up_kernel<<<dim3(UT_MAX, 8), 256, 0, stream>>>(
      Hbuf, wut, cnt_pair, pairlist, uplan, totals, out);
  aux_kernel<<<1, 256, 0, stream>>>(cnt, imp_part, out + (size_t)TOKS * CDIM);
}

// Round 8
// 82.122 us; speedup vs baseline: 1.0661x; 1.0030x over previous
//
#include <hip/hip_runtime.h>
#include <hip/hip_bf16.h>
#include <math.h>

#define TOKS 16384
#define CDIM 1024
#define NEXP 8
#define RDIM 64
#define CAP  TOKS
#define NBLK_R 1024   // router blocks (16 tokens each)
#define DT_MAX 1056   // max down tiles: 32768/32 + 16
#define UT_MAX 320    // max up tiles: 16384/64 + 64

using f32x4   = __attribute__((ext_vector_type(4))) float;
using bf16x8  = __attribute__((ext_vector_type(8))) short;
using ushort8 = __attribute__((ext_vector_type(8))) unsigned short;

__device__ __forceinline__ ushort f2bf(float f) {
  unsigned u = __builtin_bit_cast(unsigned, f);
  u += 0x7fffu + ((u >> 16) & 1u);   // round-to-nearest-even
  return (ushort)(u >> 16);
}

// async global->LDS DMA, 16B/lane; LDS dest = wave-uniform base + lane*16.
__device__ __forceinline__ void async16(const ushort* g, ushort* l) {
  __builtin_amdgcn_global_load_lds(
      (const __attribute__((address_space(1))) void*)g,
      (__attribute__((address_space(3))) void*)l, 16, 0, 0);
}

// ---- pre-pass: rw permute; Wd -> wdt[e][s][64r][64k] tiles PRE-SWIZZLED so
//      a linear global_load_lds lands in the XOR-swizzled LDS layout;
//      Wu -> wut[e][n0][128c][64r] tiles, same pre-swizzle. (verified r4/r5)
__global__ __launch_bounds__(256) void convert_kernel(
    const float* __restrict__ Wd, const float* __restrict__ Wu,
    const float* __restrict__ rw_all, const int* __restrict__ key_id,
    ushort* __restrict__ wdt, ushort* __restrict__ wut,
    float* __restrict__ rw_p) {
  const int t = blockIdx.x * 256 + threadIdx.x;
  if (t < 2048) {              // rw_p: one float4 per thread
    const int st = t >> 7, rem = t & 127;
    const int h = rem >> 6, l = rem & 63;
    const int C = (st >> 2) * 256 + l * 4 + (st & 3);
    const float4 v = *(const float4*)(rw_all + (size_t)key_id[0] * CDIM * NEXP
                                      + C * 8 + h * 4);
    ((float4*)rw_p)[t] = v;
  } else if (t < 133120) {     // Wd -> tile (e,s): [64 r][64 k], swizzled
    const int u = t - 2048;
    const int k4 = u & 255, r = (u >> 8) & 63, e = u >> 14;
    ushort4 h4;
    h4.x = f2bf(Wd[(size_t)(e * 1024 + k4 * 4 + 0) * 64 + r]);
    h4.y = f2bf(Wd[(size_t)(e * 1024 + k4 * 4 + 1) * 64 + r]);
    h4.z = f2bf(Wd[(size_t)(e * 1024 + k4 * 4 + 2) * 64 + r]);
    h4.w = f2bf(Wd[(size_t)(e * 1024 + k4 * 4 + 3) * 64 + r]);
    const int s = k4 >> 4;           // k-block (64-wide)
    const int kq4 = k4 & 15;         // ushort4 granule within row
    const int g = kq4 >> 1, hh = kq4 & 1;
    const int gs = g ^ (r & 7);      // pre-swizzle 8-ushort granule
    ((ushort4*)wdt)[((e * 16 + s) * 64 + r) * 16 + gs * 2 + hh] = h4;
  } else {                     // Wu -> tile (e,n0): [128 c][64 r], swizzled
    const int u = t - 133120;
    const int r4 = u & 15, c = (u >> 4) & 1023, e = u >> 14;
    ushort4 h4;
    h4.x = f2bf(Wu[(size_t)(e * 64 + r4 * 4 + 0) * 1024 + c]);
    h4.y = f2bf(Wu[(size_t)(e * 64 + r4 * 4 + 1) * 1024 + c]);
    h4.z = f2bf(Wu[(size_t)(e * 64 + r4 * 4 + 2) * 1024 + c]);
    h4.w = f2bf(Wu[(size_t)(e * 64 + r4 * 4 + 3) * 1024 + c]);
    const int n0 = c >> 7, cc = c & 127;
    const int g = r4 >> 1, hh = r4 & 1;
    const int gs = g ^ (cc & 7);
    ((ushort4*)wut)[((e * 8 + n0) * 128 + cc) * 16 + gs * 2 + hh] = h4;
  }
}

// ---------------- router: wave = token; NO global atomics ------------------
__global__ __launch_bounds__(256) void router_kernel(
    const float* __restrict__ x, const float* __restrict__ rw_p,
    const float* __restrict__ rb_all, const int* __restrict__ key_id,
    float* __restrict__ imp_part,
    int* __restrict__ pbuf, float2* __restrict__ ggbuf,
    int* __restrict__ histT, ushort* __restrict__ xb) {
  __shared__ float s_imp[4][NEXP];
  __shared__ int   s_pb[16];
  __shared__ float s_g1[16], s_g2[16];
  const int tid = threadIdx.x;
  const int lane = tid & 63;
  const int wave = tid >> 6;
  const int kid = key_id[0];
  const float4* rwp4 = (const float4*)rw_p;
  const float* rb = rb_all + (size_t)kid * NEXP;
  const int eln = ((lane & 1) << 2) | (lane & 2) | ((lane >> 2) & 1);
  const float rbe = rb[eln];
  float impacc = 0.f;

  const int wg = blockIdx.x * 4 + wave;
#pragma unroll 1
  for (int tt = 0; tt < 4; ++tt) {
    const int token = wg * 4 + tt;
    const float* xr = x + (size_t)token * CDIM + lane * 4;
    float4 xv[4];
#pragma unroll
    for (int j = 0; j < 4; ++j) xv[j] = *(const float4*)(xr + j * 256);
    ushort* xo = xb + (size_t)token * CDIM + lane * 4;
#pragma unroll
    for (int j = 0; j < 4; ++j) {
      ushort4 h;
      h.x = f2bf(xv[j].x); h.y = f2bf(xv[j].y);
      h.z = f2bf(xv[j].z); h.w = f2bf(xv[j].w);
      *(ushort4*)(xo + j * 256) = h;
    }
    float acc[8];
#pragma unroll
    for (int e = 0; e < 8; ++e) acc[e] = 0.f;
#pragma unroll
    for (int j = 0; j < 4; ++j) {
#pragma unroll
      for (int i = 0; i < 4; ++i) {
        const int st = j * 4 + i;
        const float4 wA = rwp4[st * 128 + lane];
        const float4 wB = rwp4[st * 128 + 64 + lane];
        const float xi = (&xv[j].x)[i];
        acc[0] = fmaf(xi, wA.x, acc[0]);
        acc[1] = fmaf(xi, wA.y, acc[1]);
        acc[2] = fmaf(xi, wA.z, acc[2]);
        acc[3] = fmaf(xi, wA.w, acc[3]);
        acc[4] = fmaf(xi, wB.x, acc[4]);
        acc[5] = fmaf(xi, wB.y, acc[5]);
        acc[6] = fmaf(xi, wB.z, acc[6]);
        acc[7] = fmaf(xi, wB.w, acc[7]);
      }
    }
    // butterfly 8 accs -> 1 (expert = bitrev3(lane&7)), then 64-lane sum
#pragma unroll
    for (int i = 0; i < 4; ++i) {
      const float send = (lane & 1) ? acc[i] : acc[i + 4];
      const float recv = __shfl_xor(send, 1);
      acc[i] = ((lane & 1) ? acc[i + 4] : acc[i]) + recv;
    }
#pragma unroll
    for (int i = 0; i < 2; ++i) {
      const float send = (lane & 2) ? acc[i] : acc[i + 2];
      const float recv = __shfl_xor(send, 2);
      acc[i] = ((lane & 2) ? acc[i + 2] : acc[i]) + recv;
    }
    {
      const float send = (lane & 4) ? acc[0] : acc[1];
      const float recv = __shfl_xor(send, 4);
      acc[0] = ((lane & 4) ? acc[1] : acc[0]) + recv;
    }
    float v = acc[0];
    v += __shfl_xor(v, 8); v += __shfl_xor(v, 16); v += __shfl_xor(v, 32);

    const float logit = v + rbe;
    float mx = logit;
    mx = fmaxf(mx, __shfl_xor(mx, 1));
    mx = fmaxf(mx, __shfl_xor(mx, 2));
    mx = fmaxf(mx, __shfl_xor(mx, 4));
    const float ex = expf(logit - mx);
    float sm = ex;
    sm += __shfl_xor(sm, 1); sm += __shfl_xor(sm, 2); sm += __shfl_xor(sm, 4);
    const float p = ex / sm;
    float bv = p; int bi = eln;
#pragma unroll
    for (int mk = 1; mk <= 4; mk <<= 1) {
      const float ov = __shfl_xor(bv, mk);
      const int oi = __shfl_xor(bi, mk);
      if (ov > bv || (ov == bv && oi < bi)) { bv = ov; bi = oi; }
    }
    const int e1 = bi; const float v1 = bv;
    float cv = (eln == e1) ? -1.f : p; int ci = eln;
#pragma unroll
    for (int mk = 1; mk <= 4; mk <<= 1) {
      const float ov = __shfl_xor(cv, mk);
      const int oi = __shfl_xor(ci, mk);
      if (ov > cv || (ov == cv && oi < ci)) { cv = ov; ci = oi; }
    }
    const int e2 = ci; const float v2 = cv;

    if (lane == 0) {
      const float gs = 1.f / (v1 + v2);
      const int li = wave * 4 + tt;
      s_g1[li] = v1 * gs;
      s_g2[li] = v2 * gs;
      s_pb[li] = e1 * 8 + e2;
    }
    impacc += p;
  }
  if (lane < 8) s_imp[wave][eln] = impacc;
  __syncthreads();
  if (tid < 8)
    imp_part[blockIdx.x * 8 + tid] =
        s_imp[0][tid] + s_imp[1][tid] + s_imp[2][tid] + s_imp[3][tid];

  // per-token records (coalesced, block-contiguous)
  if (tid < 16) {
    pbuf[blockIdx.x * 16 + tid] = s_pb[tid];
    ggbuf[blockIdx.x * 16 + tid] = make_float2(s_g1[tid], s_g2[tid]);
  }
  // transposed histograms: histT[c*1024 + blk], c in [0,80)
  if (tid < 80) {
    int c = 0;
    if (tid < 16) {
      const int k = tid >> 3, e = tid & 7;
#pragma unroll
      for (int j = 0; j < 16; ++j)
        c += ((k ? (s_pb[j] & 7) : (s_pb[j] >> 3)) == e) ? 1 : 0;
    } else {
      const int b = tid - 16;
#pragma unroll
      for (int j = 0; j < 16; ++j) c += (s_pb[j] == b) ? 1 : 0;
    }
    histT[tid * 1024 + blockIdx.x] = c;
  }
}

// -------- scan: one block per counter, parallel prefix over 1024 blocks ----
__global__ __launch_bounds__(256) void scan_kernel(
    const int* __restrict__ histT, int* __restrict__ baseT,
    int* __restrict__ cnt, int* __restrict__ cnt_pair) {
  __shared__ int ls[256];
  const int c = blockIdx.x;
  const int t = threadIdx.x;
  const int4 v = ((const int4*)(histT + (c << 10)))[t];
  const int s = v.x + v.y + v.z + v.w;
  ls[t] = s;
  __syncthreads();
#pragma unroll
  for (int off = 1; off < 256; off <<= 1) {
    const int add = (t >= off) ? ls[t - off] : 0;
    __syncthreads();
    ls[t] += add;
    __syncthreads();
  }
  const int incl = ls[t];
  const int excl = incl - s;
  int4 b;
  b.x = excl;
  b.y = excl + v.x;
  b.z = excl + v.x + v.y;
  b.w = excl + v.x + v.y + v.z;
  ((int4*)(baseT + (c << 10)))[t] = b;
  if (t == 255) {
    if (c < 16) cnt[c * 32] = incl;
    else        cnt_pair[(c - 16) * 32] = incl;
  }
}

// -------- scatter (blocks 0..255: lists+pairs) + plan (block 256) ----------
__global__ __launch_bounds__(256) void scatter_kernel(
    const int* __restrict__ baseT, const int* __restrict__ pbuf,
    const float2* __restrict__ ggbuf,
    const int* __restrict__ cnt, const int* __restrict__ cnt_pair,
    int* __restrict__ list0, float* __restrict__ gate0,
    int* __restrict__ list1, float* __restrict__ gate1,
    int* __restrict__ pairlist,
    int* __restrict__ dplan, int* __restrict__ uplan,
    int* __restrict__ totals) {
  if (blockIdx.x == 256) {   // plan: 32-tok down tiles, 64-tok up tiles
    __shared__ int doff[16], uoff[64];
    const int t = threadIdx.x;
    if (t == 0) {
      int a = 0;
      for (int y = 0; y < 16; ++y) { doff[y] = a; a += (cnt[y * 32] + 31) >> 5; }
      totals[0] = a;
      a = 0;
      for (int b2 = 0; b2 < 64; ++b2) { uoff[b2] = a; a += (cnt_pair[b2 * 32] + 63) >> 6; }
      totals[1] = a;
    }
    __syncthreads();
    if (t < 16) {
      const int nd = (cnt[t * 32] + 31) >> 5;
      for (int i = 0; i < nd; ++i) dplan[doff[t] + i] = (t << 16) | i;
    }
    if (t < 64) {
      const int nu = (cnt_pair[t * 32] + 63) >> 6;
      for (int i = 0; i < nu; ++i) uplan[uoff[t] + i] = (t << 16) | i;
    }
    return;
  }
  const int tid = threadIdx.x;
  const int lane = tid & 63;
  const int wave = tid >> 6;
  const int rb = blockIdx.x * 4 + wave;   // router block, 0..1023
  const int i = lane;
  int pb = 0; float2 gg = make_float2(0.f, 0.f);
  if (lane < 16) { pb = pbuf[rb * 16 + lane]; gg = ggbuf[rb * 16 + lane]; }
  const int e1 = pb >> 3, e2 = pb & 7;
  int r0 = 0, r1 = 0, rp = 0;
#pragma unroll
  for (int j = 0; j < 15; ++j) {
    const int q = __shfl(pb, j);
    if (j < i) {
      r0 += ((q >> 3) == e1) ? 1 : 0;
      r1 += ((q & 7) == e2) ? 1 : 0;
      rp += (q == pb) ? 1 : 0;
    }
  }
  if (lane < 16) {
    const int token = rb * 16 + i;
    const int s0 = baseT[(e1 << 10) + rb] + r0;
    list0[e1 * CAP + s0] = token;
    gate0[e1 * CAP + s0] = gg.x;
    const int s1 = baseT[((8 + e2) << 10) + rb] + r1;
    list1[e2 * CAP + s1] = token;
    gate1[e2 * CAP + s1] = gg.y;
    const int sp = baseT[((16 + pb) << 10) + rb] + rp;
    pairlist[pb * CAP + sp] = token;
  }
}

// ---- down: H[k][tok] = GELU(x@Wd_e)*gate, 32-tok x 64-r tiles -------------
// T3/T4: double-buffered global_load_lds with counted vmcnt(3) — next tile's
// DMAs stay in flight across the whole MFMA phase. LDS 28.5KB -> 5 blocks/CU.
__global__ __launch_bounds__(256) void down_kernel(
    const ushort* __restrict__ xb, const ushort* __restrict__ wdt,
    const int* __restrict__ cnt,
    const int* __restrict__ list0, const float* __restrict__ gate0,
    const int* __restrict__ list1, const float* __restrict__ gate1,
    const int* __restrict__ dplan, const int* __restrict__ totals,
    ushort* __restrict__ Hbuf) {
  if (blockIdx.x >= totals[0]) return;
  const int ent = dplan[blockIdx.x];
  const int y = ent >> 16, tile = ent & 0xffff;
  const int k = y >> 3, e = y & 7;
  const int n = cnt[y * 32];
  const int start = tile * 32;
  const int* list = k ? list1 : list0;
  const float* gate = k ? gate1 : gate0;

  __shared__ __align__(16) char smem[29184];
  ushort* As0 = (ushort*)(smem);             // 4 KB (32x64)
  ushort* As1 = (ushort*)(smem + 4096);      // 4 KB
  ushort* Bs0 = (ushort*)(smem + 8192);      // 8 KB (64x64)
  ushort* Bs1 = (ushort*)(smem + 16384);     // 8 KB
  ushort* Hs  = (ushort*)(smem + 24576);     // 4 KB (32x64)
  int*  toks  = (int*)(smem + 28672);        // 128 B
  float*  gs  = (float*)(smem + 28800);      // 128 B

  const int tid = threadIdx.x;
  const int lane = tid & 63;
  const int w = tid >> 6;

  if (tid < 32) {
    int tk = -1; float g = 0.f;
    if (start + tid < n) {
      tk = list[e * CAP + start + tid];
      g = gate[e * CAP + start + tid];
    }
    toks[tid] = tk; gs[tid] = g;
  }
  __syncthreads();

  // DMA geometry: 1KB batch = 8 rows x 128B; lane covers row lane>>3,
  // 16B chunk (lane&7). xb source col pre-swizzled (rule #21).
  const int rsub = lane >> 3;
  const int csw = ((lane & 7) * 8) ^ (rsub << 3);
  const int arow = w * 8 + rsub;
  const int tkA = toks[arow];
  const ushort* srcA = xb + (size_t)(tkA < 0 ? 0 : tkA) * CDIM + csw;
  const ushort* wde = wdt + ((size_t)e << 16);      // 16 tiles x 4096 ushorts
  const ushort* srcB0 = wde + (w * 16 + 0) * 64 + lane * 8;
  const ushort* srcB1 = wde + (w * 16 + 8) * 64 + lane * 8;
  ushort* dA0  = As0 + w * 512;
  ushort* dA1  = As1 + w * 512;
  ushort* dB0a = Bs0 + (w * 16) * 64;
  ushort* dB0b = Bs0 + (w * 16 + 8) * 64;
  ushort* dB1a = Bs1 + (w * 16) * 64;
  ushort* dB1b = Bs1 + (w * 16 + 8) * 64;

  f32x4 acc[2];
  acc[0] = (f32x4){0.f, 0.f, 0.f, 0.f};
  acc[1] = (f32x4){0.f, 0.f, 0.f, 0.f};

  // prologue: tile 0 -> buf0
  async16(srcA, dA0);
  async16(srcB0, dB0a);
  async16(srcB1, dB0b);

#pragma unroll 1
  for (int s = 0; s < 16; ++s) {
    if (s < 15) {                       // prefetch tile s+1 -> other buffer
      const int k1 = (s + 1) * 64;
      if (s & 1) {
        async16(srcA + k1, dA0);
        async16(srcB0 + (s + 1) * 4096, dB0a);
        async16(srcB1 + (s + 1) * 4096, dB0b);
      } else {
        async16(srcA + k1, dA1);
        async16(srcB0 + (s + 1) * 4096, dB1a);
        async16(srcB1 + (s + 1) * 4096, dB1b);
      }
      asm volatile("s_waitcnt vmcnt(3)" ::: "memory");   // tile s landed
    } else {
      asm volatile("s_waitcnt vmcnt(0)" ::: "memory");
    }
    __builtin_amdgcn_s_barrier();
    __builtin_amdgcn_sched_barrier(0);  // keep ds_reads below the barrier
    const ushort* Asr = (s & 1) ? As1 : As0;
    const ushort* Bsr = (s & 1) ? Bs1 : Bs0;
#pragma unroll
    for (int kk = 0; kk < 64; kk += 32) {
      const int kb = kk + (lane >> 4) * 8;
      bf16x8 a[2], bb;
#pragma unroll
      for (int m = 0; m < 2; ++m) {
        const int row = m * 16 + (lane & 15);
        a[m] = *(const bf16x8*)&Asr[row * 64 + (kb ^ ((row & 7) << 3))];
      }
      {
        const int r = w * 16 + (lane & 15);
        bb = *(const bf16x8*)&Bsr[r * 64 + (kb ^ ((r & 7) << 3))];
      }
#pragma unroll
      for (int m = 0; m < 2; ++m)
        acc[m] = __builtin_amdgcn_mfma_f32_16x16x32_bf16(a[m], bb, acc[m], 0, 0, 0);
    }
    __builtin_amdgcn_sched_barrier(0);  // keep reads above trailing barrier
    __builtin_amdgcn_s_barrier();       // buffer safe to overwrite next iter
  }

  // epilogue: GELU*gate -> Hs (each wave owns its 16-col slice)
#pragma unroll
  for (int m = 0; m < 2; ++m)
#pragma unroll
    for (int q = 0; q < 4; ++q) {
      const int slot = m * 16 + (lane >> 4) * 4 + q;
      const int r = w * 16 + (lane & 15);
      const float v = acc[m][q];
      const float ge = 0.5f * v * (1.f + erff(v * 0.70710678118654752f));
      Hs[slot * 64 + (r ^ ((slot & 7) << 3))] = f2bf(ge * gs[slot]);
    }
  __syncthreads();
  // Hs -> Hbuf[(k<<14)+tok][64] (linear rows)
  {
    const int row = tid >> 3, c8 = (tid & 7) * 8;
    const int tk = toks[row];
    if (tk >= 0) {
      *(ushort8*)(Hbuf + ((size_t)((k << 14) + tk)) * 64 + c8) =
          *(const ushort8*)&Hs[row * 64 + (c8 ^ ((row & 7) << 3))];
    }
  }
}

// ---- up: out[t] = H0[t]@Wu_ea + H1[t]@Wu_eb, 64-tok x 128-col slices ------
// Single sync point: DMA BuA+BuB up front (pre-swizzled wut), reg-gather A
// under the DMA latency, one __syncthreads, then 32 MFMAs + stores.
// Block x==UT_MAX runs the aux reduction (folded kernel).
__global__ __launch_bounds__(256) void up_kernel(
    const ushort* __restrict__ Hbuf, const ushort* __restrict__ wut,
    const int* __restrict__ cnt_pair, const int* __restrict__ pairlist,
    const int* __restrict__ uplan, const int* __restrict__ totals,
    const int* __restrict__ cnt, const float* __restrict__ imp_part,
    float* __restrict__ out) {
  __shared__ __align__(16) char smem[49408];
  if (blockIdx.x == UT_MAX) {          // aux block (y==0 only)
    if (blockIdx.y != 0) return;
    float* red = (float*)smem;
    float* tot = (float*)(smem + 1024);
    const int t = threadIdx.x;
    const int e = t & 7, b0 = t >> 3;
    float s = 0.f;
    for (int j = 0; j < NBLK_R / 32; ++j)
      s += imp_part[(b0 + 32 * j) * 8 + e];
    red[t] = s;
    __syncthreads();
    if (t < 8) {
      float tt = 0.f;
      for (int ww = 0; ww < 32; ++ww) tt += red[ww * 8 + t];
      tot[t] = tt;
    }
    __syncthreads();
    if (t == 0) {
      float a = 0.f;
#pragma unroll
      for (int ee = 0; ee < NEXP; ++ee)
        a += (tot[ee] / (float)TOKS) *
             ((float)(cnt[ee * 32] + cnt[(NEXP + ee) * 32]) / (float)(2 * TOKS));
      out[(size_t)TOKS * CDIM] = 0.001f * 8.f * a;
    }
    return;
  }
  if (blockIdx.x >= totals[1]) return;
  const int ent = uplan[blockIdx.x];
  const int b = ent >> 16, tile = ent & 0xffff;
  const int ea = b >> 3, eb = b & 7;
  const int n = cnt_pair[b * 32];
  const int start = tile * 64;
  const int n0 = blockIdx.y;   // 0..7

  ushort* A0  = (ushort*)(smem);            // 8 KB (64x64)
  ushort* A1  = (ushort*)(smem + 8192);     // 8 KB
  ushort* BuA = (ushort*)(smem + 16384);    // 16 KB (128x64)
  ushort* BuB = (ushort*)(smem + 32768);    // 16 KB
  int*  toks  = (int*)(smem + 49152);       // 256 B

  const int tid = threadIdx.x;
  const int lane = tid & 63;
  const int w = tid >> 6;
  const int wr = w >> 1, wc = w & 1;

  if (tid < 64) {
    int tk = -1;
    if (start + tid < n) tk = pairlist[b * CAP + start + tid];
    toks[tid] = tk;
  }
  __syncthreads();
  // DMA both weight tiles (4 x 1KB batches per wave per buffer)
  {
    const ushort* tA = wut + ((size_t)(ea * 8 + n0)) * 8192 + (w * 4) * 512 + lane * 8;
    const ushort* tB = wut + ((size_t)(eb * 8 + n0)) * 8192 + (w * 4) * 512 + lane * 8;
    ushort* dA = BuA + (w * 4) * 512;
    ushort* dB = BuB + (w * 4) * 512;
#pragma unroll
    for (int j = 0; j < 4; ++j) {
      async16(tA + j * 512, dA + j * 512);
      async16(tB + j * 512, dB + j * 512);
    }
  }
  // reg-gather H0/H1 rows (DMA latency hides under these load-use chains)
#pragma unroll
  for (int i = 0; i < 2; ++i) {
    const int sc = tid + i * 256;
    const int row = sc >> 3, c8 = (sc & 7) * 8;
    const int tk = toks[row];
    const int tkc = tk < 0 ? 0 : tk;
    const ushort8 v0 = *(const ushort8*)(Hbuf + (size_t)tkc * 64 + c8);
    const ushort8 v1 = *(const ushort8*)(Hbuf + ((size_t)TOKS + tkc) * 64 + c8);
    *(ushort8*)&A0[row * 64 + (c8 ^ ((row & 7) << 3))] = v0;
    *(ushort8*)&A1[row * 64 + (c8 ^ ((row & 7) << 3))] = v1;
  }
  __syncthreads();   // single full drain: DMAs + gathers visible

  f32x4 uac[2][4];
#pragma unroll
  for (int m = 0; m < 2; ++m)
#pragma unroll
    for (int nn = 0; nn < 4; ++nn) uac[m][nn] = (f32x4){0.f, 0.f, 0.f, 0.f};

  // pass A: H0 @ Wu_ea
#pragma unroll
  for (int kk = 0; kk < 64; kk += 32) {
    const int kb = kk + (lane >> 4) * 8;
    bf16x8 a[2], bbv[4];
#pragma unroll
    for (int m = 0; m < 2; ++m) {
      const int row = wr * 32 + m * 16 + (lane & 15);
      a[m] = *(const bf16x8*)&A0[row * 64 + (kb ^ ((row & 7) << 3))];
    }
#pragma unroll
    for (int nn = 0; nn < 4; ++nn) {
      const int c = wc * 64 + nn * 16 + (lane & 15);
      bbv[nn] = *(const bf16x8*)&BuA[c * 64 + (kb ^ ((c & 7) << 3))];
    }
#pragma unroll
    for (int m = 0; m < 2; ++m)
#pragma unroll
      for (int nn = 0; nn < 4; ++nn)
        uac[m][nn] = __builtin_amdgcn_mfma_f32_16x16x32_bf16(a[m], bbv[nn], uac[m][nn], 0, 0, 0);
  }
  // pass B: H1 @ Wu_eb (accumulate; separate buffer, no barrier needed)
#pragma unroll
  for (int kk = 0; kk < 64; kk += 32) {
    const int kb = kk + (lane >> 4) * 8;
    bf16x8 a[2], bbv[4];
#pragma unroll
    for (int m = 0; m < 2; ++m) {
      const int row = wr * 32 + m * 16 + (lane & 15);
      a[m] = *(const bf16x8*)&A1[row * 64 + (kb ^ ((row & 7) << 3))];
    }
#pragma unroll
    for (int nn = 0; nn < 4; ++nn) {
      const int c = wc * 64 + nn * 16 + (lane & 15);
      bbv[nn] = *(const bf16x8*)&BuB[c * 64 + (kb ^ ((c & 7) << 3))];
    }
#pragma unroll
    for (int m = 0; m < 2; ++m)
#pragma unroll
      for (int nn = 0; nn < 4; ++nn)
        uac[m][nn] = __builtin_amdgcn_mfma_f32_16x16x32_bf16(a[m], bbv[nn], uac[m][nn], 0, 0, 0);
  }
  // store this 128-col slice (each token row owned by exactly one bucket)
#pragma unroll
  for (int m = 0; m < 2; ++m)
#pragma unroll
    for (int q = 0; q < 4; ++q) {
      const int slot = wr * 32 + m * 16 + (lane >> 4) * 4 + q;
      const int tk = toks[slot];
      if (tk >= 0) {
        float* orow = out + (size_t)tk * CDIM + n0 * 128 + wc * 64 + (lane & 15);
#pragma unroll
        for (int nn = 0; nn < 4; ++nn) orow[nn * 16] = uac[m][nn][q];
      }
    }
}

extern "C" void kernel_launch(void* const* d_in, const int* in_sizes, int n_in,
                              void* d_out, int out_size, void* d_ws, size_t ws_size,
                              hipStream_t stream) {
  const float* x   = (const float*)d_in[0];
  const float* rw  = (const float*)d_in[1];
  const float* rb  = (const float*)d_in[2];
  const float* Wd  = (const float*)d_in[3];
  const float* Wu  = (const float*)d_in[4];
  const int* key_id = (const int*)d_in[5];
  float* out = (float*)d_out;

  char* ws = (char*)d_ws;
  int*    cnt      = (int*)ws;                    // 2 KB  (16 x 128B)
  int*    cnt_pair = (int*)(ws + 2048);           // 8 KB  (64 x 128B)
  int*    totals   = (int*)(ws + 10240);          // 8 B
  float*  imp_part = (float*)(ws + 16384);        // 32 KB
  int*    dplan    = (int*)(ws + 49152);          // ~4.2 KB
  int*    uplan    = (int*)(ws + 57344);          // ~1.3 KB
  int*    list0    = (int*)(ws + 65536);          // 512 KB
  float*  gate0    = (float*)(ws + 65536 + 524288);
  int*    list1    = (int*)(ws + 65536 + 1048576);
  float*  gate1    = (float*)(ws + 65536 + 1572864);
  ushort* wdt      = (ushort*)(ws + 2162688);     // 1 MB
  ushort* wut      = (ushort*)(ws + 3211264);     // 1 MB
  ushort* xb       = (ushort*)(ws + 4259840);     // 32 MB -> 37814272
  float*  rw_p     = (float*)(ws + 37814272);     // 32 KB -> 37847040
  int*    pairlist = (int*)(ws + 37847040);       // 4 MB  -> 42041344
  ushort* Hbuf     = (ushort*)(ws + 42041344);    // 4 MB  -> 46235648

  // Router scratch ALIASES the Hbuf region: fully consumed by scan/scatter
  // before down_kernel writes Hbuf. ~0.85 MB.
  int*    histT = (int*)(ws + 42041344);                // 320 KB
  int*    baseT = (int*)(ws + 42041344 + 327680);       // 320 KB
  int*    pbuf  = (int*)(ws + 42041344 + 655360);       // 64 KB
  float2* ggbuf = (float2*)(ws + 42041344 + 720896);    // 128 KB

  convert_kernel<<<1032, 256, 0, stream>>>(Wd, Wu, rw, key_id, wdt, wut, rw_p);
  router_kernel<<<NBLK_R, 256, 0, stream>>>(x, rw_p, rb, key_id, imp_part,
                                            pbuf, ggbuf, histT, xb);
  scan_kernel<<<80, 256, 0, stream>>>(histT, baseT, cnt, cnt_pair);
  scatter_kernel<<<257, 256, 0, stream>>>(baseT, pbuf, ggbuf, cnt, cnt_pair,
                                          list0, gate0, list1, gate1,
                                          pairlist, dplan, uplan, totals);
  down_kernel<<<DT_MAX, 256, 0, stream>>>(xb, wdt, cnt, list0, gate0,
                                          list1, gate1, dplan, totals, Hbuf);
  up_kernel<<<dim3(UT_MAX + 1, 8), 256, 0, stream>>>(
      Hbuf, wut, cnt_pair, pairlist, uplan, totals, cnt, imp_part, out);
}

// Round 9
// 79.154 us; speedup vs baseline: 1.1060x; 1.0375x over previous
//
#include <hip/hip_runtime.h>
#include <hip/hip_bf16.h>
#include <math.h>

#define TOKS 16384
#define CDIM 1024
#define NEXP 8
#define RDIM 64
#define CAP  TOKS
#define NBLK_R 1024   // router blocks (16 tokens each)
#define DT_MAX 528    // max down tiles: 32768/64 + 16
#define UT_MAX 320    // max up tiles: 16384/64 + 64

using f32x4   = __attribute__((ext_vector_type(4))) float;
using bf16x8  = __attribute__((ext_vector_type(8))) short;
using ushort8 = __attribute__((ext_vector_type(8))) unsigned short;

__device__ __forceinline__ ushort f2bf(float f) {
  unsigned u = __builtin_bit_cast(unsigned, f);
  u += 0x7fffu + ((u >> 16) & 1u);   // round-to-nearest-even
  return (ushort)(u >> 16);
}

// ---- pre-pass: rw permute; Wd -> wdt[e][s][64r][64k] tiles PRE-SWIZZLED
//      (granule g at position g^(row&7)); Wu -> wut[e][n0][128c][64r] same.
//      A LINEAR copy of these tiles into LDS + swizzled ds_read yields the
//      bank-conflict-free layout (verified r5/r7/r8 correctness).
__global__ __launch_bounds__(256) void convert_kernel(
    const float* __restrict__ Wd, const float* __restrict__ Wu,
    const float* __restrict__ rw_all, const int* __restrict__ key_id,
    ushort* __restrict__ wdt, ushort* __restrict__ wut,
    float* __restrict__ rw_p) {
  const int t = blockIdx.x * 256 + threadIdx.x;
  if (t < 2048) {              // rw_p: one float4 per thread
    const int st = t >> 7, rem = t & 127;
    const int h = rem >> 6, l = rem & 63;
    const int C = (st >> 2) * 256 + l * 4 + (st & 3);
    const float4 v = *(const float4*)(rw_all + (size_t)key_id[0] * CDIM * NEXP
                                      + C * 8 + h * 4);
    ((float4*)rw_p)[t] = v;
  } else if (t < 133120) {     // Wd -> tile (e,s): [64 r][64 k], swizzled
    const int u = t - 2048;
    const int k4 = u & 255, r = (u >> 8) & 63, e = u >> 14;
    ushort4 h4;
    h4.x = f2bf(Wd[(size_t)(e * 1024 + k4 * 4 + 0) * 64 + r]);
    h4.y = f2bf(Wd[(size_t)(e * 1024 + k4 * 4 + 1) * 64 + r]);
    h4.z = f2bf(Wd[(size_t)(e * 1024 + k4 * 4 + 2) * 64 + r]);
    h4.w = f2bf(Wd[(size_t)(e * 1024 + k4 * 4 + 3) * 64 + r]);
    const int s = k4 >> 4;           // k-block (64-wide)
    const int kq4 = k4 & 15;         // ushort4 granule within row
    const int g = kq4 >> 1, hh = kq4 & 1;
    const int gs = g ^ (r & 7);      // pre-swizzle 8-ushort granule
    ((ushort4*)wdt)[((e * 16 + s) * 64 + r) * 16 + gs * 2 + hh] = h4;
  } else {                     // Wu -> tile (e,n0): [128 c][64 r], swizzled
    const int u = t - 133120;
    const int r4 = u & 15, c = (u >> 4) & 1023, e = u >> 14;
    ushort4 h4;
    h4.x = f2bf(Wu[(size_t)(e * 64 + r4 * 4 + 0) * 1024 + c]);
    h4.y = f2bf(Wu[(size_t)(e * 64 + r4 * 4 + 1) * 1024 + c]);
    h4.z = f2bf(Wu[(size_t)(e * 64 + r4 * 4 + 2) * 1024 + c]);
    h4.w = f2bf(Wu[(size_t)(e * 64 + r4 * 4 + 3) * 1024 + c]);
    const int n0 = c >> 7, cc = c & 127;
    const int g = r4 >> 1, hh = r4 & 1;
    const int gs = g ^ (cc & 7);
    ((ushort4*)wut)[((e * 8 + n0) * 128 + cc) * 16 + gs * 2 + hh] = h4;
  }
}

// ---------------- router: wave = token; NO global atomics ------------------
__global__ __launch_bounds__(256) void router_kernel(
    const float* __restrict__ x, const float* __restrict__ rw_p,
    const float* __restrict__ rb_all, const int* __restrict__ key_id,
    float* __restrict__ imp_part,
    int* __restrict__ pbuf, float2* __restrict__ ggbuf,
    int* __restrict__ histT, ushort* __restrict__ xb) {
  __shared__ float s_imp[4][NEXP];
  __shared__ int   s_pb[16];
  __shared__ float s_g1[16], s_g2[16];
  const int tid = threadIdx.x;
  const int lane = tid & 63;
  const int wave = tid >> 6;
  const int kid = key_id[0];
  const float4* rwp4 = (const float4*)rw_p;
  const float* rb = rb_all + (size_t)kid * NEXP;
  const int eln = ((lane & 1) << 2) | (lane & 2) | ((lane >> 2) & 1);
  const float rbe = rb[eln];
  float impacc = 0.f;

  const int wg = blockIdx.x * 4 + wave;
#pragma unroll 1
  for (int tt = 0; tt < 4; ++tt) {
    const int token = wg * 4 + tt;
    const float* xr = x + (size_t)token * CDIM + lane * 4;
    float4 xv[4];
#pragma unroll
    for (int j = 0; j < 4; ++j) xv[j] = *(const float4*)(xr + j * 256);
    ushort* xo = xb + (size_t)token * CDIM + lane * 4;
#pragma unroll
    for (int j = 0; j < 4; ++j) {
      ushort4 h;
      h.x = f2bf(xv[j].x); h.y = f2bf(xv[j].y);
      h.z = f2bf(xv[j].z); h.w = f2bf(xv[j].w);
      *(ushort4*)(xo + j * 256) = h;
    }
    float acc[8];
#pragma unroll
    for (int e = 0; e < 8; ++e) acc[e] = 0.f;
#pragma unroll
    for (int j = 0; j < 4; ++j) {
#pragma unroll
      for (int i = 0; i < 4; ++i) {
        const int st = j * 4 + i;
        const float4 wA = rwp4[st * 128 + lane];
        const float4 wB = rwp4[st * 128 + 64 + lane];
        const float xi = (&xv[j].x)[i];
        acc[0] = fmaf(xi, wA.x, acc[0]);
        acc[1] = fmaf(xi, wA.y, acc[1]);
        acc[2] = fmaf(xi, wA.z, acc[2]);
        acc[3] = fmaf(xi, wA.w, acc[3]);
        acc[4] = fmaf(xi, wB.x, acc[4]);
        acc[5] = fmaf(xi, wB.y, acc[5]);
        acc[6] = fmaf(xi, wB.z, acc[6]);
        acc[7] = fmaf(xi, wB.w, acc[7]);
      }
    }
    // butterfly 8 accs -> 1 (expert = bitrev3(lane&7)), then 64-lane sum
#pragma unroll
    for (int i = 0; i < 4; ++i) {
      const float send = (lane & 1) ? acc[i] : acc[i + 4];
      const float recv = __shfl_xor(send, 1);
      acc[i] = ((lane & 1) ? acc[i + 4] : acc[i]) + recv;
    }
#pragma unroll
    for (int i = 0; i < 2; ++i) {
      const float send = (lane & 2) ? acc[i] : acc[i + 2];
      const float recv = __shfl_xor(send, 2);
      acc[i] = ((lane & 2) ? acc[i + 2] : acc[i]) + recv;
    }
    {
      const float send = (lane & 4) ? acc[0] : acc[1];
      const float recv = __shfl_xor(send, 4);
      acc[0] = ((lane & 4) ? acc[1] : acc[0]) + recv;
    }
    float v = acc[0];
    v += __shfl_xor(v, 8); v += __shfl_xor(v, 16); v += __shfl_xor(v, 32);

    const float logit = v + rbe;
    float mx = logit;
    mx = fmaxf(mx, __shfl_xor(mx, 1));
    mx = fmaxf(mx, __shfl_xor(mx, 2));
    mx = fmaxf(mx, __shfl_xor(mx, 4));
    const float ex = expf(logit - mx);
    float sm = ex;
    sm += __shfl_xor(sm, 1); sm += __shfl_xor(sm, 2); sm += __shfl_xor(sm, 4);
    const float p = ex / sm;
    float bv = p; int bi = eln;
#pragma unroll
    for (int mk = 1; mk <= 4; mk <<= 1) {
      const float ov = __shfl_xor(bv, mk);
      const int oi = __shfl_xor(bi, mk);
      if (ov > bv || (ov == bv && oi < bi)) { bv = ov; bi = oi; }
    }
    const int e1 = bi; const float v1 = bv;
    float cv = (eln == e1) ? -1.f : p; int ci = eln;
#pragma unroll
    for (int mk = 1; mk <= 4; mk <<= 1) {
      const float ov = __shfl_xor(cv, mk);
      const int oi = __shfl_xor(ci, mk);
      if (ov > cv || (ov == cv && oi < ci)) { cv = ov; ci = oi; }
    }
    const int e2 = ci; const float v2 = cv;

    if (lane == 0) {
      const float gs = 1.f / (v1 + v2);
      const int li = wave * 4 + tt;
      s_g1[li] = v1 * gs;
      s_g2[li] = v2 * gs;
      s_pb[li] = e1 * 8 + e2;
    }
    impacc += p;
  }
  if (lane < 8) s_imp[wave][eln] = impacc;
  __syncthreads();
  if (tid < 8)
    imp_part[blockIdx.x * 8 + tid] =
        s_imp[0][tid] + s_imp[1][tid] + s_imp[2][tid] + s_imp[3][tid];

  // per-token records (coalesced, block-contiguous)
  if (tid < 16) {
    pbuf[blockIdx.x * 16 + tid] = s_pb[tid];
    ggbuf[blockIdx.x * 16 + tid] = make_float2(s_g1[tid], s_g2[tid]);
  }
  // transposed histograms: histT[c*1024 + blk], c in [0,80)
  if (tid < 80) {
    int c = 0;
    if (tid < 16) {
      const int k = tid >> 3, e = tid & 7;
#pragma unroll
      for (int j = 0; j < 16; ++j)
        c += ((k ? (s_pb[j] & 7) : (s_pb[j] >> 3)) == e) ? 1 : 0;
    } else {
      const int b = tid - 16;
#pragma unroll
      for (int j = 0; j < 16; ++j) c += (s_pb[j] == b) ? 1 : 0;
    }
    histT[tid * 1024 + blockIdx.x] = c;
  }
}

// -------- scan: one block per counter, parallel prefix over 1024 blocks ----
__global__ __launch_bounds__(256) void scan_kernel(
    const int* __restrict__ histT, int* __restrict__ baseT,
    int* __restrict__ cnt, int* __restrict__ cnt_pair) {
  __shared__ int ls[256];
  const int c = blockIdx.x;
  const int t = threadIdx.x;
  const int4 v = ((const int4*)(histT + (c << 10)))[t];
  const int s = v.x + v.y + v.z + v.w;
  ls[t] = s;
  __syncthreads();
#pragma unroll
  for (int off = 1; off < 256; off <<= 1) {
    const int add = (t >= off) ? ls[t - off] : 0;
    __syncthreads();
    ls[t] += add;
    __syncthreads();
  }
  const int incl = ls[t];
  const int excl = incl - s;
  int4 b;
  b.x = excl;
  b.y = excl + v.x;
  b.z = excl + v.x + v.y;
  b.w = excl + v.x + v.y + v.z;
  ((int4*)(baseT + (c << 10)))[t] = b;
  if (t == 255) {
    if (c < 16) cnt[c * 32] = incl;
    else        cnt_pair[(c - 16) * 32] = incl;
  }
}

// -------- scatter (blocks 0..255: lists+pairs) + plan (block 256) ----------
__global__ __launch_bounds__(256) void scatter_kernel(
    const int* __restrict__ baseT, const int* __restrict__ pbuf,
    const float2* __restrict__ ggbuf,
    const int* __restrict__ cnt, const int* __restrict__ cnt_pair,
    int* __restrict__ list0, float* __restrict__ gate0,
    int* __restrict__ list1, float* __restrict__ gate1,
    int* __restrict__ pairlist,
    int* __restrict__ dplan, int* __restrict__ uplan,
    int* __restrict__ totals) {
  if (blockIdx.x == 256) {   // plan: 64-tok down tiles, 64-tok up tiles
    __shared__ int doff[16], uoff[64];
    const int t = threadIdx.x;
    if (t == 0) {
      int a = 0;
      for (int y = 0; y < 16; ++y) { doff[y] = a; a += (cnt[y * 32] + 63) >> 6; }
      totals[0] = a;
      a = 0;
      for (int b2 = 0; b2 < 64; ++b2) { uoff[b2] = a; a += (cnt_pair[b2 * 32] + 63) >> 6; }
      totals[1] = a;
    }
    __syncthreads();
    if (t < 16) {
      const int nd = (cnt[t * 32] + 63) >> 6;
      for (int i = 0; i < nd; ++i) dplan[doff[t] + i] = (t << 16) | i;
    }
    if (t < 64) {
      const int nu = (cnt_pair[t * 32] + 63) >> 6;
      for (int i = 0; i < nu; ++i) uplan[uoff[t] + i] = (t << 16) | i;
    }
    return;
  }
  const int tid = threadIdx.x;
  const int lane = tid & 63;
  const int wave = tid >> 6;
  const int rb = blockIdx.x * 4 + wave;   // router block, 0..1023
  const int i = lane;
  int pb = 0; float2 gg = make_float2(0.f, 0.f);
  if (lane < 16) { pb = pbuf[rb * 16 + lane]; gg = ggbuf[rb * 16 + lane]; }
  const int e1 = pb >> 3, e2 = pb & 7;
  int r0 = 0, r1 = 0, rp = 0;
#pragma unroll
  for (int j = 0; j < 15; ++j) {
    const int q = __shfl(pb, j);
    if (j < i) {
      r0 += ((q >> 3) == e1) ? 1 : 0;
      r1 += ((q & 7) == e2) ? 1 : 0;
      rp += (q == pb) ? 1 : 0;
    }
  }
  if (lane < 16) {
    const int token = rb * 16 + i;
    const int s0 = baseT[(e1 << 10) + rb] + r0;
    list0[e1 * CAP + s0] = token;
    gate0[e1 * CAP + s0] = gg.x;
    const int s1 = baseT[((8 + e2) << 10) + rb] + r1;
    list1[e2 * CAP + s1] = token;
    gate1[e2 * CAP + s1] = gg.y;
    const int sp = baseT[((16 + pb) << 10) + rb] + rp;
    pairlist[pb * CAP + sp] = token;
  }
}

// ---- down: H[k][tok] = GELU(x@Wd_e)*gate, 64-tok x 64-r tiles -------------
// Reg-prefetch staging; LDS 25KB -> 6 blocks/CU; 528 blocks; weight L2
// traffic halved vs 32-tok tiles; 8 MFMAs/wave/K-step.
__global__ __launch_bounds__(256) void down_kernel(
    const ushort* __restrict__ xb, const ushort* __restrict__ wdt,
    const int* __restrict__ cnt,
    const int* __restrict__ list0, const float* __restrict__ gate0,
    const int* __restrict__ list1, const float* __restrict__ gate1,
    const int* __restrict__ dplan, const int* __restrict__ totals,
    ushort* __restrict__ Hbuf) {
  if (blockIdx.x >= totals[0]) return;
  const int ent = dplan[blockIdx.x];
  const int y = ent >> 16, tile = ent & 0xffff;
  const int k = y >> 3, e = y & 7;
  const int n = cnt[y * 32];
  const int start = tile * 64;
  const int* list = k ? list1 : list0;
  const float* gate = k ? gate1 : gate0;

  __shared__ __align__(16) char smem[25600];
  ushort* As = (ushort*)(smem);            // 8 KB (64x64)
  ushort* Bs = (ushort*)(smem + 8192);     // 8 KB (64x64)
  ushort* Hs = (ushort*)(smem + 16384);    // 8 KB (64x64)
  int*  toks = (int*)(smem + 24576);       // 256 B
  float*  gs = (float*)(smem + 24832);     // 256 B

  const int tid = threadIdx.x;
  const int lane = tid & 63;
  const int w = tid >> 6;

  if (tid < 64) {
    int tk = -1; float g = 0.f;
    if (start + tid < n) {
      tk = list[e * CAP + start + tid];
      g = gate[e * CAP + start + tid];
    }
    toks[tid] = tk; gs[tid] = g;
  }
  __syncthreads();

  // staging: thread t -> granule chunks c0=t (row t>>3), c1=t+256 (row+32).
  // A: source col swizzled per row (xb natural layout); LDS write LINEAR.
  // B: wdt tiles pre-swizzled in global; LINEAR copy.
  const int row0 = tid >> 3;
  const int g8 = (tid & 7) * 8;
  const int csw = g8 ^ ((row0 & 7) << 3);   // (row0+32)&7 == row0&7
  const int tk0 = toks[row0], tk1 = toks[row0 + 32];
  const ushort* xr0 = xb + (size_t)(tk0 < 0 ? 0 : tk0) * CDIM + csw;
  const ushort* xr1 = xb + (size_t)(tk1 < 0 ? 0 : tk1) * CDIM + csw;
  const ushort* wde = wdt + ((size_t)e << 16);   // 16 tiles x 4096 ushorts

  f32x4 acc[4];
#pragma unroll
  for (int nn = 0; nn < 4; ++nn) acc[nn] = (f32x4){0.f, 0.f, 0.f, 0.f};

  ushort8 rA0, rA1, rB0, rB1;
  rA0 = *(const ushort8*)(xr0);
  rA1 = *(const ushort8*)(xr1);
  rB0 = *(const ushort8*)(wde + tid * 8);
  rB1 = *(const ushort8*)(wde + tid * 8 + 2048);

#pragma unroll 1
  for (int s = 0; s < 16; ++s) {
    __syncthreads();                       // prev step's LDS reads done
    *(ushort8*)&As[tid * 8]        = rA0;
    *(ushort8*)&As[tid * 8 + 2048] = rA1;
    *(ushort8*)&Bs[tid * 8]        = rB0;
    *(ushort8*)&Bs[tid * 8 + 2048] = rB1;
    if (s < 15) {                          // prefetch step s+1 under MFMA
      rA0 = *(const ushort8*)(xr0 + (s + 1) * 64);
      rA1 = *(const ushort8*)(xr1 + (s + 1) * 64);
      rB0 = *(const ushort8*)(wde + ((s + 1) << 12) + tid * 8);
      rB1 = *(const ushort8*)(wde + ((s + 1) << 12) + tid * 8 + 2048);
    }
    __syncthreads();
#pragma unroll
    for (int kk = 0; kk < 64; kk += 32) {
      const int kb = kk + (lane >> 4) * 8;
      bf16x8 a, bb[4];
      {
        const int row = w * 16 + (lane & 15);
        a = *(const bf16x8*)&As[row * 64 + (kb ^ ((row & 7) << 3))];
      }
#pragma unroll
      for (int nn = 0; nn < 4; ++nn) {
        const int r = nn * 16 + (lane & 15);
        bb[nn] = *(const bf16x8*)&Bs[r * 64 + (kb ^ ((r & 7) << 3))];
      }
#pragma unroll
      for (int nn = 0; nn < 4; ++nn)
        acc[nn] = __builtin_amdgcn_mfma_f32_16x16x32_bf16(a, bb[nn], acc[nn], 0, 0, 0);
    }
  }

  // epilogue: GELU*gate -> Hs (wave w owns token slots w*16..w*16+15)
#pragma unroll
  for (int nn = 0; nn < 4; ++nn)
#pragma unroll
    for (int q = 0; q < 4; ++q) {
      const int slot = w * 16 + (lane >> 4) * 4 + q;
      const int r = nn * 16 + (lane & 15);
      const float v = acc[nn][q];
      const float ge = 0.5f * v * (1.f + erff(v * 0.70710678118654752f));
      Hs[slot * 64 + (r ^ ((slot & 7) << 3))] = f2bf(ge * gs[slot]);
    }
  __syncthreads();
  // Hs -> Hbuf[(k<<14)+tok][64] (linear rows; thread covers rows row0,row0+32)
  if (tk0 >= 0)
    *(ushort8*)(Hbuf + ((size_t)((k << 14) + tk0)) * 64 + g8) =
        *(const ushort8*)&Hs[row0 * 64 + (g8 ^ ((row0 & 7) << 3))];
  if (tk1 >= 0)
    *(ushort8*)(Hbuf + ((size_t)((k << 14) + tk1)) * 64 + g8) =
        *(const ushort8*)&Hs[(row0 + 32) * 64 + (g8 ^ ((row0 & 7) << 3))];
}

// ---- up: out[t] = H0[t]@Wu_ea + H1[t]@Wu_eb, 64-tok x 2 col-slices --------
// A0/A1 staged ONCE per block (was 8x); slice-1 weights reg-prefetched under
// slice-0 MFMAs. LDS 48.4KB -> 3 blocks/CU; grid 640 (+aux block).
__global__ __launch_bounds__(256) void up_kernel(
    const ushort* __restrict__ Hbuf, const ushort* __restrict__ wut,
    const int* __restrict__ cnt_pair, const int* __restrict__ pairlist,
    const int* __restrict__ uplan, const int* __restrict__ totals,
    const int* __restrict__ cnt, const float* __restrict__ imp_part,
    float* __restrict__ out) {
  __shared__ __align__(16) char smem[49664];
  if (blockIdx.x == UT_MAX) {          // aux block (y==0 only)
    if (blockIdx.y != 0) return;
    float* red = (float*)smem;
    float* tot = (float*)(smem + 1024);
    const int t = threadIdx.x;
    const int e = t & 7, b0 = t >> 3;
    float s = 0.f;
    for (int j = 0; j < NBLK_R / 32; ++j)
      s += imp_part[(b0 + 32 * j) * 8 + e];
    red[t] = s;
    __syncthreads();
    if (t < 8) {
      float tt = 0.f;
      for (int ww = 0; ww < 32; ++ww) tt += red[ww * 8 + t];
      tot[t] = tt;
    }
    __syncthreads();
    if (t == 0) {
      float a = 0.f;
#pragma unroll
      for (int ee = 0; ee < NEXP; ++ee)
        a += (tot[ee] / (float)TOKS) *
             ((float)(cnt[ee * 32] + cnt[(NEXP + ee) * 32]) / (float)(2 * TOKS));
      out[(size_t)TOKS * CDIM] = 0.001f * 8.f * a;
    }
    return;
  }
  if (blockIdx.x >= totals[1]) return;
  const int ent = uplan[blockIdx.x];
  const int b = ent >> 16, tile = ent & 0xffff;
  const int ea = b >> 3, eb = b & 7;
  const int n = cnt_pair[b * 32];
  const int start = tile * 64;
  const int ybase = blockIdx.y * 2;    // 2 slices per block

  ushort* A0  = (ushort*)(smem);            // 8 KB (64x64)
  ushort* A1  = (ushort*)(smem + 8192);     // 8 KB
  ushort* BuA = (ushort*)(smem + 16384);    // 16 KB (128x64)
  ushort* BuB = (ushort*)(smem + 32768);    // 16 KB
  int*  toks  = (int*)(smem + 49152);       // 256 B

  const int tid = threadIdx.x;
  const int lane = tid & 63;
  const int w = tid >> 6;
  const int wr = w >> 1, wc = w & 1;

  if (tid < 64) {
    int tk = -1;
    if (start + tid < n) tk = pairlist[b * CAP + start + tid];
    toks[tid] = tk;
  }
  __syncthreads();

  // issue slice-0 weight loads (pre-swizzled wut; linear copy)
  const ushort* wuA = wut + ((size_t)(ea * 8 + ybase)) * 8192;
  const ushort* wuB = wut + ((size_t)(eb * 8 + ybase)) * 8192;
  ushort8 rUA[4], rUB[4];
#pragma unroll
  for (int j = 0; j < 4; ++j) {
    rUA[j] = *(const ushort8*)(wuA + (tid + j * 256) * 8);
    rUB[j] = *(const ushort8*)(wuB + (tid + j * 256) * 8);
  }
  // A-gather (source col swizzled; LDS linear) — ONCE per block
  const int row0 = tid >> 3;
  const int g8 = (tid & 7) * 8;
  const int csw = g8 ^ ((row0 & 7) << 3);
  const int tk0 = toks[row0], tk1 = toks[row0 + 32];
  const size_t t0 = (size_t)(tk0 < 0 ? 0 : tk0);
  const size_t t1 = (size_t)(tk1 < 0 ? 0 : tk1);
  *(ushort8*)&A0[tid * 8]        = *(const ushort8*)(Hbuf + t0 * 64 + csw);
  *(ushort8*)&A0[tid * 8 + 2048] = *(const ushort8*)(Hbuf + t1 * 64 + csw);
  *(ushort8*)&A1[tid * 8]        = *(const ushort8*)(Hbuf + (TOKS + t0) * 64 + csw);
  *(ushort8*)&A1[tid * 8 + 2048] = *(const ushort8*)(Hbuf + (TOKS + t1) * 64 + csw);
  // write slice-0 weights
#pragma unroll
  for (int j = 0; j < 4; ++j) {
    *(ushort8*)&BuA[(tid + j * 256) * 8] = rUA[j];
    *(ushort8*)&BuB[(tid + j * 256) * 8] = rUB[j];
  }
  __syncthreads();

#pragma unroll 1
  for (int j2 = 0; j2 < 2; ++j2) {
    const int n0 = ybase + j2;
    if (j2 == 0) {                      // prefetch slice-1 weights under MFMA
#pragma unroll
      for (int j = 0; j < 4; ++j) {
        rUA[j] = *(const ushort8*)(wuA + 8192 + (tid + j * 256) * 8);
        rUB[j] = *(const ushort8*)(wuB + 8192 + (tid + j * 256) * 8);
      }
    }
    f32x4 uac[2][4];
#pragma unroll
    for (int m = 0; m < 2; ++m)
#pragma unroll
      for (int nn = 0; nn < 4; ++nn) uac[m][nn] = (f32x4){0.f, 0.f, 0.f, 0.f};
    // pass A: H0 @ Wu_ea
#pragma unroll
    for (int kk = 0; kk < 64; kk += 32) {
      const int kb = kk + (lane >> 4) * 8;
      bf16x8 a[2], bbv[4];
#pragma unroll
      for (int m = 0; m < 2; ++m) {
        const int row = wr * 32 + m * 16 + (lane & 15);
        a[m] = *(const bf16x8*)&A0[row * 64 + (kb ^ ((row & 7) << 3))];
      }
#pragma unroll
      for (int nn = 0; nn < 4; ++nn) {
        const int c = wc * 64 + nn * 16 + (lane & 15);
        bbv[nn] = *(const bf16x8*)&BuA[c * 64 + (kb ^ ((c & 7) << 3))];
      }
#pragma unroll
      for (int m = 0; m < 2; ++m)
#pragma unroll
        for (int nn = 0; nn < 4; ++nn)
          uac[m][nn] = __builtin_amdgcn_mfma_f32_16x16x32_bf16(a[m], bbv[nn], uac[m][nn], 0, 0, 0);
    }
    // pass B: H1 @ Wu_eb (accumulate)
#pragma unroll
    for (int kk = 0; kk < 64; kk += 32) {
      const int kb = kk + (lane >> 4) * 8;
      bf16x8 a[2], bbv[4];
#pragma unroll
      for (int m = 0; m < 2; ++m) {
        const int row = wr * 32 + m * 16 + (lane & 15);
        a[m] = *(const bf16x8*)&A1[row * 64 + (kb ^ ((row & 7) << 3))];
      }
#pragma unroll
      for (int nn = 0; nn < 4; ++nn) {
        const int c = wc * 64 + nn * 16 + (lane & 15);
        bbv[nn] = *(const bf16x8*)&BuB[c * 64 + (kb ^ ((c & 7) << 3))];
      }
#pragma unroll
      for (int m = 0; m < 2; ++m)
#pragma unroll
        for (int nn = 0; nn < 4; ++nn)
          uac[m][nn] = __builtin_amdgcn_mfma_f32_16x16x32_bf16(a[m], bbv[nn], uac[m][nn], 0, 0, 0);
    }
    if (j2 == 0) {
      __syncthreads();                  // all waves done reading Bu
#pragma unroll
      for (int j = 0; j < 4; ++j) {
        *(ushort8*)&BuA[(tid + j * 256) * 8] = rUA[j];
        *(ushort8*)&BuB[(tid + j * 256) * 8] = rUB[j];
      }
    }
    // store this 128-col slice
#pragma unroll
    for (int m = 0; m < 2; ++m)
#pragma unroll
      for (int q = 0; q < 4; ++q) {
        const int slot = wr * 32 + m * 16 + (lane >> 4) * 4 + q;
        const int tk = toks[slot];
        if (tk >= 0) {
          float* orow = out + (size_t)tk * CDIM + n0 * 128 + wc * 64 + (lane & 15);
#pragma unroll
          for (int nn = 0; nn < 4; ++nn) orow[nn * 16] = uac[m][nn][q];
        }
      }
    if (j2 == 0) __syncthreads();       // Bu writes visible for slice 1
  }
}

extern "C" void kernel_launch(void* const* d_in, const int* in_sizes, int n_in,
                              void* d_out, int out_size, void* d_ws, size_t ws_size,
                              hipStream_t stream) {
  const float* x   = (const float*)d_in[0];
  const float* rw  = (const float*)d_in[1];
  const float* rb  = (const float*)d_in[2];
  const float* Wd  = (const float*)d_in[3];
  const float* Wu  = (const float*)d_in[4];
  const int* key_id = (const int*)d_in[5];
  float* out = (float*)d_out;

  char* ws = (char*)d_ws;
  int*    cnt      = (int*)ws;                    // 2 KB  (16 x 128B)
  int*    cnt_pair = (int*)(ws + 2048);           // 8 KB  (64 x 128B)
  int*    totals   = (int*)(ws + 10240);          // 8 B
  float*  imp_part = (float*)(ws + 16384);        // 32 KB
  int*    dplan    = (int*)(ws + 49152);          // ~2.2 KB
  int*    uplan    = (int*)(ws + 57344);          // ~1.3 KB
  int*    list0    = (int*)(ws + 65536);          // 512 KB
  float*  gate0    = (float*)(ws + 65536 + 524288);
  int*    list1    = (int*)(ws + 65536 + 1048576);
  float*  gate1    = (float*)(ws + 65536 + 1572864);
  ushort* wdt      = (ushort*)(ws + 2162688);     // 1 MB
  ushort* wut      = (ushort*)(ws + 3211264);     // 1 MB
  ushort* xb       = (ushort*)(ws + 4259840);     // 32 MB -> 37814272
  float*  rw_p     = (float*)(ws + 37814272);     // 32 KB -> 37847040
  int*    pairlist = (int*)(ws + 37847040);       // 4 MB  -> 42041344
  ushort* Hbuf     = (ushort*)(ws + 42041344);    // 4 MB  -> 46235648

  // Router scratch ALIASES the Hbuf region: fully consumed by scan/scatter
  // before down_kernel writes Hbuf. ~0.85 MB.
  int*    histT = (int*)(ws + 42041344);                // 320 KB
  int*    baseT = (int*)(ws + 42041344 + 327680);       // 320 KB
  int*    pbuf  = (int*)(ws + 42041344 + 655360);       // 64 KB
  float2* ggbuf = (float2*)(ws + 42041344 + 720896);    // 128 KB

  convert_kernel<<<1032, 256, 0, stream>>>(Wd, Wu, rw, key_id, wdt, wut, rw_p);
  router_kernel<<<NBLK_R, 256, 0, stream>>>(x, rw_p, rb, key_id, imp_part,
                                            pbuf, ggbuf, histT, xb);
  scan_kernel<<<80, 256, 0, stream>>>(histT, baseT, cnt, cnt_pair);
  scatter_kernel<<<257, 256, 0, stream>>>(baseT, pbuf, ggbuf, cnt, cnt_pair,
                                          list0, gate0, list1, gate1,
                                          pairlist, dplan, uplan, totals);
  down_kernel<<<DT_MAX, 256, 0, stream>>>(xb, wdt, cnt, list0, gate0,
                                          list1, gate1, dplan, totals, Hbuf);
  up_kernel<<<dim3(UT_MAX + 1, 4), 256, 0, stream>>>(
      Hbuf, wut, cnt_pair, pairlist, uplan, totals, cnt, imp_part, out);
}

// Round 10
// 77.285 us; speedup vs baseline: 1.1328x; 1.0242x over previous
//
#include <hip/hip_runtime.h>
#include <hip/hip_bf16.h>
#include <math.h>

#define TOKS 16384
#define CDIM 1024
#define NEXP 8
#define RDIM 64
#define CAP  TOKS
#define NBLK_R 1024   // router blocks (16 tokens each)
#define DT_MAX 528    // max down tiles: 32768/64 + 16
#define UT_MAX 320    // max up tiles: 16384/64 + 64

using f32x4   = __attribute__((ext_vector_type(4))) float;
using bf16x8  = __attribute__((ext_vector_type(8))) short;
using ushort8 = __attribute__((ext_vector_type(8))) unsigned short;

__device__ __forceinline__ ushort f2bf(float f) {
  unsigned u = __builtin_bit_cast(unsigned, f);
  u += 0x7fffu + ((u >> 16) & 1u);   // round-to-nearest-even
  return (ushort)(u >> 16);
}

// ---- setup: blocks 0..1023 = router; 1024..2047 = weight convert ----------
// Router: stages rw[kid] into per-block LDS in the PERMUTED layout
//   (coalesced global read, one-time scattered LDS write), so the old rw_p
//   global table and its producing pass are gone. x is prefetched one token
//   ahead of the compute. NO global atomics.
// Convert: Wd -> wdt[e][s][64r][64k] tiles PRE-SWIZZLED (granule g at
//   position g^(row&7)); Wu -> wut[e][n0][128c][64r] same (verified r5-r9).
__global__ __launch_bounds__(256) void setup_kernel(
    const float* __restrict__ x, const float* __restrict__ rw_all,
    const float* __restrict__ rb_all, const int* __restrict__ key_id,
    const float* __restrict__ Wd, const float* __restrict__ Wu,
    float* __restrict__ imp_part,
    int* __restrict__ pbuf, float2* __restrict__ ggbuf,
    int* __restrict__ histT, ushort* __restrict__ xb,
    ushort* __restrict__ wdt, ushort* __restrict__ wut) {
  const int bid = blockIdx.x;
  if (bid >= NBLK_R) {         // ---------------- weight convert ----------
    const int u = (bid - NBLK_R) * 256 + threadIdx.x;
    if (u < 131072) {          // Wd -> tile (e,s): [64 r][64 k], swizzled
      const int k4 = u & 255, r = (u >> 8) & 63, e = u >> 14;
      ushort4 h4;
      h4.x = f2bf(Wd[(size_t)(e * 1024 + k4 * 4 + 0) * 64 + r]);
      h4.y = f2bf(Wd[(size_t)(e * 1024 + k4 * 4 + 1) * 64 + r]);
      h4.z = f2bf(Wd[(size_t)(e * 1024 + k4 * 4 + 2) * 64 + r]);
      h4.w = f2bf(Wd[(size_t)(e * 1024 + k4 * 4 + 3) * 64 + r]);
      const int s = k4 >> 4;           // k-block (64-wide)
      const int kq4 = k4 & 15;         // ushort4 granule within row
      const int g = kq4 >> 1, hh = kq4 & 1;
      const int gs = g ^ (r & 7);      // pre-swizzle 8-ushort granule
      ((ushort4*)wdt)[((e * 16 + s) * 64 + r) * 16 + gs * 2 + hh] = h4;
    } else {                   // Wu -> tile (e,n0): [128 c][64 r], swizzled
      const int u2 = u - 131072;
      const int r4 = u2 & 15, c = (u2 >> 4) & 1023, e = u2 >> 14;
      ushort4 h4;
      h4.x = f2bf(Wu[(size_t)(e * 64 + r4 * 4 + 0) * 1024 + c]);
      h4.y = f2bf(Wu[(size_t)(e * 64 + r4 * 4 + 1) * 1024 + c]);
      h4.z = f2bf(Wu[(size_t)(e * 64 + r4 * 4 + 2) * 1024 + c]);
      h4.w = f2bf(Wu[(size_t)(e * 64 + r4 * 4 + 3) * 1024 + c]);
      const int n0 = c >> 7, cc = c & 127;
      const int g = r4 >> 1, hh = r4 & 1;
      const int gs = g ^ (cc & 7);
      ((ushort4*)wut)[((e * 8 + n0) * 128 + cc) * 16 + gs * 2 + hh] = h4;
    }
    return;
  }
  // ---------------- router ----------------
  __shared__ float4 s_rw[2048];        // 32 KB, permuted router weights
  __shared__ float s_imp[4][NEXP];
  __shared__ int   s_pb[16];
  __shared__ float s_g1[16], s_g2[16];
  const int tid = threadIdx.x;
  const int lane = tid & 63;
  const int wave = tid >> 6;
  const int kid = key_id[0];
  // stage rw[kid] -> LDS in permuted layout (slot st*128 + h*64 + l holds
  // float4 rw[C*8 + h*4 ..], C = (st>>2)*256 + l*4 + (st&3)).
  {
    const float4* rwg = (const float4*)rw_all + (size_t)kid * 2048;
#pragma unroll
    for (int j = 0; j < 8; ++j) {
      const int g = tid + j * 256;
      const float4 v = rwg[g];
      const int C = g >> 1, h = g & 1;
      const int st = ((C >> 8) << 2) | (C & 3);
      const int l = (C >> 2) & 63;
      s_rw[st * 128 + h * 64 + l] = v;
    }
  }
  __syncthreads();

  const float* rb = rb_all + (size_t)kid * NEXP;
  const int eln = ((lane & 1) << 2) | (lane & 2) | ((lane >> 2) & 1);
  const float rbe = rb[eln];
  float impacc = 0.f;

  const int wg = bid * 4 + wave;
  const float* xr0 = x + (size_t)(wg * 4) * CDIM + lane * 4;
  float4 xv[4];
#pragma unroll
  for (int j = 0; j < 4; ++j) xv[j] = *(const float4*)(xr0 + j * 256);

#pragma unroll 1
  for (int tt = 0; tt < 4; ++tt) {
    const int token = wg * 4 + tt;
    float4 nx[4];
    if (tt < 3) {                      // prefetch next token's x (hides HBM)
      const float* xrn = xr0 + (size_t)(tt + 1) * CDIM;
#pragma unroll
      for (int j = 0; j < 4; ++j) nx[j] = *(const float4*)(xrn + j * 256);
    }
    ushort* xo = xb + (size_t)token * CDIM + lane * 4;
#pragma unroll
    for (int j = 0; j < 4; ++j) {
      ushort4 h;
      h.x = f2bf(xv[j].x); h.y = f2bf(xv[j].y);
      h.z = f2bf(xv[j].z); h.w = f2bf(xv[j].w);
      *(ushort4*)(xo + j * 256) = h;
    }
    float acc[8];
#pragma unroll
    for (int e = 0; e < 8; ++e) acc[e] = 0.f;
#pragma unroll
    for (int j = 0; j < 4; ++j) {
#pragma unroll
      for (int i = 0; i < 4; ++i) {
        const int st = j * 4 + i;
        const float4 wA = s_rw[st * 128 + lane];
        const float4 wB = s_rw[st * 128 + 64 + lane];
        const float xi = (&xv[j].x)[i];
        acc[0] = fmaf(xi, wA.x, acc[0]);
        acc[1] = fmaf(xi, wA.y, acc[1]);
        acc[2] = fmaf(xi, wA.z, acc[2]);
        acc[3] = fmaf(xi, wA.w, acc[3]);
        acc[4] = fmaf(xi, wB.x, acc[4]);
        acc[5] = fmaf(xi, wB.y, acc[5]);
        acc[6] = fmaf(xi, wB.z, acc[6]);
        acc[7] = fmaf(xi, wB.w, acc[7]);
      }
    }
    // butterfly 8 accs -> 1 (expert = bitrev3(lane&7)), then 64-lane sum
#pragma unroll
    for (int i = 0; i < 4; ++i) {
      const float send = (lane & 1) ? acc[i] : acc[i + 4];
      const float recv = __shfl_xor(send, 1);
      acc[i] = ((lane & 1) ? acc[i + 4] : acc[i]) + recv;
    }
#pragma unroll
    for (int i = 0; i < 2; ++i) {
      const float send = (lane & 2) ? acc[i] : acc[i + 2];
      const float recv = __shfl_xor(send, 2);
      acc[i] = ((lane & 2) ? acc[i + 2] : acc[i]) + recv;
    }
    {
      const float send = (lane & 4) ? acc[0] : acc[1];
      const float recv = __shfl_xor(send, 4);
      acc[0] = ((lane & 4) ? acc[1] : acc[0]) + recv;
    }
    float v = acc[0];
    v += __shfl_xor(v, 8); v += __shfl_xor(v, 16); v += __shfl_xor(v, 32);

    const float logit = v + rbe;
    float mx = logit;
    mx = fmaxf(mx, __shfl_xor(mx, 1));
    mx = fmaxf(mx, __shfl_xor(mx, 2));
    mx = fmaxf(mx, __shfl_xor(mx, 4));
    const float ex = expf(logit - mx);
    float sm = ex;
    sm += __shfl_xor(sm, 1); sm += __shfl_xor(sm, 2); sm += __shfl_xor(sm, 4);
    const float p = ex / sm;
    float bv = p; int bi = eln;
#pragma unroll
    for (int mk = 1; mk <= 4; mk <<= 1) {
      const float ov = __shfl_xor(bv, mk);
      const int oi = __shfl_xor(bi, mk);
      if (ov > bv || (ov == bv && oi < bi)) { bv = ov; bi = oi; }
    }
    const int e1 = bi; const float v1 = bv;
    float cv = (eln == e1) ? -1.f : p; int ci = eln;
#pragma unroll
    for (int mk = 1; mk <= 4; mk <<= 1) {
      const float ov = __shfl_xor(cv, mk);
      const int oi = __shfl_xor(ci, mk);
      if (ov > cv || (ov == cv && oi < ci)) { cv = ov; ci = oi; }
    }
    const int e2 = ci; const float v2 = cv;

    if (lane == 0) {
      const float gs = 1.f / (v1 + v2);
      const int li = wave * 4 + tt;
      s_g1[li] = v1 * gs;
      s_g2[li] = v2 * gs;
      s_pb[li] = e1 * 8 + e2;
    }
    impacc += p;
    if (tt < 3) {
      xv[0] = nx[0]; xv[1] = nx[1]; xv[2] = nx[2]; xv[3] = nx[3];
    }
  }
  if (lane < 8) s_imp[wave][eln] = impacc;
  __syncthreads();
  if (tid < 8)
    imp_part[bid * 8 + tid] =
        s_imp[0][tid] + s_imp[1][tid] + s_imp[2][tid] + s_imp[3][tid];

  // per-token records (coalesced, block-contiguous)
  if (tid < 16) {
    pbuf[bid * 16 + tid] = s_pb[tid];
    ggbuf[bid * 16 + tid] = make_float2(s_g1[tid], s_g2[tid]);
  }
  // transposed histograms: histT[c*1024 + blk], c in [0,80)
  if (tid < 80) {
    int c = 0;
    if (tid < 16) {
      const int k = tid >> 3, e = tid & 7;
#pragma unroll
      for (int j = 0; j < 16; ++j)
        c += ((k ? (s_pb[j] & 7) : (s_pb[j] >> 3)) == e) ? 1 : 0;
    } else {
      const int b = tid - 16;
#pragma unroll
      for (int j = 0; j < 16; ++j) c += (s_pb[j] == b) ? 1 : 0;
    }
    histT[tid * 1024 + bid] = c;
  }
}

// -------- scan: one block per counter, parallel prefix over 1024 blocks ----
__global__ __launch_bounds__(256) void scan_kernel(
    const int* __restrict__ histT, int* __restrict__ baseT,
    int* __restrict__ cnt, int* __restrict__ cnt_pair) {
  __shared__ int ls[256];
  const int c = blockIdx.x;
  const int t = threadIdx.x;
  const int4 v = ((const int4*)(histT + (c << 10)))[t];
  const int s = v.x + v.y + v.z + v.w;
  ls[t] = s;
  __syncthreads();
#pragma unroll
  for (int off = 1; off < 256; off <<= 1) {
    const int add = (t >= off) ? ls[t - off] : 0;
    __syncthreads();
    ls[t] += add;
    __syncthreads();
  }
  const int incl = ls[t];
  const int excl = incl - s;
  int4 b;
  b.x = excl;
  b.y = excl + v.x;
  b.z = excl + v.x + v.y;
  b.w = excl + v.x + v.y + v.z;
  ((int4*)(baseT + (c << 10)))[t] = b;
  if (t == 255) {
    if (c < 16) cnt[c * 32] = incl;
    else        cnt_pair[(c - 16) * 32] = incl;
  }
}

// -------- scatter (blocks 0..255: lists+pairs) + plan (block 256) ----------
__global__ __launch_bounds__(256) void scatter_kernel(
    const int* __restrict__ baseT, const int* __restrict__ pbuf,
    const float2* __restrict__ ggbuf,
    const int* __restrict__ cnt, const int* __restrict__ cnt_pair,
    int* __restrict__ list0, float* __restrict__ gate0,
    int* __restrict__ list1, float* __restrict__ gate1,
    int* __restrict__ pairlist,
    int* __restrict__ dplan, int* __restrict__ uplan,
    int* __restrict__ totals) {
  if (blockIdx.x == 256) {   // plan: 64-tok down tiles, 64-tok up tiles
    __shared__ int doff[16], uoff[64];
    const int t = threadIdx.x;
    if (t == 0) {
      int a = 0;
      for (int y = 0; y < 16; ++y) { doff[y] = a; a += (cnt[y * 32] + 63) >> 6; }
      totals[0] = a;
      a = 0;
      for (int b2 = 0; b2 < 64; ++b2) { uoff[b2] = a; a += (cnt_pair[b2 * 32] + 63) >> 6; }
      totals[1] = a;
    }
    __syncthreads();
    if (t < 16) {
      const int nd = (cnt[t * 32] + 63) >> 6;
      for (int i = 0; i < nd; ++i) dplan[doff[t] + i] = (t << 16) | i;
    }
    if (t < 64) {
      const int nu = (cnt_pair[t * 32] + 63) >> 6;
      for (int i = 0; i < nu; ++i) uplan[uoff[t] + i] = (t << 16) | i;
    }
    return;
  }
  const int tid = threadIdx.x;
  const int lane = tid & 63;
  const int wave = tid >> 6;
  const int rb = blockIdx.x * 4 + wave;   // router block, 0..1023
  const int i = lane;
  int pb = 0; float2 gg = make_float2(0.f, 0.f);
  if (lane < 16) { pb = pbuf[rb * 16 + lane]; gg = ggbuf[rb * 16 + lane]; }
  const int e1 = pb >> 3, e2 = pb & 7;
  int r0 = 0, r1 = 0, rp = 0;
#pragma unroll
  for (int j = 0; j < 15; ++j) {
    const int q = __shfl(pb, j);
    if (j < i) {
      r0 += ((q >> 3) == e1) ? 1 : 0;
      r1 += ((q & 7) == e2) ? 1 : 0;
      rp += (q == pb) ? 1 : 0;
    }
  }
  if (lane < 16) {
    const int token = rb * 16 + i;
    const int s0 = baseT[(e1 << 10) + rb] + r0;
    list0[e1 * CAP + s0] = token;
    gate0[e1 * CAP + s0] = gg.x;
    const int s1 = baseT[((8 + e2) << 10) + rb] + r1;
    list1[e2 * CAP + s1] = token;
    gate1[e2 * CAP + s1] = gg.y;
    const int sp = baseT[((16 + pb) << 10) + rb] + rp;
    pairlist[pb * CAP + sp] = token;
  }
}

// ---- down: H[k][tok] = GELU(x@Wd_e)*gate, 64-tok x 64-r tiles -------------
// Reg-prefetch staging; LDS 25KB -> 6 blocks/CU; 528 blocks; 8 MFMAs/wave/step.
__global__ __launch_bounds__(256) void down_kernel(
    const ushort* __restrict__ xb, const ushort* __restrict__ wdt,
    const int* __restrict__ cnt,
    const int* __restrict__ list0, const float* __restrict__ gate0,
    const int* __restrict__ list1, const float* __restrict__ gate1,
    const int* __restrict__ dplan, const int* __restrict__ totals,
    ushort* __restrict__ Hbuf) {
  if (blockIdx.x >= totals[0]) return;
  const int ent = dplan[blockIdx.x];
  const int y = ent >> 16, tile = ent & 0xffff;
  const int k = y >> 3, e = y & 7;
  const int n = cnt[y * 32];
  const int start = tile * 64;
  const int* list = k ? list1 : list0;
  const float* gate = k ? gate1 : gate0;

  __shared__ __align__(16) char smem[25600];
  ushort* As = (ushort*)(smem);            // 8 KB (64x64)
  ushort* Bs = (ushort*)(smem + 8192);     // 8 KB (64x64)
  ushort* Hs = (ushort*)(smem + 16384);    // 8 KB (64x64)
  int*  toks = (int*)(smem + 24576);       // 256 B
  float*  gs = (float*)(smem + 24832);     // 256 B

  const int tid = threadIdx.x;
  const int lane = tid & 63;
  const int w = tid >> 6;

  if (tid < 64) {
    int tk = -1; float g = 0.f;
    if (start + tid < n) {
      tk = list[e * CAP + start + tid];
      g = gate[e * CAP + start + tid];
    }
    toks[tid] = tk; gs[tid] = g;
  }
  __syncthreads();

  // staging: thread t -> granule chunks c0=t (row t>>3), c1=t+256 (row+32).
  // A: source col swizzled per row (xb natural layout); LDS write LINEAR.
  // B: wdt tiles pre-swizzled in global; LINEAR copy.
  const int row0 = tid >> 3;
  const int g8 = (tid & 7) * 8;
  const int csw = g8 ^ ((row0 & 7) << 3);   // (row0+32)&7 == row0&7
  const int tk0 = toks[row0], tk1 = toks[row0 + 32];
  const ushort* xr0 = xb + (size_t)(tk0 < 0 ? 0 : tk0) * CDIM + csw;
  const ushort* xr1 = xb + (size_t)(tk1 < 0 ? 0 : tk1) * CDIM + csw;
  const ushort* wde = wdt + ((size_t)e << 16);   // 16 tiles x 4096 ushorts

  f32x4 acc[4];
#pragma unroll
  for (int nn = 0; nn < 4; ++nn) acc[nn] = (f32x4){0.f, 0.f, 0.f, 0.f};

  ushort8 rA0, rA1, rB0, rB1;
  rA0 = *(const ushort8*)(xr0);
  rA1 = *(const ushort8*)(xr1);
  rB0 = *(const ushort8*)(wde + tid * 8);
  rB1 = *(const ushort8*)(wde + tid * 8 + 2048);

#pragma unroll 1
  for (int s = 0; s < 16; ++s) {
    __syncthreads();                       // prev step's LDS reads done
    *(ushort8*)&As[tid * 8]        = rA0;
    *(ushort8*)&As[tid * 8 + 2048] = rA1;
    *(ushort8*)&Bs[tid * 8]        = rB0;
    *(ushort8*)&Bs[tid * 8 + 2048] = rB1;
    if (s < 15) {                          // prefetch step s+1 under MFMA
      rA0 = *(const ushort8*)(xr0 + (s + 1) * 64);
      rA1 = *(const ushort8*)(xr1 + (s + 1) * 64);
      rB0 = *(const ushort8*)(wde + ((s + 1) << 12) + tid * 8);
      rB1 = *(const ushort8*)(wde + ((s + 1) << 12) + tid * 8 + 2048);
    }
    __syncthreads();
#pragma unroll
    for (int kk = 0; kk < 64; kk += 32) {
      const int kb = kk + (lane >> 4) * 8;
      bf16x8 a, bb[4];
      {
        const int row = w * 16 + (lane & 15);
        a = *(const bf16x8*)&As[row * 64 + (kb ^ ((row & 7) << 3))];
      }
#pragma unroll
      for (int nn = 0; nn < 4; ++nn) {
        const int r = nn * 16 + (lane & 15);
        bb[nn] = *(const bf16x8*)&Bs[r * 64 + (kb ^ ((r & 7) << 3))];
      }
#pragma unroll
      for (int nn = 0; nn < 4; ++nn)
        acc[nn] = __builtin_amdgcn_mfma_f32_16x16x32_bf16(a, bb[nn], acc[nn], 0, 0, 0);
    }
  }

  // epilogue: GELU*gate -> Hs (wave w owns token slots w*16..w*16+15)
#pragma unroll
  for (int nn = 0; nn < 4; ++nn)
#pragma unroll
    for (int q = 0; q < 4; ++q) {
      const int slot = w * 16 + (lane >> 4) * 4 + q;
      const int r = nn * 16 + (lane & 15);
      const float v = acc[nn][q];
      const float ge = 0.5f * v * (1.f + erff(v * 0.70710678118654752f));
      Hs[slot * 64 + (r ^ ((slot & 7) << 3))] = f2bf(ge * gs[slot]);
    }
  __syncthreads();
  // Hs -> Hbuf[(k<<14)+tok][64] (linear rows; thread covers rows row0,row0+32)
  if (tk0 >= 0)
    *(ushort8*)(Hbuf + ((size_t)((k << 14) + tk0)) * 64 + g8) =
        *(const ushort8*)&Hs[row0 * 64 + (g8 ^ ((row0 & 7) << 3))];
  if (tk1 >= 0)
    *(ushort8*)(Hbuf + ((size_t)((k << 14) + tk1)) * 64 + g8) =
        *(const ushort8*)&Hs[(row0 + 32) * 64 + (g8 ^ ((row0 & 7) << 3))];
}

// ---- up: out[t] = H0[t]@Wu_ea + H1[t]@Wu_eb, 64-tok x 2 col-slices --------
// A0/A1 staged ONCE per block; slice-1 weights reg-prefetched under slice-0
// MFMAs. LDS 48.4KB -> 3 blocks/CU; grid 640 (+aux block).
__global__ __launch_bounds__(256) void up_kernel(
    const ushort* __restrict__ Hbuf, const ushort* __restrict__ wut,
    const int* __restrict__ cnt_pair, const int* __restrict__ pairlist,
    const int* __restrict__ uplan, const int* __restrict__ totals,
    const int* __restrict__ cnt, const float* __restrict__ imp_part,
    float* __restrict__ out) {
  __shared__ __align__(16) char smem[49664];
  if (blockIdx.x == UT_MAX) {          // aux block (y==0 only)
    if (blockIdx.y != 0) return;
    float* red = (float*)smem;
    float* tot = (float*)(smem + 1024);
    const int t = threadIdx.x;
    const int e = t & 7, b0 = t >> 3;
    float s = 0.f;
    for (int j = 0; j < NBLK_R / 32; ++j)
      s += imp_part[(b0 + 32 * j) * 8 + e];
    red[t] = s;
    __syncthreads();
    if (t < 8) {
      float tt = 0.f;
      for (int ww = 0; ww < 32; ++ww) tt += red[ww * 8 + t];
      tot[t] = tt;
    }
    __syncthreads();
    if (t == 0) {
      float a = 0.f;
#pragma unroll
      for (int ee = 0; ee < NEXP; ++ee)
        a += (tot[ee] / (float)TOKS) *
             ((float)(cnt[ee * 32] + cnt[(NEXP + ee) * 32]) / (float)(2 * TOKS));
      out[(size_t)TOKS * CDIM] = 0.001f * 8.f * a;
    }
    return;
  }
  if (blockIdx.x >= totals[1]) return;
  const int ent = uplan[blockIdx.x];
  const int b = ent >> 16, tile = ent & 0xffff;
  const int ea = b >> 3, eb = b & 7;
  const int n = cnt_pair[b * 32];
  const int start = tile * 64;
  const int ybase = blockIdx.y * 2;    // 2 slices per block

  ushort* A0  = (ushort*)(smem);            // 8 KB (64x64)
  ushort* A1  = (ushort*)(smem + 8192);     // 8 KB
  ushort* BuA = (ushort*)(smem + 16384);    // 16 KB (128x64)
  ushort* BuB = (ushort*)(smem + 32768);    // 16 KB
  int*  toks  = (int*)(smem + 49152);       // 256 B

  const int tid = threadIdx.x;
  const int lane = tid & 63;
  const int w = tid >> 6;
  const int wr = w >> 1, wc = w & 1;

  if (tid < 64) {
    int tk = -1;
    if (start + tid < n) tk = pairlist[b * CAP + start + tid];
    toks[tid] = tk;
  }
  __syncthreads();

  // issue slice-0 weight loads (pre-swizzled wut; linear copy)
  const ushort* wuA = wut + ((size_t)(ea * 8 + ybase)) * 8192;
  const ushort* wuB = wut + ((size_t)(eb * 8 + ybase)) * 8192;
  ushort8 rUA[4], rUB[4];
#pragma unroll
  for (int j = 0; j < 4; ++j) {
    rUA[j] = *(const ushort8*)(wuA + (tid + j * 256) * 8);
    rUB[j] = *(const ushort8*)(wuB + (tid + j * 256) * 8);
  }
  // A-gather (source col swizzled; LDS linear) — ONCE per block
  const int row0 = tid >> 3;
  const int g8 = (tid & 7) * 8;
  const int csw = g8 ^ ((row0 & 7) << 3);
  const int tk0 = toks[row0], tk1 = toks[row0 + 32];
  const size_t t0 = (size_t)(tk0 < 0 ? 0 : tk0);
  const size_t t1 = (size_t)(tk1 < 0 ? 0 : tk1);
  *(ushort8*)&A0[tid * 8]        = *(const ushort8*)(Hbuf + t0 * 64 + csw);
  *(ushort8*)&A0[tid * 8 + 2048] = *(const ushort8*)(Hbuf + t1 * 64 + csw);
  *(ushort8*)&A1[tid * 8]        = *(const ushort8*)(Hbuf + (TOKS + t0) * 64 + csw);
  *(ushort8*)&A1[tid * 8 + 2048] = *(const ushort8*)(Hbuf + (TOKS + t1) * 64 + csw);
  // write slice-0 weights
#pragma unroll
  for (int j = 0; j < 4; ++j) {
    *(ushort8*)&BuA[(tid + j * 256) * 8] = rUA[j];
    *(ushort8*)&BuB[(tid + j * 256) * 8] = rUB[j];
  }
  __syncthreads();

#pragma unroll 1
  for (int j2 = 0; j2 < 2; ++j2) {
    const int n0 = ybase + j2;
    if (j2 == 0) {                      // prefetch slice-1 weights under MFMA
#pragma unroll
      for (int j = 0; j < 4; ++j) {
        rUA[j] = *(const ushort8*)(wuA + 8192 + (tid + j * 256) * 8);
        rUB[j] = *(const ushort8*)(wuB + 8192 + (tid + j * 256) * 8);
      }
    }
    f32x4 uac[2][4];
#pragma unroll
    for (int m = 0; m < 2; ++m)
#pragma unroll
      for (int nn = 0; nn < 4; ++nn) uac[m][nn] = (f32x4){0.f, 0.f, 0.f, 0.f};
    // pass A: H0 @ Wu_ea
#pragma unroll
    for (int kk = 0; kk < 64; kk += 32) {
      const int kb = kk + (lane >> 4) * 8;
      bf16x8 a[2], bbv[4];
#pragma unroll
      for (int m = 0; m < 2; ++m) {
        const int row = wr * 32 + m * 16 + (lane & 15);
        a[m] = *(const bf16x8*)&A0[row * 64 + (kb ^ ((row & 7) << 3))];
      }
#pragma unroll
      for (int nn = 0; nn < 4; ++nn) {
        const int c = wc * 64 + nn * 16 + (lane & 15);
        bbv[nn] = *(const bf16x8*)&BuA[c * 64 + (kb ^ ((c & 7) << 3))];
      }
#pragma unroll
      for (int m = 0; m < 2; ++m)
#pragma unroll
        for (int nn = 0; nn < 4; ++nn)
          uac[m][nn] = __builtin_amdgcn_mfma_f32_16x16x32_bf16(a[m], bbv[nn], uac[m][nn], 0, 0, 0);
    }
    // pass B: H1 @ Wu_eb (accumulate)
#pragma unroll
    for (int kk = 0; kk < 64; kk += 32) {
      const int kb = kk + (lane >> 4) * 8;
      bf16x8 a[2], bbv[4];
#pragma unroll
      for (int m = 0; m < 2; ++m) {
        const int row = wr * 32 + m * 16 + (lane & 15);
        a[m] = *(const bf16x8*)&A1[row * 64 + (kb ^ ((row & 7) << 3))];
      }
#pragma unroll
      for (int nn = 0; nn < 4; ++nn) {
        const int c = wc * 64 + nn * 16 + (lane & 15);
        bbv[nn] = *(const bf16x8*)&BuB[c * 64 + (kb ^ ((c & 7) << 3))];
      }
#pragma unroll
      for (int m = 0; m < 2; ++m)
#pragma unroll
        for (int nn = 0; nn < 4; ++nn)
          uac[m][nn] = __builtin_amdgcn_mfma_f32_16x16x32_bf16(a[m], bbv[nn], uac[m][nn], 0, 0, 0);
    }
    if (j2 == 0) {
      __syncthreads();                  // all waves done reading Bu
#pragma unroll
      for (int j = 0; j < 4; ++j) {
        *(ushort8*)&BuA[(tid + j * 256) * 8] = rUA[j];
        *(ushort8*)&BuB[(tid + j * 256) * 8] = rUB[j];
      }
    }
    // store this 128-col slice
#pragma unroll
    for (int m = 0; m < 2; ++m)
#pragma unroll
      for (int q = 0; q < 4; ++q) {
        const int slot = wr * 32 + m * 16 + (lane >> 4) * 4 + q;
        const int tk = toks[slot];
        if (tk >= 0) {
          float* orow = out + (size_t)tk * CDIM + n0 * 128 + wc * 64 + (lane & 15);
#pragma unroll
          for (int nn = 0; nn < 4; ++nn) orow[nn * 16] = uac[m][nn][q];
        }
      }
    if (j2 == 0) __syncthreads();       // Bu writes visible for slice 1
  }
}

extern "C" void kernel_launch(void* const* d_in, const int* in_sizes, int n_in,
                              void* d_out, int out_size, void* d_ws, size_t ws_size,
                              hipStream_t stream) {
  const float* x   = (const float*)d_in[0];
  const float* rw  = (const float*)d_in[1];
  const float* rb  = (const float*)d_in[2];
  const float* Wd  = (const float*)d_in[3];
  const float* Wu  = (const float*)d_in[4];
  const int* key_id = (const int*)d_in[5];
  float* out = (float*)d_out;

  char* ws = (char*)d_ws;
  int*    cnt      = (int*)ws;                    // 2 KB  (16 x 128B)
  int*    cnt_pair = (int*)(ws + 2048);           // 8 KB  (64 x 128B)
  int*    totals   = (int*)(ws + 10240);          // 8 B
  float*  imp_part = (float*)(ws + 16384);        // 32 KB
  int*    dplan    = (int*)(ws + 49152);          // ~2.2 KB
  int*    uplan    = (int*)(ws + 57344);          // ~1.3 KB
  int*    list0    = (int*)(ws + 65536);          // 512 KB
  float*  gate0    = (float*)(ws + 65536 + 524288);
  int*    list1    = (int*)(ws + 65536 + 1048576);
  float*  gate1    = (float*)(ws + 65536 + 1572864);
  ushort* wdt      = (ushort*)(ws + 2162688);     // 1 MB
  ushort* wut      = (ushort*)(ws + 3211264);     // 1 MB
  ushort* xb       = (ushort*)(ws + 4259840);     // 32 MB -> 37814272
  int*    pairlist = (int*)(ws + 37847040);       // 4 MB  -> 42041344
  ushort* Hbuf     = (ushort*)(ws + 42041344);    // 4 MB  -> 46235648

  // Router scratch ALIASES the Hbuf region: fully consumed by scan/scatter
  // before down_kernel writes Hbuf. ~0.85 MB.
  int*    histT = (int*)(ws + 42041344);                // 320 KB
  int*    baseT = (int*)(ws + 42041344 + 327680);       // 320 KB
  int*    pbuf  = (int*)(ws + 42041344 + 655360);       // 64 KB
  float2* ggbuf = (float2*)(ws + 42041344 + 720896);    // 128 KB

  setup_kernel<<<2048, 256, 0, stream>>>(x, rw, rb, key_id, Wd, Wu, imp_part,
                                         pbuf, ggbuf, histT, xb, wdt, wut);
  scan_kernel<<<80, 256, 0, stream>>>(histT, baseT, cnt, cnt_pair);
  scatter_kernel<<<257, 256, 0, stream>>>(baseT, pbuf, ggbuf, cnt, cnt_pair,
                                          list0, gate0, list1, gate1,
                                          pairlist, dplan, uplan, totals);
  down_kernel<<<DT_MAX, 256, 0, stream>>>(xb, wdt, cnt, list0, gate0,
                                          list1, gate1, dplan, totals, Hbuf);
  up_kernel<<<dim3(UT_MAX + 1, 4), 256, 0, stream>>>(
      Hbuf, wut, cnt_pair, pairlist, uplan, totals, cnt, imp_part, out);
}

// Round 11
// 72.680 us; speedup vs baseline: 1.2046x; 1.0634x over previous
//
#include <hip/hip_runtime.h>
#include <hip/hip_bf16.h>
#include <math.h>

#define TOKS 16384
#define CDIM 1024
#define NEXP 8
#define RDIM 64
#define CAP  TOKS
#define NBLK_R 1024   // router blocks (16 tokens each)
#define DT_MAX 528    // max down tiles: 32768/64 + 16
#define UT_MAX 320    // max up tiles: 16384/64 + 64

using f32x4   = __attribute__((ext_vector_type(4))) float;
using bf16x8  = __attribute__((ext_vector_type(8))) short;
using ushort8 = __attribute__((ext_vector_type(8))) unsigned short;

__device__ __forceinline__ ushort f2bf(float f) {
  unsigned u = __builtin_bit_cast(unsigned, f);
  u += 0x7fffu + ((u >> 16) & 1u);   // round-to-nearest-even
  return (ushort)(u >> 16);
}

// ---- setup: blocks 0..1023 = router (1024 thr, 16 waves, 1 token/wave);
//      blocks 1024..1279 = weight convert (1024 thr).
// Router: rw[kid] staged into padded-permuted LDS (stride 132/66 float4 ->
//   staging writes hit banks {0,8,16,24}/phase = conflict-free; reads cover
//   all 32 banks). One token per wave kills the serial 4-token loop.
// Convert: Wd -> wdt[e][s][64r][64k] PRE-SWIZZLED (granule g at g^(row&7));
//   Wu -> wut[e][n0][128c][64r] same (verified r5-r10).
__global__ __launch_bounds__(1024) void setup_kernel(
    const float* __restrict__ x, const float* __restrict__ rw_all,
    const float* __restrict__ rb_all, const int* __restrict__ key_id,
    const float* __restrict__ Wd, const float* __restrict__ Wu,
    float* __restrict__ imp_part,
    int* __restrict__ pbuf, float2* __restrict__ ggbuf,
    int* __restrict__ histT, ushort* __restrict__ xb,
    ushort* __restrict__ wdt, ushort* __restrict__ wut) {
  const int bid = blockIdx.x;
  const int tid = threadIdx.x;
  if (bid >= NBLK_R) {         // ---------------- weight convert ----------
    const int u = (bid - NBLK_R) * 1024 + tid;
    if (u < 131072) {          // Wd -> tile (e,s): [64 r][64 k], swizzled
      const int k4 = u & 255, r = (u >> 8) & 63, e = u >> 14;
      ushort4 h4;
      h4.x = f2bf(Wd[(size_t)(e * 1024 + k4 * 4 + 0) * 64 + r]);
      h4.y = f2bf(Wd[(size_t)(e * 1024 + k4 * 4 + 1) * 64 + r]);
      h4.z = f2bf(Wd[(size_t)(e * 1024 + k4 * 4 + 2) * 64 + r]);
      h4.w = f2bf(Wd[(size_t)(e * 1024 + k4 * 4 + 3) * 64 + r]);
      const int s = k4 >> 4;           // k-block (64-wide)
      const int kq4 = k4 & 15;         // ushort4 granule within row
      const int g = kq4 >> 1, hh = kq4 & 1;
      const int gs = g ^ (r & 7);      // pre-swizzle 8-ushort granule
      ((ushort4*)wdt)[((e * 16 + s) * 64 + r) * 16 + gs * 2 + hh] = h4;
    } else {                   // Wu -> tile (e,n0): [128 c][64 r], swizzled
      const int u2 = u - 131072;
      const int r4 = u2 & 15, c = (u2 >> 4) & 1023, e = u2 >> 14;
      ushort4 h4;
      h4.x = f2bf(Wu[(size_t)(e * 64 + r4 * 4 + 0) * 1024 + c]);
      h4.y = f2bf(Wu[(size_t)(e * 64 + r4 * 4 + 1) * 1024 + c]);
      h4.z = f2bf(Wu[(size_t)(e * 64 + r4 * 4 + 2) * 1024 + c]);
      h4.w = f2bf(Wu[(size_t)(e * 64 + r4 * 4 + 3) * 1024 + c]);
      const int n0 = c >> 7, cc = c & 127;
      const int g = r4 >> 1, hh = r4 & 1;
      const int gs = g ^ (cc & 7);
      ((ushort4*)wut)[((e * 8 + n0) * 128 + cc) * 16 + gs * 2 + hh] = h4;
    }
    return;
  }
  // ---------------- router (16 waves, 1 token each) ----------------
  __shared__ float4 s_rw[2112];        // 33 KB, permuted+padded (132/66)
  __shared__ float s_imp[16][NEXP];
  __shared__ int   s_pb[16];
  __shared__ float s_g1[16], s_g2[16];
  const int lane = tid & 63;
  const int wave = tid >> 6;           // 0..15 = token index in group
  const int kid = key_id[0];
  // stage rw[kid] -> LDS: coalesced read, padded scatter write.
  {
    const float4* rwg = (const float4*)rw_all + (size_t)kid * 2048;
#pragma unroll
    for (int j = 0; j < 2; ++j) {
      const int g = tid + j * 1024;
      const float4 v = rwg[g];
      const int C = g >> 1, h = g & 1;
      const int st = ((C >> 8) << 2) | (C & 3);
      const int l = (C >> 2) & 63;
      s_rw[st * 132 + h * 66 + l] = v;
    }
  }
  __syncthreads();

  const float* rb = rb_all + (size_t)kid * NEXP;
  const int eln = ((lane & 1) << 2) | (lane & 2) | ((lane >> 2) & 1);
  const float rbe = rb[eln];

  const int token = bid * 16 + wave;
  const float* xr = x + (size_t)token * CDIM + lane * 4;
  float4 xv[4];
#pragma unroll
  for (int j = 0; j < 4; ++j) xv[j] = *(const float4*)(xr + j * 256);
  ushort* xo = xb + (size_t)token * CDIM + lane * 4;
#pragma unroll
  for (int j = 0; j < 4; ++j) {
    ushort4 h;
    h.x = f2bf(xv[j].x); h.y = f2bf(xv[j].y);
    h.z = f2bf(xv[j].z); h.w = f2bf(xv[j].w);
    *(ushort4*)(xo + j * 256) = h;
  }
  float acc[8];
#pragma unroll
  for (int e = 0; e < 8; ++e) acc[e] = 0.f;
#pragma unroll
  for (int j = 0; j < 4; ++j) {
#pragma unroll
    for (int i = 0; i < 4; ++i) {
      const int st = j * 4 + i;
      const float4 wA = s_rw[st * 132 + lane];
      const float4 wB = s_rw[st * 132 + 66 + lane];
      const float xi = (&xv[j].x)[i];
      acc[0] = fmaf(xi, wA.x, acc[0]);
      acc[1] = fmaf(xi, wA.y, acc[1]);
      acc[2] = fmaf(xi, wA.z, acc[2]);
      acc[3] = fmaf(xi, wA.w, acc[3]);
      acc[4] = fmaf(xi, wB.x, acc[4]);
      acc[5] = fmaf(xi, wB.y, acc[5]);
      acc[6] = fmaf(xi, wB.z, acc[6]);
      acc[7] = fmaf(xi, wB.w, acc[7]);
    }
  }
  // butterfly 8 accs -> 1 (expert = bitrev3(lane&7)), then 64-lane sum
#pragma unroll
  for (int i = 0; i < 4; ++i) {
    const float send = (lane & 1) ? acc[i] : acc[i + 4];
    const float recv = __shfl_xor(send, 1);
    acc[i] = ((lane & 1) ? acc[i + 4] : acc[i]) + recv;
  }
#pragma unroll
  for (int i = 0; i < 2; ++i) {
    const float send = (lane & 2) ? acc[i] : acc[i + 2];
    const float recv = __shfl_xor(send, 2);
    acc[i] = ((lane & 2) ? acc[i + 2] : acc[i]) + recv;
  }
  {
    const float send = (lane & 4) ? acc[0] : acc[1];
    const float recv = __shfl_xor(send, 4);
    acc[0] = ((lane & 4) ? acc[1] : acc[0]) + recv;
  }
  float v = acc[0];
  v += __shfl_xor(v, 8); v += __shfl_xor(v, 16); v += __shfl_xor(v, 32);

  const float logit = v + rbe;
  float mx = logit;
  mx = fmaxf(mx, __shfl_xor(mx, 1));
  mx = fmaxf(mx, __shfl_xor(mx, 2));
  mx = fmaxf(mx, __shfl_xor(mx, 4));
  const float ex = expf(logit - mx);
  float sm = ex;
  sm += __shfl_xor(sm, 1); sm += __shfl_xor(sm, 2); sm += __shfl_xor(sm, 4);
  const float p = ex / sm;
  float bv = p; int bi = eln;
#pragma unroll
  for (int mk = 1; mk <= 4; mk <<= 1) {
    const float ov = __shfl_xor(bv, mk);
    const int oi = __shfl_xor(bi, mk);
    if (ov > bv || (ov == bv && oi < bi)) { bv = ov; bi = oi; }
  }
  const int e1 = bi; const float v1 = bv;
  float cv = (eln == e1) ? -1.f : p; int ci = eln;
#pragma unroll
  for (int mk = 1; mk <= 4; mk <<= 1) {
    const float ov = __shfl_xor(cv, mk);
    const int oi = __shfl_xor(ci, mk);
    if (ov > cv || (ov == cv && oi < ci)) { cv = ov; ci = oi; }
  }
  const int e2 = ci; const float v2 = cv;

  if (lane == 0) {
    const float gs = 1.f / (v1 + v2);
    s_g1[wave] = v1 * gs;
    s_g2[wave] = v2 * gs;
    s_pb[wave] = e1 * 8 + e2;
  }
  if (lane < 8) s_imp[wave][eln] = p;   // per-expert prob of this token
  __syncthreads();
  if (tid < 8) {
    float s = 0.f;
#pragma unroll
    for (int wv = 0; wv < 16; ++wv) s += s_imp[wv][tid];
    imp_part[bid * 8 + tid] = s;
  }
  // per-token records (coalesced, block-contiguous)
  if (tid < 16) {
    pbuf[bid * 16 + tid] = s_pb[tid];
    ggbuf[bid * 16 + tid] = make_float2(s_g1[tid], s_g2[tid]);
  }
  // transposed histograms: histT[c*1024 + blk], c in [0,80)
  if (tid < 80) {
    int c = 0;
    if (tid < 16) {
      const int k = tid >> 3, e = tid & 7;
#pragma unroll
      for (int j = 0; j < 16; ++j)
        c += ((k ? (s_pb[j] & 7) : (s_pb[j] >> 3)) == e) ? 1 : 0;
    } else {
      const int b = tid - 16;
#pragma unroll
      for (int j = 0; j < 16; ++j) c += (s_pb[j] == b) ? 1 : 0;
    }
    histT[tid * 1024 + bid] = c;
  }
}

// -------- scan: one block per counter, parallel prefix over 1024 blocks ----
__global__ __launch_bounds__(256) void scan_kernel(
    const int* __restrict__ histT, int* __restrict__ baseT,
    int* __restrict__ cnt, int* __restrict__ cnt_pair) {
  __shared__ int ls[256];
  const int c = blockIdx.x;
  const int t = threadIdx.x;
  const int4 v = ((const int4*)(histT + (c << 10)))[t];
  const int s = v.x + v.y + v.z + v.w;
  ls[t] = s;
  __syncthreads();
#pragma unroll
  for (int off = 1; off < 256; off <<= 1) {
    const int add = (t >= off) ? ls[t - off] : 0;
    __syncthreads();
    ls[t] += add;
    __syncthreads();
  }
  const int incl = ls[t];
  const int excl = incl - s;
  int4 b;
  b.x = excl;
  b.y = excl + v.x;
  b.z = excl + v.x + v.y;
  b.w = excl + v.x + v.y + v.z;
  ((int4*)(baseT + (c << 10)))[t] = b;
  if (t == 255) {
    if (c < 16) cnt[c * 32] = incl;
    else        cnt_pair[(c - 16) * 32] = incl;
  }
}

// -------- scatter (blocks 0..255: lists+pairs) + plan (block 256) ----------
__global__ __launch_bounds__(256) void scatter_kernel(
    const int* __restrict__ baseT, const int* __restrict__ pbuf,
    const float2* __restrict__ ggbuf,
    const int* __restrict__ cnt, const int* __restrict__ cnt_pair,
    int* __restrict__ list0, float* __restrict__ gate0,
    int* __restrict__ list1, float* __restrict__ gate1,
    int* __restrict__ pairlist,
    int* __restrict__ dplan, int* __restrict__ uplan,
    int* __restrict__ totals) {
  if (blockIdx.x == 256) {   // plan: 64-tok down tiles, 64-tok up tiles
    __shared__ int doff[16], uoff[64];
    const int t = threadIdx.x;
    if (t == 0) {
      int a = 0;
      for (int y = 0; y < 16; ++y) { doff[y] = a; a += (cnt[y * 32] + 63) >> 6; }
      totals[0] = a;
      a = 0;
      for (int b2 = 0; b2 < 64; ++b2) { uoff[b2] = a; a += (cnt_pair[b2 * 32] + 63) >> 6; }
      totals[1] = a;
    }
    __syncthreads();
    if (t < 16) {
      const int nd = (cnt[t * 32] + 63) >> 6;
      for (int i = 0; i < nd; ++i) dplan[doff[t] + i] = (t << 16) | i;
    }
    if (t < 64) {
      const int nu = (cnt_pair[t * 32] + 63) >> 6;
      for (int i = 0; i < nu; ++i) uplan[uoff[t] + i] = (t << 16) | i;
    }
    return;
  }
  const int tid = threadIdx.x;
  const int lane = tid & 63;
  const int wave = tid >> 6;
  const int rb = blockIdx.x * 4 + wave;   // router block, 0..1023
  const int i = lane;
  int pb = 0; float2 gg = make_float2(0.f, 0.f);
  if (lane < 16) { pb = pbuf[rb * 16 + lane]; gg = ggbuf[rb * 16 + lane]; }
  const int e1 = pb >> 3, e2 = pb & 7;
  int r0 = 0, r1 = 0, rp = 0;
#pragma unroll
  for (int j = 0; j < 15; ++j) {
    const int q = __shfl(pb, j);
    if (j < i) {
      r0 += ((q >> 3) == e1) ? 1 : 0;
      r1 += ((q & 7) == e2) ? 1 : 0;
      rp += (q == pb) ? 1 : 0;
    }
  }
  if (lane < 16) {
    const int token = rb * 16 + i;
    const int s0 = baseT[(e1 << 10) + rb] + r0;
    list0[e1 * CAP + s0] = token;
    gate0[e1 * CAP + s0] = gg.x;
    const int s1 = baseT[((8 + e2) << 10) + rb] + r1;
    list1[e2 * CAP + s1] = token;
    gate1[e2 * CAP + s1] = gg.y;
    const int sp = baseT[((16 + pb) << 10) + rb] + rp;
    pairlist[pb * CAP + sp] = token;
  }
}

// ---- down: H[k][tok] = GELU(x@Wd_e)*gate, 64-tok x 64-r tiles -------------
// Reg-prefetch staging; LDS 25KB -> 6 blocks/CU; 528 blocks; 8 MFMAs/wave/step.
__global__ __launch_bounds__(256) void down_kernel(
    const ushort* __restrict__ xb, const ushort* __restrict__ wdt,
    const int* __restrict__ cnt,
    const int* __restrict__ list0, const float* __restrict__ gate0,
    const int* __restrict__ list1, const float* __restrict__ gate1,
    const int* __restrict__ dplan, const int* __restrict__ totals,
    ushort* __restrict__ Hbuf) {
  if (blockIdx.x >= totals[0]) return;
  const int ent = dplan[blockIdx.x];
  const int y = ent >> 16, tile = ent & 0xffff;
  const int k = y >> 3, e = y & 7;
  const int n = cnt[y * 32];
  const int start = tile * 64;
  const int* list = k ? list1 : list0;
  const float* gate = k ? gate1 : gate0;

  __shared__ __align__(16) char smem[25600];
  ushort* As = (ushort*)(smem);            // 8 KB (64x64)
  ushort* Bs = (ushort*)(smem + 8192);     // 8 KB (64x64)
  ushort* Hs = (ushort*)(smem + 16384);    // 8 KB (64x64)
  int*  toks = (int*)(smem + 24576);       // 256 B
  float*  gs = (float*)(smem + 24832);     // 256 B

  const int tid = threadIdx.x;
  const int lane = tid & 63;
  const int w = tid >> 6;

  if (tid < 64) {
    int tk = -1; float g = 0.f;
    if (start + tid < n) {
      tk = list[e * CAP + start + tid];
      g = gate[e * CAP + start + tid];
    }
    toks[tid] = tk; gs[tid] = g;
  }
  __syncthreads();

  // staging: thread t -> granule chunks c0=t (row t>>3), c1=t+256 (row+32).
  // A: source col swizzled per row (xb natural layout); LDS write LINEAR.
  // B: wdt tiles pre-swizzled in global; LINEAR copy.
  const int row0 = tid >> 3;
  const int g8 = (tid & 7) * 8;
  const int csw = g8 ^ ((row0 & 7) << 3);   // (row0+32)&7 == row0&7
  const int tk0 = toks[row0], tk1 = toks[row0 + 32];
  const ushort* xr0 = xb + (size_t)(tk0 < 0 ? 0 : tk0) * CDIM + csw;
  const ushort* xr1 = xb + (size_t)(tk1 < 0 ? 0 : tk1) * CDIM + csw;
  const ushort* wde = wdt + ((size_t)e << 16);   // 16 tiles x 4096 ushorts

  f32x4 acc[4];
#pragma unroll
  for (int nn = 0; nn < 4; ++nn) acc[nn] = (f32x4){0.f, 0.f, 0.f, 0.f};

  ushort8 rA0, rA1, rB0, rB1;
  rA0 = *(const ushort8*)(xr0);
  rA1 = *(const ushort8*)(xr1);
  rB0 = *(const ushort8*)(wde + tid * 8);
  rB1 = *(const ushort8*)(wde + tid * 8 + 2048);

#pragma unroll 1
  for (int s = 0; s < 16; ++s) {
    __syncthreads();                       // prev step's LDS reads done
    *(ushort8*)&As[tid * 8]        = rA0;
    *(ushort8*)&As[tid * 8 + 2048] = rA1;
    *(ushort8*)&Bs[tid * 8]        = rB0;
    *(ushort8*)&Bs[tid * 8 + 2048] = rB1;
    if (s < 15) {                          // prefetch step s+1 under MFMA
      rA0 = *(const ushort8*)(xr0 + (s + 1) * 64);
      rA1 = *(const ushort8*)(xr1 + (s + 1) * 64);
      rB0 = *(const ushort8*)(wde + ((s + 1) << 12) + tid * 8);
      rB1 = *(const ushort8*)(wde + ((s + 1) << 12) + tid * 8 + 2048);
    }
    __syncthreads();
#pragma unroll
    for (int kk = 0; kk < 64; kk += 32) {
      const int kb = kk + (lane >> 4) * 8;
      bf16x8 a, bb[4];
      {
        const int row = w * 16 + (lane & 15);
        a = *(const bf16x8*)&As[row * 64 + (kb ^ ((row & 7) << 3))];
      }
#pragma unroll
      for (int nn = 0; nn < 4; ++nn) {
        const int r = nn * 16 + (lane & 15);
        bb[nn] = *(const bf16x8*)&Bs[r * 64 + (kb ^ ((r & 7) << 3))];
      }
#pragma unroll
      for (int nn = 0; nn < 4; ++nn)
        acc[nn] = __builtin_amdgcn_mfma_f32_16x16x32_bf16(a, bb[nn], acc[nn], 0, 0, 0);
    }
  }

  // epilogue: GELU*gate -> Hs (wave w owns token slots w*16..w*16+15)
#pragma unroll
  for (int nn = 0; nn < 4; ++nn)
#pragma unroll
    for (int q = 0; q < 4; ++q) {
      const int slot = w * 16 + (lane >> 4) * 4 + q;
      const int r = nn * 16 + (lane & 15);
      const float v = acc[nn][q];
      const float ge = 0.5f * v * (1.f + erff(v * 0.70710678118654752f));
      Hs[slot * 64 + (r ^ ((slot & 7) << 3))] = f2bf(ge * gs[slot]);
    }
  __syncthreads();
  // Hs -> Hbuf[(k<<14)+tok][64] (linear rows; thread covers rows row0,row0+32)
  if (tk0 >= 0)
    *(ushort8*)(Hbuf + ((size_t)((k << 14) + tk0)) * 64 + g8) =
        *(const ushort8*)&Hs[row0 * 64 + (g8 ^ ((row0 & 7) << 3))];
  if (tk1 >= 0)
    *(ushort8*)(Hbuf + ((size_t)((k << 14) + tk1)) * 64 + g8) =
        *(const ushort8*)&Hs[(row0 + 32) * 64 + (g8 ^ ((row0 & 7) << 3))];
}

// ---- up: out[t] = H0[t]@Wu_ea + H1[t]@Wu_eb, 64-tok x 2 col-slices --------
// A0/A1 staged ONCE per block; slice-1 weights reg-prefetched under slice-0
// MFMAs. LDS 48.4KB -> 3 blocks/CU; grid 640 (+aux block).
__global__ __launch_bounds__(256) void up_kernel(
    const ushort* __restrict__ Hbuf, const ushort* __restrict__ wut,
    const int* __restrict__ cnt_pair, const int* __restrict__ pairlist,
    const int* __restrict__ uplan, const int* __restrict__ totals,
    const int* __restrict__ cnt, const float* __restrict__ imp_part,
    float* __restrict__ out) {
  __shared__ __align__(16) char smem[49664];
  if (blockIdx.x == UT_MAX) {          // aux block (y==0 only)
    if (blockIdx.y != 0) return;
    float* red = (float*)smem;
    float* tot = (float*)(smem + 1024);
    const int t = threadIdx.x;
    const int e = t & 7, b0 = t >> 3;
    float s = 0.f;
    for (int j = 0; j < NBLK_R / 32; ++j)
      s += imp_part[(b0 + 32 * j) * 8 + e];
    red[t] = s;
    __syncthreads();
    if (t < 8) {
      float tt = 0.f;
      for (int ww = 0; ww < 32; ++ww) tt += red[ww * 8 + t];
      tot[t] = tt;
    }
    __syncthreads();
    if (t == 0) {
      float a = 0.f;
#pragma unroll
      for (int ee = 0; ee < NEXP; ++ee)
        a += (tot[ee] / (float)TOKS) *
             ((float)(cnt[ee * 32] + cnt[(NEXP + ee) * 32]) / (float)(2 * TOKS));
      out[(size_t)TOKS * CDIM] = 0.001f * 8.f * a;
    }
    return;
  }
  if (blockIdx.x >= totals[1]) return;
  const int ent = uplan[blockIdx.x];
  const int b = ent >> 16, tile = ent & 0xffff;
  const int ea = b >> 3, eb = b & 7;
  const int n = cnt_pair[b * 32];
  const int start = tile * 64;
  const int ybase = blockIdx.y * 2;    // 2 slices per block

  ushort* A0  = (ushort*)(smem);            // 8 KB (64x64)
  ushort* A1  = (ushort*)(smem + 8192);     // 8 KB
  ushort* BuA = (ushort*)(smem + 16384);    // 16 KB (128x64)
  ushort* BuB = (ushort*)(smem + 32768);    // 16 KB
  int*  toks  = (int*)(smem + 49152);       // 256 B

  const int tid = threadIdx.x;
  const int lane = tid & 63;
  const int w = tid >> 6;
  const int wr = w >> 1, wc = w & 1;

  if (tid < 64) {
    int tk = -1;
    if (start + tid < n) tk = pairlist[b * CAP + start + tid];
    toks[tid] = tk;
  }
  __syncthreads();

  // issue slice-0 weight loads (pre-swizzled wut; linear copy)
  const ushort* wuA = wut + ((size_t)(ea * 8 + ybase)) * 8192;
  const ushort* wuB = wut + ((size_t)(eb * 8 + ybase)) * 8192;
  ushort8 rUA[4], rUB[4];
#pragma unroll
  for (int j = 0; j < 4; ++j) {
    rUA[j] = *(const ushort8*)(wuA + (tid + j * 256) * 8);
    rUB[j] = *(const ushort8*)(wuB + (tid + j * 256) * 8);
  }
  // A-gather (source col swizzled; LDS linear) — ONCE per block
  const int row0 = tid >> 3;
  const int g8 = (tid & 7) * 8;
  const int csw = g8 ^ ((row0 & 7) << 3);
  const int tk0 = toks[row0], tk1 = toks[row0 + 32];
  const size_t t0 = (size_t)(tk0 < 0 ? 0 : tk0);
  const size_t t1 = (size_t)(tk1 < 0 ? 0 : tk1);
  *(ushort8*)&A0[tid * 8]        = *(const ushort8*)(Hbuf + t0 * 64 + csw);
  *(ushort8*)&A0[tid * 8 + 2048] = *(const ushort8*)(Hbuf + t1 * 64 + csw);
  *(ushort8*)&A1[tid * 8]        = *(const ushort8*)(Hbuf + (TOKS + t0) * 64 + csw);
  *(ushort8*)&A1[tid * 8 + 2048] = *(const ushort8*)(Hbuf + (TOKS + t1) * 64 + csw);
  // write slice-0 weights
#pragma unroll
  for (int j = 0; j < 4; ++j) {
    *(ushort8*)&BuA[(tid + j * 256) * 8] = rUA[j];
    *(ushort8*)&BuB[(tid + j * 256) * 8] = rUB[j];
  }
  __syncthreads();

#pragma unroll 1
  for (int j2 = 0; j2 < 2; ++j2) {
    const int n0 = ybase + j2;
    if (j2 == 0) {                      // prefetch slice-1 weights under MFMA
#pragma unroll
      for (int j = 0; j < 4; ++j) {
        rUA[j] = *(const ushort8*)(wuA + 8192 + (tid + j * 256) * 8);
        rUB[j] = *(const ushort8*)(wuB + 8192 + (tid + j * 256) * 8);
      }
    }
    f32x4 uac[2][4];
#pragma unroll
    for (int m = 0; m < 2; ++m)
#pragma unroll
      for (int nn = 0; nn < 4; ++nn) uac[m][nn] = (f32x4){0.f, 0.f, 0.f, 0.f};
    // pass A: H0 @ Wu_ea
#pragma unroll
    for (int kk = 0; kk < 64; kk += 32) {
      const int kb = kk + (lane >> 4) * 8;
      bf16x8 a[2], bbv[4];
#pragma unroll
      for (int m = 0; m < 2; ++m) {
        const int row = wr * 32 + m * 16 + (lane & 15);
        a[m] = *(const bf16x8*)&A0[row * 64 + (kb ^ ((row & 7) << 3))];
      }
#pragma unroll
      for (int nn = 0; nn < 4; ++nn) {
        const int c = wc * 64 + nn * 16 + (lane & 15);
        bbv[nn] = *(const bf16x8*)&BuA[c * 64 + (kb ^ ((c & 7) << 3))];
      }
#pragma unroll
      for (int m = 0; m < 2; ++m)
#pragma unroll
        for (int nn = 0; nn < 4; ++nn)
          uac[m][nn] = __builtin_amdgcn_mfma_f32_16x16x32_bf16(a[m], bbv[nn], uac[m][nn], 0, 0, 0);
    }
    // pass B: H1 @ Wu_eb (accumulate)
#pragma unroll
    for (int kk = 0; kk < 64; kk += 32) {
      const int kb = kk + (lane >> 4) * 8;
      bf16x8 a[2], bbv[4];
#pragma unroll
      for (int m = 0; m < 2; ++m) {
        const int row = wr * 32 + m * 16 + (lane & 15);
        a[m] = *(const bf16x8*)&A1[row * 64 + (kb ^ ((row & 7) << 3))];
      }
#pragma unroll
      for (int nn = 0; nn < 4; ++nn) {
        const int c = wc * 64 + nn * 16 + (lane & 15);
        bbv[nn] = *(const bf16x8*)&BuB[c * 64 + (kb ^ ((c & 7) << 3))];
      }
#pragma unroll
      for (int m = 0; m < 2; ++m)
#pragma unroll
        for (int nn = 0; nn < 4; ++nn)
          uac[m][nn] = __builtin_amdgcn_mfma_f32_16x16x32_bf16(a[m], bbv[nn], uac[m][nn], 0, 0, 0);
    }
    if (j2 == 0) {
      __syncthreads();                  // all waves done reading Bu
#pragma unroll
      for (int j = 0; j < 4; ++j) {
        *(ushort8*)&BuA[(tid + j * 256) * 8] = rUA[j];
        *(ushort8*)&BuB[(tid + j * 256) * 8] = rUB[j];
      }
    }
    // store this 128-col slice
#pragma unroll
    for (int m = 0; m < 2; ++m)
#pragma unroll
      for (int q = 0; q < 4; ++q) {
        const int slot = wr * 32 + m * 16 + (lane >> 4) * 4 + q;
        const int tk = toks[slot];
        if (tk >= 0) {
          float* orow = out + (size_t)tk * CDIM + n0 * 128 + wc * 64 + (lane & 15);
#pragma unroll
          for (int nn = 0; nn < 4; ++nn) orow[nn * 16] = uac[m][nn][q];
        }
      }
    if (j2 == 0) __syncthreads();       // Bu writes visible for slice 1
  }
}

extern "C" void kernel_launch(void* const* d_in, const int* in_sizes, int n_in,
                              void* d_out, int out_size, void* d_ws, size_t ws_size,
                              hipStream_t stream) {
  const float* x   = (const float*)d_in[0];
  const float* rw  = (const float*)d_in[1];
  const float* rb  = (const float*)d_in[2];
  const float* Wd  = (const float*)d_in[3];
  const float* Wu  = (const float*)d_in[4];
  const int* key_id = (const int*)d_in[5];
  float* out = (float*)d_out;

  char* ws = (char*)d_ws;
  int*    cnt      = (int*)ws;                    // 2 KB  (16 x 128B)
  int*    cnt_pair = (int*)(ws + 2048);           // 8 KB  (64 x 128B)
  int*    totals   = (int*)(ws + 10240);          // 8 B
  float*  imp_part = (float*)(ws + 16384);        // 32 KB
  int*    dplan    = (int*)(ws + 49152);          // ~2.2 KB
  int*    uplan    = (int*)(ws + 57344);          // ~1.3 KB
  int*    list0    = (int*)(ws + 65536);          // 512 KB
  float*  gate0    = (float*)(ws + 65536 + 524288);
  int*    list1    = (int*)(ws + 65536 + 1048576);
  float*  gate1    = (float*)(ws + 65536 + 1572864);
  ushort* wdt      = (ushort*)(ws + 2162688);     // 1 MB
  ushort* wut      = (ushort*)(ws + 3211264);     // 1 MB
  ushort* xb       = (ushort*)(ws + 4259840);     // 32 MB -> 37814272
  int*    pairlist = (int*)(ws + 37847040);       // 4 MB  -> 42041344
  ushort* Hbuf     = (ushort*)(ws + 42041344);    // 4 MB  -> 46235648

  // Router scratch ALIASES the Hbuf region: fully consumed by scan/scatter
  // before down_kernel writes Hbuf. ~0.85 MB.
  int*    histT = (int*)(ws + 42041344);                // 320 KB
  int*    baseT = (int*)(ws + 42041344 + 327680);       // 320 KB
  int*    pbuf  = (int*)(ws + 42041344 + 655360);       // 64 KB
  float2* ggbuf = (float2*)(ws + 42041344 + 720896);    // 128 KB

  setup_kernel<<<NBLK_R + 256, 1024, 0, stream>>>(
      x, rw, rb, key_id, Wd, Wu, imp_part, pbuf, ggbuf, histT, xb, wdt, wut);
  scan_kernel<<<80, 256, 0, stream>>>(histT, baseT, cnt, cnt_pair);
  scatter_kernel<<<257, 256, 0, stream>>>(baseT, pbuf, ggbuf, cnt, cnt_pair,
                                          list0, gate0, list1, gate1,
                                          pairlist, dplan, uplan, totals);
  down_kernel<<<DT_MAX, 256, 0, stream>>>(xb, wdt, cnt, list0, gate0,
                                          list1, gate1, dplan, totals, Hbuf);
  up_kernel<<<dim3(UT_MAX + 1, 4), 256, 0, stream>>>(
      Hbuf, wut, cnt_pair, pairlist, uplan, totals, cnt, imp_part, out);
}

// Round 12
// 72.368 us; speedup vs baseline: 1.2098x; 1.0043x over previous
//
#include <hip/hip_runtime.h>
#include <hip/hip_bf16.h>
#include <math.h>

#define TOKS 16384
#define CDIM 1024
#define NEXP 8
#define RDIM 64
#define CAP  TOKS
#define NBLK_R 1024   // router blocks (16 tokens each)
#define DT_MAX 576    // max down tiles: 16384/32 + 64 pair buckets
#define UT_MAX 320    // max up tiles: 16384/64 + 64

using f32x4   = __attribute__((ext_vector_type(4))) float;
using bf16x8  = __attribute__((ext_vector_type(8))) short;
using ushort8 = __attribute__((ext_vector_type(8))) unsigned short;

__device__ __forceinline__ ushort f2bf(float f) {
  unsigned u = __builtin_bit_cast(unsigned, f);
  u += 0x7fffu + ((u >> 16) & 1u);   // round-to-nearest-even
  return (ushort)(u >> 16);
}

// ---- setup: blocks 0..1023 = router (1024 thr, 16 waves, 1 token/wave);
//      blocks 1024..1279 = weight convert (1024 thr). (verified r11)
__global__ __launch_bounds__(1024) void setup_kernel(
    const float* __restrict__ x, const float* __restrict__ rw_all,
    const float* __restrict__ rb_all, const int* __restrict__ key_id,
    const float* __restrict__ Wd, const float* __restrict__ Wu,
    float* __restrict__ imp_part,
    int* __restrict__ pbuf, float2* __restrict__ ggbuf,
    int* __restrict__ histT, ushort* __restrict__ xb,
    ushort* __restrict__ wdt, ushort* __restrict__ wut) {
  const int bid = blockIdx.x;
  const int tid = threadIdx.x;
  if (bid >= NBLK_R) {         // ---------------- weight convert ----------
    const int u = (bid - NBLK_R) * 1024 + tid;
    if (u < 131072) {          // Wd -> tile (e,s): [64 r][64 k], swizzled
      const int k4 = u & 255, r = (u >> 8) & 63, e = u >> 14;
      ushort4 h4;
      h4.x = f2bf(Wd[(size_t)(e * 1024 + k4 * 4 + 0) * 64 + r]);
      h4.y = f2bf(Wd[(size_t)(e * 1024 + k4 * 4 + 1) * 64 + r]);
      h4.z = f2bf(Wd[(size_t)(e * 1024 + k4 * 4 + 2) * 64 + r]);
      h4.w = f2bf(Wd[(size_t)(e * 1024 + k4 * 4 + 3) * 64 + r]);
      const int s = k4 >> 4;           // k-block (64-wide)
      const int kq4 = k4 & 15;         // ushort4 granule within row
      const int g = kq4 >> 1, hh = kq4 & 1;
      const int gs = g ^ (r & 7);      // pre-swizzle 8-ushort granule
      ((ushort4*)wdt)[((e * 16 + s) * 64 + r) * 16 + gs * 2 + hh] = h4;
    } else {                   // Wu -> tile (e,n0): [128 c][64 r], swizzled
      const int u2 = u - 131072;
      const int r4 = u2 & 15, c = (u2 >> 4) & 1023, e = u2 >> 14;
      ushort4 h4;
      h4.x = f2bf(Wu[(size_t)(e * 64 + r4 * 4 + 0) * 1024 + c]);
      h4.y = f2bf(Wu[(size_t)(e * 64 + r4 * 4 + 1) * 1024 + c]);
      h4.z = f2bf(Wu[(size_t)(e * 64 + r4 * 4 + 2) * 1024 + c]);
      h4.w = f2bf(Wu[(size_t)(e * 64 + r4 * 4 + 3) * 1024 + c]);
      const int n0 = c >> 7, cc = c & 127;
      const int g = r4 >> 1, hh = r4 & 1;
      const int gs = g ^ (cc & 7);
      ((ushort4*)wut)[((e * 8 + n0) * 128 + cc) * 16 + gs * 2 + hh] = h4;
    }
    return;
  }
  // ---------------- router (16 waves, 1 token each) ----------------
  __shared__ float4 s_rw[2112];        // 33 KB, permuted+padded (132/66)
  __shared__ float s_imp[16][NEXP];
  __shared__ int   s_pb[16];
  __shared__ float s_g1[16], s_g2[16];
  const int lane = tid & 63;
  const int wave = tid >> 6;           // 0..15 = token index in group
  const int kid = key_id[0];
  // stage rw[kid] -> LDS: coalesced read, padded scatter write.
  {
    const float4* rwg = (const float4*)rw_all + (size_t)kid * 2048;
#pragma unroll
    for (int j = 0; j < 2; ++j) {
      const int g = tid + j * 1024;
      const float4 v = rwg[g];
      const int C = g >> 1, h = g & 1;
      const int st = ((C >> 8) << 2) | (C & 3);
      const int l = (C >> 2) & 63;
      s_rw[st * 132 + h * 66 + l] = v;
    }
  }
  __syncthreads();

  const float* rb = rb_all + (size_t)kid * NEXP;
  const int eln = ((lane & 1) << 2) | (lane & 2) | ((lane >> 2) & 1);
  const float rbe = rb[eln];

  const int token = bid * 16 + wave;
  const float* xr = x + (size_t)token * CDIM + lane * 4;
  float4 xv[4];
#pragma unroll
  for (int j = 0; j < 4; ++j) xv[j] = *(const float4*)(xr + j * 256);
  ushort* xo = xb + (size_t)token * CDIM + lane * 4;
#pragma unroll
  for (int j = 0; j < 4; ++j) {
    ushort4 h;
    h.x = f2bf(xv[j].x); h.y = f2bf(xv[j].y);
    h.z = f2bf(xv[j].z); h.w = f2bf(xv[j].w);
    *(ushort4*)(xo + j * 256) = h;
  }
  float acc[8];
#pragma unroll
  for (int e = 0; e < 8; ++e) acc[e] = 0.f;
#pragma unroll
  for (int j = 0; j < 4; ++j) {
#pragma unroll
    for (int i = 0; i < 4; ++i) {
      const int st = j * 4 + i;
      const float4 wA = s_rw[st * 132 + lane];
      const float4 wB = s_rw[st * 132 + 66 + lane];
      const float xi = (&xv[j].x)[i];
      acc[0] = fmaf(xi, wA.x, acc[0]);
      acc[1] = fmaf(xi, wA.y, acc[1]);
      acc[2] = fmaf(xi, wA.z, acc[2]);
      acc[3] = fmaf(xi, wA.w, acc[3]);
      acc[4] = fmaf(xi, wB.x, acc[4]);
      acc[5] = fmaf(xi, wB.y, acc[5]);
      acc[6] = fmaf(xi, wB.z, acc[6]);
      acc[7] = fmaf(xi, wB.w, acc[7]);
    }
  }
  // butterfly 8 accs -> 1 (expert = bitrev3(lane&7)), then 64-lane sum
#pragma unroll
  for (int i = 0; i < 4; ++i) {
    const float send = (lane & 1) ? acc[i] : acc[i + 4];
    const float recv = __shfl_xor(send, 1);
    acc[i] = ((lane & 1) ? acc[i + 4] : acc[i]) + recv;
  }
#pragma unroll
  for (int i = 0; i < 2; ++i) {
    const float send = (lane & 2) ? acc[i] : acc[i + 2];
    const float recv = __shfl_xor(send, 2);
    acc[i] = ((lane & 2) ? acc[i + 2] : acc[i]) + recv;
  }
  {
    const float send = (lane & 4) ? acc[0] : acc[1];
    const float recv = __shfl_xor(send, 4);
    acc[0] = ((lane & 4) ? acc[1] : acc[0]) + recv;
  }
  float v = acc[0];
  v += __shfl_xor(v, 8); v += __shfl_xor(v, 16); v += __shfl_xor(v, 32);

  const float logit = v + rbe;
  float mx = logit;
  mx = fmaxf(mx, __shfl_xor(mx, 1));
  mx = fmaxf(mx, __shfl_xor(mx, 2));
  mx = fmaxf(mx, __shfl_xor(mx, 4));
  const float ex = expf(logit - mx);
  float sm = ex;
  sm += __shfl_xor(sm, 1); sm += __shfl_xor(sm, 2); sm += __shfl_xor(sm, 4);
  const float p = ex / sm;
  float bv = p; int bi = eln;
#pragma unroll
  for (int mk = 1; mk <= 4; mk <<= 1) {
    const float ov = __shfl_xor(bv, mk);
    const int oi = __shfl_xor(bi, mk);
    if (ov > bv || (ov == bv && oi < bi)) { bv = ov; bi = oi; }
  }
  const int e1 = bi; const float v1 = bv;
  float cv = (eln == e1) ? -1.f : p; int ci = eln;
#pragma unroll
  for (int mk = 1; mk <= 4; mk <<= 1) {
    const float ov = __shfl_xor(cv, mk);
    const int oi = __shfl_xor(ci, mk);
    if (ov > cv || (ov == cv && oi < ci)) { cv = ov; ci = oi; }
  }
  const int e2 = ci; const float v2 = cv;

  if (lane == 0) {
    const float gs = 1.f / (v1 + v2);
    s_g1[wave] = v1 * gs;
    s_g2[wave] = v2 * gs;
    s_pb[wave] = e1 * 8 + e2;
  }
  if (lane < 8) s_imp[wave][eln] = p;   // per-expert prob of this token
  __syncthreads();
  if (tid < 8) {
    float s = 0.f;
#pragma unroll
    for (int wv = 0; wv < 16; ++wv) s += s_imp[wv][tid];
    imp_part[bid * 8 + tid] = s;
  }
  // per-token records (coalesced, block-contiguous)
  if (tid < 16) {
    pbuf[bid * 16 + tid] = s_pb[tid];
    ggbuf[bid * 16 + tid] = make_float2(s_g1[tid], s_g2[tid]);
  }
  // transposed histograms: histT[c*1024 + blk], c in [0,80)
  if (tid < 80) {
    int c = 0;
    if (tid < 16) {
      const int k = tid >> 3, e = tid & 7;
#pragma unroll
      for (int j = 0; j < 16; ++j)
        c += ((k ? (s_pb[j] & 7) : (s_pb[j] >> 3)) == e) ? 1 : 0;
    } else {
      const int b = tid - 16;
#pragma unroll
      for (int j = 0; j < 16; ++j) c += (s_pb[j] == b) ? 1 : 0;
    }
    histT[tid * 1024 + bid] = c;
  }
}

// -------- scan: one block per counter, parallel prefix over 1024 blocks ----
__global__ __launch_bounds__(256) void scan_kernel(
    const int* __restrict__ histT, int* __restrict__ baseT,
    int* __restrict__ cnt, int* __restrict__ cnt_pair) {
  __shared__ int ls[256];
  const int c = blockIdx.x;
  const int t = threadIdx.x;
  const int4 v = ((const int4*)(histT + (c << 10)))[t];
  const int s = v.x + v.y + v.z + v.w;
  ls[t] = s;
  __syncthreads();
#pragma unroll
  for (int off = 1; off < 256; off <<= 1) {
    const int add = (t >= off) ? ls[t - off] : 0;
    __syncthreads();
    ls[t] += add;
    __syncthreads();
  }
  const int incl = ls[t];
  const int excl = incl - s;
  int4 b;
  b.x = excl;
  b.y = excl + v.x;
  b.z = excl + v.x + v.y;
  b.w = excl + v.x + v.y + v.z;
  ((int4*)(baseT + (c << 10)))[t] = b;
  if (t == 255) {
    if (c < 16) cnt[c * 32] = incl;
    else        cnt_pair[(c - 16) * 32] = incl;
  }
}

// -------- scatter (blocks 0..255: pairlist only) + plan (block 256) --------
__global__ __launch_bounds__(256) void scatter_kernel(
    const int* __restrict__ baseT, const int* __restrict__ pbuf,
    const int* __restrict__ cnt_pair,
    int* __restrict__ pairlist,
    int* __restrict__ dplan, int* __restrict__ uplan,
    int* __restrict__ totals) {
  if (blockIdx.x == 256) {   // plan: 32-tok down tiles, 64-tok up tiles
    __shared__ int doff[64], uoff[64];
    const int t = threadIdx.x;
    if (t == 0) {
      int a = 0;
      for (int b2 = 0; b2 < 64; ++b2) { doff[b2] = a; a += (cnt_pair[b2 * 32] + 31) >> 5; }
      totals[0] = a;
      a = 0;
      for (int b2 = 0; b2 < 64; ++b2) { uoff[b2] = a; a += (cnt_pair[b2 * 32] + 63) >> 6; }
      totals[1] = a;
    }
    __syncthreads();
    if (t < 64) {
      const int nd = (cnt_pair[t * 32] + 31) >> 5;
      for (int i = 0; i < nd; ++i) dplan[doff[t] + i] = (t << 16) | i;
      const int nu = (cnt_pair[t * 32] + 63) >> 6;
      for (int i = 0; i < nu; ++i) uplan[uoff[t] + i] = (t << 16) | i;
    }
    return;
  }
  const int tid = threadIdx.x;
  const int lane = tid & 63;
  const int wave = tid >> 6;
  const int rb = blockIdx.x * 4 + wave;   // router block, 0..1023
  const int i = lane;
  int pb = 0;
  if (lane < 16) pb = pbuf[rb * 16 + lane];
  int rp = 0;
#pragma unroll
  for (int j = 0; j < 15; ++j) {
    const int q = __shfl(pb, j);
    if (j < i) rp += (q == pb) ? 1 : 0;
  }
  if (lane < 16) {
    const int token = rb * 16 + i;
    const int sp = baseT[((16 + pb) << 10) + rb] + rp;
    pairlist[pb * CAP + sp] = token;
  }
}

// ---- down (pair-based): per 32-token pair tile, compute BOTH experts' H.
// H0 = GELU(x@Wd_e1)*g1 -> Hbuf[tok]; H1 = GELU(x@Wd_e2)*g2 -> Hbuf[TOKS+tok].
// xb staged ONCE per token (was twice); gates direct from ggbuf; LDS 28.5KB.
__global__ __launch_bounds__(256) void down_kernel(
    const ushort* __restrict__ xb, const ushort* __restrict__ wdt,
    const int* __restrict__ cnt_pair, const int* __restrict__ pairlist,
    const float2* __restrict__ ggbuf,
    const int* __restrict__ dplan, const int* __restrict__ totals,
    ushort* __restrict__ Hbuf) {
  if (blockIdx.x >= totals[0]) return;
  const int ent = dplan[blockIdx.x];
  const int b = ent >> 16, tile = ent & 0xffff;
  const int ea = b >> 3, eb = b & 7;
  const int n = cnt_pair[b * 32];
  const int start = tile * 32;

  __shared__ __align__(16) char smem[29184];
  ushort* As  = (ushort*)(smem);            // 4 KB (32x64)
  ushort* BsA = (ushort*)(smem + 4096);     // 8 KB (64x64, e1)
  ushort* BsB = (ushort*)(smem + 12288);    // 8 KB (64x64, e2)
  ushort* Hs0 = (ushort*)(smem + 20480);    // 4 KB (32x64)
  ushort* Hs1 = (ushort*)(smem + 24576);    // 4 KB
  int*  toks  = (int*)(smem + 28672);       // 128 B
  float* g1s  = (float*)(smem + 28800);     // 128 B
  float* g2s  = (float*)(smem + 28928);     // 128 B

  const int tid = threadIdx.x;
  const int lane = tid & 63;
  const int w = tid >> 6;

  if (tid < 32) {
    int tk = -1; float2 gg = make_float2(0.f, 0.f);
    if (start + tid < n) {
      tk = pairlist[b * CAP + start + tid];
      gg = ggbuf[tk];
    }
    toks[tid] = tk; g1s[tid] = gg.x; g2s[tid] = gg.y;
  }
  __syncthreads();

  // staging: thread t -> A row tid>>3 (0..31), chunk (tid&7)*8 (src-swizzled);
  // B: pre-swizzled wdt tiles, LINEAR copy (2 chunks per expert per thread).
  const int row0 = tid >> 3;
  const int g8 = (tid & 7) * 8;
  const int csw = g8 ^ ((row0 & 7) << 3);
  const int tk0 = toks[row0];
  const ushort* xr0 = xb + (size_t)(tk0 < 0 ? 0 : tk0) * CDIM + csw;
  const ushort* wdA = wdt + ((size_t)ea << 16);   // 16 tiles x 4096 ushorts
  const ushort* wdB = wdt + ((size_t)eb << 16);

  f32x4 acc[2][2];
#pragma unroll
  for (int m = 0; m < 2; ++m)
#pragma unroll
    for (int nn = 0; nn < 2; ++nn) acc[m][nn] = (f32x4){0.f, 0.f, 0.f, 0.f};

  ushort8 rA, rBA0, rBA1, rBB0, rBB1;
  rA   = *(const ushort8*)(xr0);
  rBA0 = *(const ushort8*)(wdA + tid * 8);
  rBA1 = *(const ushort8*)(wdA + tid * 8 + 2048);
  rBB0 = *(const ushort8*)(wdB + tid * 8);
  rBB1 = *(const ushort8*)(wdB + tid * 8 + 2048);

#pragma unroll 1
  for (int s = 0; s < 16; ++s) {
    __syncthreads();                       // prev step's LDS reads done
    *(ushort8*)&As [tid * 8]        = rA;
    *(ushort8*)&BsA[tid * 8]        = rBA0;
    *(ushort8*)&BsA[tid * 8 + 2048] = rBA1;
    *(ushort8*)&BsB[tid * 8]        = rBB0;
    *(ushort8*)&BsB[tid * 8 + 2048] = rBB1;
    if (s < 15) {                          // prefetch step s+1 under MFMA
      rA   = *(const ushort8*)(xr0 + (s + 1) * 64);
      rBA0 = *(const ushort8*)(wdA + ((s + 1) << 12) + tid * 8);
      rBA1 = *(const ushort8*)(wdA + ((s + 1) << 12) + tid * 8 + 2048);
      rBB0 = *(const ushort8*)(wdB + ((s + 1) << 12) + tid * 8);
      rBB1 = *(const ushort8*)(wdB + ((s + 1) << 12) + tid * 8 + 2048);
    }
    __syncthreads();
    const ushort* Bsx = (w < 2) ? BsA : BsB;
    const int wn = (w & 1) * 32;
#pragma unroll
    for (int kk = 0; kk < 64; kk += 32) {
      const int kb = kk + (lane >> 4) * 8;
      bf16x8 a[2], bb[2];
#pragma unroll
      for (int m = 0; m < 2; ++m) {
        const int row = m * 16 + (lane & 15);
        a[m] = *(const bf16x8*)&As[row * 64 + (kb ^ ((row & 7) << 3))];
      }
#pragma unroll
      for (int nn = 0; nn < 2; ++nn) {
        const int r = wn + nn * 16 + (lane & 15);
        bb[nn] = *(const bf16x8*)&Bsx[r * 64 + (kb ^ ((r & 7) << 3))];
      }
#pragma unroll
      for (int m = 0; m < 2; ++m)
#pragma unroll
        for (int nn = 0; nn < 2; ++nn)
          acc[m][nn] = __builtin_amdgcn_mfma_f32_16x16x32_bf16(a[m], bb[nn], acc[m][nn], 0, 0, 0);
    }
  }

  // epilogue: GELU*gate -> Hs0 (waves 0,1) / Hs1 (waves 2,3)
  {
    ushort* Hsx = (w < 2) ? Hs0 : Hs1;
    const float* gsx = (w < 2) ? g1s : g2s;
    const int wn = (w & 1) * 32;
#pragma unroll
    for (int m = 0; m < 2; ++m)
#pragma unroll
      for (int nn = 0; nn < 2; ++nn)
#pragma unroll
        for (int q = 0; q < 4; ++q) {
          const int slot = m * 16 + (lane >> 4) * 4 + q;
          const int r = wn + nn * 16 + (lane & 15);
          const float v = acc[m][nn][q];
          const float ge = 0.5f * v * (1.f + erff(v * 0.70710678118654752f));
          Hsx[slot * 64 + (r ^ ((slot & 7) << 3))] = f2bf(ge * gsx[slot]);
        }
  }
  __syncthreads();
  // writeout: thread covers row row0 of both halves (32 rows x 8 chunks)
  if (tk0 >= 0) {
    const int lof = row0 * 64 + (g8 ^ ((row0 & 7) << 3));
    *(ushort8*)(Hbuf + (size_t)tk0 * 64 + g8) = *(const ushort8*)&Hs0[lof];
    *(ushort8*)(Hbuf + ((size_t)TOKS + tk0) * 64 + g8) = *(const ushort8*)&Hs1[lof];
  }
}

// ---- up: out[t] = H0[t]@Wu_ea + H1[t]@Wu_eb, 64-tok x 2 col-slices --------
// (verified r9-r11) A0/A1 staged ONCE per block; slice-1 weights
// reg-prefetched under slice-0 MFMAs. Block x==UT_MAX runs aux.
__global__ __launch_bounds__(256) void up_kernel(
    const ushort* __restrict__ Hbuf, const ushort* __restrict__ wut,
    const int* __restrict__ cnt_pair, const int* __restrict__ pairlist,
    const int* __restrict__ uplan, const int* __restrict__ totals,
    const int* __restrict__ cnt, const float* __restrict__ imp_part,
    float* __restrict__ out) {
  __shared__ __align__(16) char smem[49664];
  if (blockIdx.x == UT_MAX) {          // aux block (y==0 only)
    if (blockIdx.y != 0) return;
    float* red = (float*)smem;
    float* tot = (float*)(smem + 1024);
    const int t = threadIdx.x;
    const int e = t & 7, b0 = t >> 3;
    float s = 0.f;
    for (int j = 0; j < NBLK_R / 32; ++j)
      s += imp_part[(b0 + 32 * j) * 8 + e];
    red[t] = s;
    __syncthreads();
    if (t < 8) {
      float tt = 0.f;
      for (int ww = 0; ww < 32; ++ww) tt += red[ww * 8 + t];
      tot[t] = tt;
    }
    __syncthreads();
    if (t == 0) {
      float a = 0.f;
#pragma unroll
      for (int ee = 0; ee < NEXP; ++ee)
        a += (tot[ee] / (float)TOKS) *
             ((float)(cnt[ee * 32] + cnt[(NEXP + ee) * 32]) / (float)(2 * TOKS));
      out[(size_t)TOKS * CDIM] = 0.001f * 8.f * a;
    }
    return;
  }
  if (blockIdx.x >= totals[1]) return;
  const int ent = uplan[blockIdx.x];
  const int b = ent >> 16, tile = ent & 0xffff;
  const int ea = b >> 3, eb = b & 7;
  const int n = cnt_pair[b * 32];
  const int start = tile * 64;
  const int ybase = blockIdx.y * 2;    // 2 slices per block

  ushort* A0  = (ushort*)(smem);            // 8 KB (64x64)
  ushort* A1  = (ushort*)(smem + 8192);     // 8 KB
  ushort* BuA = (ushort*)(smem + 16384);    // 16 KB (128x64)
  ushort* BuB = (ushort*)(smem + 32768);    // 16 KB
  int*  toks  = (int*)(smem + 49152);       // 256 B

  const int tid = threadIdx.x;
  const int lane = tid & 63;
  const int w = tid >> 6;
  const int wr = w >> 1, wc = w & 1;

  if (tid < 64) {
    int tk = -1;
    if (start + tid < n) tk = pairlist[b * CAP + start + tid];
    toks[tid] = tk;
  }
  __syncthreads();

  // issue slice-0 weight loads (pre-swizzled wut; linear copy)
  const ushort* wuA = wut + ((size_t)(ea * 8 + ybase)) * 8192;
  const ushort* wuB = wut + ((size_t)(eb * 8 + ybase)) * 8192;
  ushort8 rUA[4], rUB[4];
#pragma unroll
  for (int j = 0; j < 4; ++j) {
    rUA[j] = *(const ushort8*)(wuA + (tid + j * 256) * 8);
    rUB[j] = *(const ushort8*)(wuB + (tid + j * 256) * 8);
  }
  // A-gather (source col swizzled; LDS linear) — ONCE per block
  const int row0 = tid >> 3;
  const int g8 = (tid & 7) * 8;
  const int csw = g8 ^ ((row0 & 7) << 3);
  const int tk0 = toks[row0], tk1 = toks[row0 + 32];
  const size_t t0 = (size_t)(tk0 < 0 ? 0 : tk0);
  const size_t t1 = (size_t)(tk1 < 0 ? 0 : tk1);
  *(ushort8*)&A0[tid * 8]        = *(const ushort8*)(Hbuf + t0 * 64 + csw);
  *(ushort8*)&A0[tid * 8 + 2048] = *(const ushort8*)(Hbuf + t1 * 64 + csw);
  *(ushort8*)&A1[tid * 8]        = *(const ushort8*)(Hbuf + (TOKS + t0) * 64 + csw);
  *(ushort8*)&A1[tid * 8 + 2048] = *(const ushort8*)(Hbuf + (TOKS + t1) * 64 + csw);
  // write slice-0 weights
#pragma unroll
  for (int j = 0; j < 4; ++j) {
    *(ushort8*)&BuA[(tid + j * 256) * 8] = rUA[j];
    *(ushort8*)&BuB[(tid + j * 256) * 8] = rUB[j];
  }
  __syncthreads();

#pragma unroll 1
  for (int j2 = 0; j2 < 2; ++j2) {
    const int n0 = ybase + j2;
    if (j2 == 0) {                      // prefetch slice-1 weights under MFMA
#pragma unroll
      for (int j = 0; j < 4; ++j) {
        rUA[j] = *(const ushort8*)(wuA + 8192 + (tid + j * 256) * 8);
        rUB[j] = *(const ushort8*)(wuB + 8192 + (tid + j * 256) * 8);
      }
    }
    f32x4 uac[2][4];
#pragma unroll
    for (int m = 0; m < 2; ++m)
#pragma unroll
      for (int nn = 0; nn < 4; ++nn) uac[m][nn] = (f32x4){0.f, 0.f, 0.f, 0.f};
    // pass A: H0 @ Wu_ea
#pragma unroll
    for (int kk = 0; kk < 64; kk += 32) {
      const int kb = kk + (lane >> 4) * 8;
      bf16x8 a[2], bbv[4];
#pragma unroll
      for (int m = 0; m < 2; ++m) {
        const int row = wr * 32 + m * 16 + (lane & 15);
        a[m] = *(const bf16x8*)&A0[row * 64 + (kb ^ ((row & 7) << 3))];
      }
#pragma unroll
      for (int nn = 0; nn < 4; ++nn) {
        const int c = wc * 64 + nn * 16 + (lane & 15);
        bbv[nn] = *(const bf16x8*)&BuA[c * 64 + (kb ^ ((c & 7) << 3))];
      }
#pragma unroll
      for (int m = 0; m < 2; ++m)
#pragma unroll
        for (int nn = 0; nn < 4; ++nn)
          uac[m][nn] = __builtin_amdgcn_mfma_f32_16x16x32_bf16(a[m], bbv[nn], uac[m][nn], 0, 0, 0);
    }
    // pass B: H1 @ Wu_eb (accumulate)
#pragma unroll
    for (int kk = 0; kk < 64; kk += 32) {
      const int kb = kk + (lane >> 4) * 8;
      bf16x8 a[2], bbv[4];
#pragma unroll
      for (int m = 0; m < 2; ++m) {
        const int row = wr * 32 + m * 16 + (lane & 15);
        a[m] = *(const bf16x8*)&A1[row * 64 + (kb ^ ((row & 7) << 3))];
      }
#pragma unroll
      for (int nn = 0; nn < 4; ++nn) {
        const int c = wc * 64 + nn * 16 + (lane & 15);
        bbv[nn] = *(const bf16x8*)&BuB[c * 64 + (kb ^ ((c & 7) << 3))];
      }
#pragma unroll
      for (int m = 0; m < 2; ++m)
#pragma unroll
        for (int nn = 0; nn < 4; ++nn)
          uac[m][nn] = __builtin_amdgcn_mfma_f32_16x16x32_bf16(a[m], bbv[nn], uac[m][nn], 0, 0, 0);
    }
    if (j2 == 0) {
      __syncthreads();                  // all waves done reading Bu
#pragma unroll
      for (int j = 0; j < 4; ++j) {
        *(ushort8*)&BuA[(tid + j * 256) * 8] = rUA[j];
        *(ushort8*)&BuB[(tid + j * 256) * 8] = rUB[j];
      }
    }
    // store this 128-col slice
#pragma unroll
    for (int m = 0; m < 2; ++m)
#pragma unroll
      for (int q = 0; q < 4; ++q) {
        const int slot = wr * 32 + m * 16 + (lane >> 4) * 4 + q;
        const int tk = toks[slot];
        if (tk >= 0) {
          float* orow = out + (size_t)tk * CDIM + n0 * 128 + wc * 64 + (lane & 15);
#pragma unroll
          for (int nn = 0; nn < 4; ++nn) orow[nn * 16] = uac[m][nn][q];
        }
      }
    if (j2 == 0) __syncthreads();       // Bu writes visible for slice 1
  }
}

extern "C" void kernel_launch(void* const* d_in, const int* in_sizes, int n_in,
                              void* d_out, int out_size, void* d_ws, size_t ws_size,
                              hipStream_t stream) {
  const float* x   = (const float*)d_in[0];
  const float* rw  = (const float*)d_in[1];
  const float* rb  = (const float*)d_in[2];
  const float* Wd  = (const float*)d_in[3];
  const float* Wu  = (const float*)d_in[4];
  const int* key_id = (const int*)d_in[5];
  float* out = (float*)d_out;

  char* ws = (char*)d_ws;
  int*    cnt      = (int*)ws;                    // 2 KB  (16 x 128B)
  int*    cnt_pair = (int*)(ws + 2048);           // 8 KB  (64 x 128B)
  int*    totals   = (int*)(ws + 10240);          // 8 B
  float*  imp_part = (float*)(ws + 16384);        // 32 KB
  int*    dplan    = (int*)(ws + 49152);          // ~2.3 KB
  int*    uplan    = (int*)(ws + 57344);          // ~1.3 KB
  int*    pbuf     = (int*)(ws + 65536);          // 64 KB  (NOT aliased: read by scatter)
  float2* ggbuf    = (float2*)(ws + 131072);      // 128 KB (NOT aliased: read by down)
  ushort* wdt      = (ushort*)(ws + 2162688);     // 1 MB
  ushort* wut      = (ushort*)(ws + 3211264);     // 1 MB
  ushort* xb       = (ushort*)(ws + 4259840);     // 32 MB -> 37814272
  int*    pairlist = (int*)(ws + 37847040);       // 4 MB  -> 42041344
  ushort* Hbuf     = (ushort*)(ws + 42041344);    // 4 MB  -> 46235648

  // histT/baseT ALIAS the Hbuf region: fully consumed by scan/scatter before
  // down_kernel writes Hbuf. (pbuf/ggbuf moved OUT of the alias region since
  // down now reads ggbuf while writing Hbuf.)
  int*    histT = (int*)(ws + 42041344);                // 320 KB
  int*    baseT = (int*)(ws + 42041344 + 327680);       // 320 KB

  setup_kernel<<<NBLK_R + 256, 1024, 0, stream>>>(
      x, rw, rb, key_id, Wd, Wu, imp_part, pbuf, ggbuf, histT, xb, wdt, wut);
  scan_kernel<<<80, 256, 0, stream>>>(histT, baseT, cnt, cnt_pair);
  scatter_kernel<<<257, 256, 0, stream>>>(baseT, pbuf, cnt_pair,
                                          pairlist, dplan, uplan, totals);
  down_kernel<<<DT_MAX, 256, 0, stream>>>(xb, wdt, cnt_pair, pairlist, ggbuf,
                                          dplan, totals, Hbuf);
  up_kernel<<<dim3(UT_MAX + 1, 4), 256, 0, stream>>>(
      Hbuf, wut, cnt_pair, pairlist, uplan, totals, cnt, imp_part, out);
}